// Round 6
// baseline (215.781 us; speedup 1.0000x reference)
//
#include <hip/hip_runtime.h>

// ---------------------------------------------------------------------------
// LoRA_Attention: fold LoRA into weights; bf16 MFMA GEMMs; split-K flash
// attention. R14: k_attn kt-loop deep-pipelined — K/V prefetched 2 tiles
// ahead, relW prefetched 1 tile ahead and issued AFTER barrier#2, so
// barrier#1's vmcnt(0) drain only sees loads >=1 iteration old (R13 showed
// flat per-CU throughput vs residency = loaded-latency-bound chain, not
// occupancy). Loop unrolled x2 with register ping-pong (compile-time buf
// indices). CHUNKS=3 (648 blocks <= 768 cap at (256,3), single phase).
// relW direct-global bf16; exp2 softmax no-max; XCD-local grid.
// ---------------------------------------------------------------------------

#define DIM   768
#define HEADS 12
#define HD    64
#define NTOK  2304
#define RANK  8
#define GRD   48
#define CHUNKS 3
#define KEYS_PER_CHUNK 768
#define KT_PER 12
#define LOG2E 1.44269504088896f

typedef __attribute__((ext_vector_type(8))) short bf16x8;
typedef __attribute__((ext_vector_type(4))) float f32x4;
typedef unsigned short ushort_t;

__device__ __forceinline__ unsigned short f2bf(float x) {
    union { float f; unsigned u; } v; v.f = x;
    unsigned r = v.u + 0x7fffu + ((v.u >> 16) & 1u);
    return (unsigned short)(r >> 16);
}
__device__ __forceinline__ float bf2f(unsigned short h) {
    return __uint_as_float(((unsigned)h) << 16);
}
__device__ __forceinline__ void gload_lds16(const ushort_t* g, ushort_t* l) {
    __builtin_amdgcn_global_load_lds(
        (const __attribute__((address_space(1))) unsigned int*)g,
        (__attribute__((address_space(3))) unsigned int*)l, 16, 0, 0);
}

// ---------------------------------------------------------------------------
// k_prep: fold LoRA into transposed weights (all 2304 blocks) + convert
// x / rel tables to bf16 (blocks < 1740). Independent tasks, one launch.
// ---------------------------------------------------------------------------
__global__ __launch_bounds__(256) void k_prep(
    const float* __restrict__ x, ushort_t* __restrict__ xb,
    const float* __restrict__ rph, const float* __restrict__ rpw,
    ushort_t* __restrict__ rphb, ushort_t* __restrict__ rpwb,
    const float* __restrict__ Wq, const float* __restrict__ Wk,
    const float* __restrict__ Wv, const float* __restrict__ Wp,
    const float* __restrict__ Aq, const float* __restrict__ Bq,
    const float* __restrict__ Ak, const float* __restrict__ Bk,
    const float* __restrict__ Av, const float* __restrict__ Bv,
    ushort_t* __restrict__ WT) {
    int bid = blockIdx.x, tid = threadIdx.x;

    if (bid < 1740) {
        if (bid < 1728) {
            int idx = (bid * 256 + tid) * 4;
            float4 v = *(const float4*)(x + idx);
            ushort4 o = make_ushort4(f2bf(v.x), f2bf(v.y), f2bf(v.z), f2bf(v.w));
            *(ushort4*)(xb + idx) = o;
        } else {
            int e = ((bid - 1728) * 256 + tid) * 4;
            const int TSZ = (2 * GRD - 1) * HD;   // 6080
            if (e < TSZ) {
                float4 v = *(const float4*)(rph + e);
                ushort4 o = make_ushort4(f2bf(v.x), f2bf(v.y), f2bf(v.z), f2bf(v.w));
                *(ushort4*)(rphb + e) = o;
            } else if (e < 2 * TSZ) {
                float4 v = *(const float4*)(rpw + e - TSZ);
                ushort4 o = make_ushort4(f2bf(v.x), f2bf(v.y), f2bf(v.z), f2bf(v.w));
                *(ushort4*)(rpwb + e - TSZ) = o;
            }
        }
    }

    int kb = (bid % 24) * 32;
    int nb = (bid / 24) * 32;
    int sel = nb / DIM, nmod = nb % DIM;
    const float* W = (sel == 0) ? Wq : (sel == 1) ? Wk : (sel == 2) ? Wv : Wp;
    const float* A = (sel == 0) ? Aq : (sel == 1) ? Ak : Av;
    const float* B = (sel == 0) ? Bq : (sel == 1) ? Bk : Bv;
    __shared__ float T[32][33];
    for (int i = tid; i < 1024; i += 256) {
        int kl = i >> 5, nl = i & 31;
        float v = W[(kb + kl) * DIM + nmod + nl];
        if (sel < 3) {
            #pragma unroll
            for (int r = 0; r < RANK; r++)
                v += A[(kb + kl) * RANK + r] * B[r * DIM + nmod + nl];
        }
        T[kl][nl] = v;
    }
    __syncthreads();
    for (int i = tid; i < 1024; i += 256) {
        int nl = i >> 5, kl = i & 31;
        WT[(size_t)(nb + nl) * DIM + kb + kl] = f2bf(T[kl][nl]);
    }
}

// ---------------------------------------------------------------------------
// QKV GEMM: 128(M)x64(N) tiles -> 648 blocks (~2.5/CU, no packing tail),
// BK=32, global_load_lds DMA, 12 KB LDS. Waves 2x2: wave = 64 rows x 32 cols.
// ---------------------------------------------------------------------------
__global__ __launch_bounds__(256) void k_gemm_qkv(
    const ushort_t* __restrict__ xb, const ushort_t* __restrict__ WT,
    const float* __restrict__ bq, const float* __restrict__ bk,
    const float* __restrict__ bv,
    ushort_t* __restrict__ Qb, ushort_t* __restrict__ Kb,
    ushort_t* __restrict__ Vtb) {
    __shared__ __align__(16) ushort_t As[128 * 32];   // 8 KB
    __shared__ __align__(16) ushort_t Bs[64 * 32];    // 4 KB
    int tid = threadIdx.x;
    int wave = tid >> 6, lane = tid & 63, quad = lane >> 4, l16 = lane & 15;
    int wx = wave & 1, wy = wave >> 1;
    int nb = blockIdx.x * 64, mb = blockIdx.y * 128;

    f32x4 zero = {0.f, 0.f, 0.f, 0.f};
    f32x4 acc[4][2];
    #pragma unroll
    for (int i = 0; i < 4; i++)
        #pragma unroll
        for (int j = 0; j < 2; j++) acc[i][j] = zero;

    int rl = lane >> 2;            // 0..15
    int cl = (lane & 3) * 8;       // element col within 32
    const ushort_t* gA = xb + (size_t)(mb + wave * 32 + rl) * DIM + cl;
    const ushort_t* gB = WT + (size_t)(nb + wave * 16 + rl) * DIM + cl;
    ushort_t* lA = &As[(wave * 32) * 32];
    ushort_t* lB = &Bs[(wave * 16) * 32];

    for (int k0 = 0; k0 < DIM; k0 += 32) {
        __syncthreads();
        gload_lds16(gA + k0,            lA);
        gload_lds16(gA + k0 + 16 * DIM, lA + 16 * 32);
        gload_lds16(gB + k0,            lB);
        __syncthreads();
        bf16x8 af[4], bf[2];
        #pragma unroll
        for (int i = 0; i < 4; i++)
            af[i] = *(const bf16x8*)&As[(wy * 64 + i * 16 + l16) * 32 + quad * 8];
        #pragma unroll
        for (int j = 0; j < 2; j++)
            bf[j] = *(const bf16x8*)&Bs[(wx * 32 + j * 16 + l16) * 32 + quad * 8];
        #pragma unroll
        for (int i = 0; i < 4; i++)
            #pragma unroll
            for (int j = 0; j < 2; j++)
                acc[i][j] = __builtin_amdgcn_mfma_f32_16x16x32_bf16(af[i], bf[j], acc[i][j], 0, 0, 0);
    }

    #pragma unroll
    for (int j = 0; j < 2; j++) {
        int col = nb + wx * 32 + j * 16 + l16;
        int sel = col / DIM, rem = col % DIM;
        int hh = rem >> 6, cc = rem & 63;
        const float* bias = (sel == 0) ? bq : (sel == 1) ? bk : bv;
        float bval = bias[rem];
        #pragma unroll
        for (int i = 0; i < 4; i++) {
            #pragma unroll
            for (int r = 0; r < 4; r++) {
                int row = mb + wy * 64 + i * 16 + quad * 4 + r;
                unsigned short o = f2bf(acc[i][j][r] + bval);
                if (sel == 0)      Qb[(size_t)(hh * NTOK + row) * HD + cc] = o;
                else if (sel == 1) Kb[(size_t)(hh * NTOK + row) * HD + cc] = o;
                else               Vtb[(size_t)(hh * HD + cc) * NTOK + row] = o;
            }
        }
    }
}

// ---------------------------------------------------------------------------
// Rel-pos bias via MFMA (outputs pre-scaled by log2 e).
// relW emitted as bf16 (k_attn reads it directly from global); relH
// stays f32 (staged+converted into k_attn's small rhs LDS buffer).
// ---------------------------------------------------------------------------
__global__ __launch_bounds__(256) void k_relmm(
    const ushort_t* __restrict__ Qb, const ushort_t* __restrict__ rphb,
    const ushort_t* __restrict__ rpwb, float* __restrict__ relH,
    ushort_t* __restrict__ relWb) {
    int id = blockIdx.x * 4 + (threadIdx.x >> 6);
    int lane = threadIdx.x & 63, quad = lane >> 4, l16 = lane & 15;
    bool isW = id >= 576;
    int t = isW ? id - 576 : id;
    int h = t / GRD, g = t % GRD;
    const ushort_t* tab = isW ? rpwb : rphb;

    f32x4 zero = {0.f, 0.f, 0.f, 0.f};
    f32x4 acc[3][3];
    #pragma unroll
    for (int i = 0; i < 3; i++)
        #pragma unroll
        for (int j = 0; j < 3; j++) acc[i][j] = zero;

    bf16x8 bfr[3][2];
    #pragma unroll
    for (int ct = 0; ct < 3; ct++) {
        int trow = g + 47 - (ct * 16 + l16);
        bfr[ct][0] = *(const bf16x8*)&tab[(size_t)trow * HD + quad * 8];
        bfr[ct][1] = *(const bf16x8*)&tab[(size_t)trow * HD + 32 + quad * 8];
    }
    #pragma unroll
    for (int ms = 0; ms < 3; ms++) {
        int m = ms * 16 + l16;
        int n = isW ? m * GRD + g : g * GRD + m;
        bf16x8 a0 = *(const bf16x8*)&Qb[(size_t)(h * NTOK + n) * HD + quad * 8];
        bf16x8 a1 = *(const bf16x8*)&Qb[(size_t)(h * NTOK + n) * HD + 32 + quad * 8];
        #pragma unroll
        for (int ct = 0; ct < 3; ct++) {
            acc[ms][ct] = __builtin_amdgcn_mfma_f32_16x16x32_bf16(a0, bfr[ct][0], acc[ms][ct], 0, 0, 0);
            acc[ms][ct] = __builtin_amdgcn_mfma_f32_16x16x32_bf16(a1, bfr[ct][1], acc[ms][ct], 0, 0, 0);
        }
    }
    #pragma unroll
    for (int ms = 0; ms < 3; ms++) {
        #pragma unroll
        for (int ct = 0; ct < 3; ct++) {
            #pragma unroll
            for (int r = 0; r < 4; r++) {
                int m = ms * 16 + quad * 4 + r;
                int n = isW ? m * GRD + g : g * GRD + m;
                int col = ct * 16 + l16;
                float val = acc[ms][ct][r] * LOG2E;
                if (isW)
                    relWb[(size_t)(h * NTOK + n) * GRD + col] = f2bf(val);
                else
                    relH[(size_t)(h * NTOK + n) * GRD + col] = val;
            }
        }
    }
}

// ---------------------------------------------------------------------------
// Flash attention, split-K. Block = (128 q-rows, head, chunk of 768 keys).
// Grid 648 <= 768 capacity (3 blk/CU at (256,3)): single-phase.
// Deep pipeline: K/V 2 tiles ahead (reg ping-pong, issue-to-use ~2 iters),
// relW 1 tile ahead issued post-barrier#2 (barrier#1 vmcnt(0) drain never
// exposes raw load latency). Loop unrolled x2, compile-time buffer indices.
// ---------------------------------------------------------------------------
__global__ __launch_bounds__(256, 3) void k_attn(
    const ushort_t* __restrict__ Qb, const ushort_t* __restrict__ Kb,
    const ushort_t* __restrict__ Vtb, const float* __restrict__ relH,
    const ushort_t* __restrict__ relWb, float* __restrict__ Opart,
    float* __restrict__ Lpart) {
    int h = blockIdx.x / CHUNKS, chunk = blockIdx.x - h * CHUNKS;
    int qt = blockIdx.y;
    int tid = threadIdx.x;
    int wave = tid >> 6, lane = tid & 63, quad = lane >> 4, l16 = lane & 15;
    int qbase = qt * 128;
    int kbase = chunk * KEYS_PER_CHUNK;

    __shared__ __align__(16) ushort_t Ks[64 * 68];
    __shared__ __align__(16) ushort_t Vs[64 * 68];
    __shared__ __align__(16) ushort_t Ps[4][32 * 68];
    __shared__ __align__(16) ushort_t rhs[128 * 18];

    for (int i = tid; i < 128 * 16; i += 256) {
        int r = i >> 4, c = i & 15;
        rhs[r * 18 + c] = f2bf(relH[(size_t)(h * NTOK + qbase + r) * GRD + chunk * 16 + c]);
    }

    bf16x8 qf[2][2];
    #pragma unroll
    for (int s = 0; s < 2; s++) {
        int qrow = qbase + wave * 32 + s * 16 + l16;
        qf[s][0] = *(const bf16x8*)&Qb[(size_t)(h * NTOK + qrow) * HD + quad * 8];
        qf[s][1] = *(const bf16x8*)&Qb[(size_t)(h * NTOK + qrow) * HD + 32 + quad * 8];
    }

    int r0 = tid >> 3, c0 = (tid & 7) * 8;
    const ushort_t* kg0 = Kb + (size_t)(h * NTOK + r0) * HD + c0;
    const ushort_t* kg1 = Kb + (size_t)(h * NTOK + r0 + 32) * HD + c0;
    const ushort_t* vg0 = Vtb + (size_t)(h * HD + r0) * NTOK + c0;
    const ushort_t* vg1 = Vtb + (size_t)(h * HD + r0 + 32) * NTOK + c0;
    int sk0 = r0 * 68 + c0, sk1 = sk0 + 32 * 68;

    // per-lane relW row pointers (rows owned by this lane across s=0,1)
    const ushort_t* rw0 = relWb + (size_t)(h * NTOK + qbase + wave * 32 + l16) * GRD;
    const ushort_t* rw1 = rw0 + (size_t)16 * GRD;

    float lacc[2] = {0.f, 0.f};
    f32x4 zero = {0.f, 0.f, 0.f, 0.f};
    f32x4 oacc[2][4];
    #pragma unroll
    for (int s = 0; s < 2; s++)
        #pragma unroll
        for (int cs = 0; cs < 4; cs++) oacc[s][cs] = zero;

    const float scale2 = 0.125f * LOG2E;

    // ---- 2-deep K/V register prefetch (A = even kt, B = odd kt) ----
    uint4 kA0 = *(const uint4*)(kg0 + (size_t)kbase * HD);
    uint4 kA1 = *(const uint4*)(kg1 + (size_t)kbase * HD);
    uint4 vA0 = *(const uint4*)(vg0 + kbase);
    uint4 vA1 = *(const uint4*)(vg1 + kbase);
    uint4 kB0 = *(const uint4*)(kg0 + (size_t)(kbase + 64) * HD);
    uint4 kB1 = *(const uint4*)(kg1 + (size_t)(kbase + 64) * HD);
    uint4 vB0 = *(const uint4*)(vg0 + (kbase + 64));
    uint4 vB1 = *(const uint4*)(vg1 + (kbase + 64));

    // ---- 1-deep relW prefetch: fill buffer for kt=0 ----
    uint2 rwvA[2][4], rwvB[2][4];
    #pragma unroll
    for (int ks = 0; ks < 4; ks++) {
        int kb4 = kbase + ks * 16 + quad * 4;
        int kh = kb4 / 48;
        int kw0 = kb4 - kh * 48;
        rwvA[0][ks] = *(const uint2*)(rw0 + kw0);
        rwvA[1][ks] = *(const uint2*)(rw1 + kw0);
    }

    // one kt iteration; buffers passed by reference with compile-time identity
    auto kt_body = [&](int kt, uint4& Rk0, uint4& Rk1, uint4& Rv0, uint4& Rv1,
                       uint2 (&rwvC)[2][4], uint2 (&rwvN)[2][4]) {
        int kb = kbase + kt * 64;

        __syncthreads();
        *(uint4*)&Ks[sk0] = Rk0;  *(uint4*)&Ks[sk1] = Rk1;
        *(uint4*)&Vs[sk0] = Rv0;  *(uint4*)&Vs[sk1] = Rv1;
        __syncthreads();

        // refill this register buffer with tile kt+2
        if (kt + 2 < KT_PER) {
            int kbn = kb + 128;
            Rk0 = *(const uint4*)(kg0 + (size_t)kbn * HD);
            Rk1 = *(const uint4*)(kg1 + (size_t)kbn * HD);
            Rv0 = *(const uint4*)(vg0 + kbn);
            Rv1 = *(const uint4*)(vg1 + kbn);
        }
        // prefetch relW for kt+1
        if (kt + 1 < KT_PER) {
            int kbp = kb + 64;
            #pragma unroll
            for (int ks = 0; ks < 4; ks++) {
                int kb4 = kbp + ks * 16 + quad * 4;
                int kh = kb4 / 48;
                int kw0 = kb4 - kh * 48;
                rwvN[0][ks] = *(const uint2*)(rw0 + kw0);
                rwvN[1][ks] = *(const uint2*)(rw1 + kw0);
            }
        }

        #pragma unroll
        for (int ks = 0; ks < 4; ks++) {
            bf16x8 kf0 = *(const bf16x8*)&Ks[(ks * 16 + l16) * 68 + quad * 8];
            bf16x8 kf1 = *(const bf16x8*)&Ks[(ks * 16 + l16) * 68 + 32 + quad * 8];
            f32x4 st[2];
            #pragma unroll
            for (int s = 0; s < 2; s++) {
                f32x4 z = zero;
                z = __builtin_amdgcn_mfma_f32_16x16x32_bf16(kf0, qf[s][0], z, 0, 0, 0);
                z = __builtin_amdgcn_mfma_f32_16x16x32_bf16(kf1, qf[s][1], z, 0, 0, 0);
                st[s] = z;
            }
            int kb4 = kb + ks * 16 + quad * 4;
            int khl = kb4 / 48 - chunk * 16;
            #pragma unroll
            for (int s = 0; s < 2; s++) {
                int row = wave * 32 + s * 16 + l16;
                float rh = bf2f(rhs[row * 18 + khl]);
                uint2 u = rwvC[s][ks];
                float p0 = __builtin_amdgcn_exp2f(st[s][0] * scale2 + rh + __uint_as_float(u.x << 16));
                float p1 = __builtin_amdgcn_exp2f(st[s][1] * scale2 + rh + __uint_as_float(u.x & 0xffff0000u));
                float p2 = __builtin_amdgcn_exp2f(st[s][2] * scale2 + rh + __uint_as_float(u.y << 16));
                float p3 = __builtin_amdgcn_exp2f(st[s][3] * scale2 + rh + __uint_as_float(u.y & 0xffff0000u));
                lacc[s] += (p0 + p1) + (p2 + p3);
                uint2 w;
                w.x = __builtin_amdgcn_perm(__float_as_uint(p1), __float_as_uint(p0), 0x07060302u);
                w.y = __builtin_amdgcn_perm(__float_as_uint(p3), __float_as_uint(p2), 0x07060302u);
                *(uint2*)&Ps[wave][(s * 16 + l16) * 68 + ks * 16 + quad * 4] = w;
            }
        }

        bf16x8 vf[4][2];
        #pragma unroll
        for (int cs = 0; cs < 4; cs++) {
            vf[cs][0] = *(const bf16x8*)&Vs[(cs * 16 + l16) * 68 + quad * 8];
            vf[cs][1] = *(const bf16x8*)&Vs[(cs * 16 + l16) * 68 + 32 + quad * 8];
        }
        #pragma unroll
        for (int s = 0; s < 2; s++) {
            bf16x8 pa0 = *(const bf16x8*)&Ps[wave][(s * 16 + l16) * 68 + quad * 8];
            bf16x8 pa1 = *(const bf16x8*)&Ps[wave][(s * 16 + l16) * 68 + 32 + quad * 8];
            #pragma unroll
            for (int cs = 0; cs < 4; cs++) {
                oacc[s][cs] = __builtin_amdgcn_mfma_f32_16x16x32_bf16(pa0, vf[cs][0], oacc[s][cs], 0, 0, 0);
                oacc[s][cs] = __builtin_amdgcn_mfma_f32_16x16x32_bf16(pa1, vf[cs][1], oacc[s][cs], 0, 0, 0);
            }
        }
    };

    #pragma unroll 1
    for (int kt = 0; kt < KT_PER; kt += 2) {
        kt_body(kt,     kA0, kA1, vA0, vA1, rwvA, rwvB);
        kt_body(kt + 1, kB0, kB1, vB0, vB1, rwvB, rwvA);
    }

    #pragma unroll
    for (int s = 0; s < 2; s++) {
        float l = lacc[s];
        l += __shfl_xor(l, 16);
        l += __shfl_xor(l, 32);
        lacc[s] = l;
    }

    size_t obase = (size_t)(chunk * HEADS + h) * NTOK;
    #pragma unroll
    for (int s = 0; s < 2; s++) {
        #pragma unroll
        for (int cs = 0; cs < 4; cs++) {
            #pragma unroll
            for (int r = 0; r < 4; r++) {
                int row = qbase + wave * 32 + s * 16 + quad * 4 + r;
                Opart[(obase + row) * HD + cs * 16 + l16] = oacc[s][cs][r];
            }
        }
        if (quad == 0)
            Lpart[obase + qbase + wave * 32 + s * 16 + l16] = lacc[s];
    }
}

// ---------------------------------------------------------------------------
// Merge split-K partials: Ob = (sum_ch O) / (sum_ch l), bf16.
// ---------------------------------------------------------------------------
__global__ __launch_bounds__(256) void k_merge(const float* __restrict__ Opart,
                                               const float* __restrict__ Lpart,
                                               ushort_t* __restrict__ Ob) {
    int t = blockIdx.x * 256 + threadIdx.x;
    int e = t * 4;
    int c = e & (HD - 1);
    int row = (e >> 6) % NTOK;
    int h = e / (NTOK * HD);
    const int ostride = HEADS * NTOK * HD;
    float4 s = {0.f, 0.f, 0.f, 0.f};
    float l = 0.f;
    #pragma unroll
    for (int ch = 0; ch < CHUNKS; ch++) {
        float4 v = *(const float4*)&Opart[(size_t)ch * ostride + e];
        s.x += v.x; s.y += v.y; s.z += v.z; s.w += v.w;
        l += Lpart[(size_t)(ch * HEADS + h) * NTOK + row];
    }
    float inv = 1.0f / l;
    ushort4 o = make_ushort4(f2bf(s.x * inv), f2bf(s.y * inv),
                             f2bf(s.z * inv), f2bf(s.w * inv));
    *(ushort4*)&Ob[(size_t)row * DIM + h * HD + c] = o;
}

// ---------------------------------------------------------------------------
// Output projection: 128(M)x64(N) tiles -> 216 blocks, BK=32,
// global_load_lds DMA staging, 12 KB LDS. 2x2 waves: wave = 64 rows x 32 cols.
// ---------------------------------------------------------------------------
__global__ __launch_bounds__(256) void k_gemm_proj(
    const ushort_t* __restrict__ Ob, const ushort_t* __restrict__ WTp,
    const float* __restrict__ bp, float* __restrict__ out) {
    __shared__ __align__(16) ushort_t As[128 * 32];   // 8 KB
    __shared__ __align__(16) ushort_t Bs[64 * 32];    // 4 KB
    int tid = threadIdx.x;
    int wave = tid >> 6, lane = tid & 63, quad = lane >> 4, l16 = lane & 15;
    int wx = wave & 1, wy = wave >> 1;
    int nb = blockIdx.x * 64, mb = blockIdx.y * 128;

    f32x4 zero = {0.f, 0.f, 0.f, 0.f};
    f32x4 acc[4][2];
    #pragma unroll
    for (int i = 0; i < 4; i++)
        #pragma unroll
        for (int j = 0; j < 2; j++) acc[i][j] = zero;

    int rl = lane >> 2;
    int cl = (lane & 3) * 8;
    const ushort_t* gA = Ob + (size_t)(mb + wave * 32 + rl) * DIM + cl;
    const ushort_t* gB = WTp + (size_t)(nb + wave * 16 + rl) * DIM + cl;
    ushort_t* lA = &As[(wave * 32) * 32];
    ushort_t* lB = &Bs[(wave * 16) * 32];

    for (int k0 = 0; k0 < DIM; k0 += 32) {
        __syncthreads();
        gload_lds16(gA + k0,            lA);
        gload_lds16(gA + k0 + 16 * DIM, lA + 16 * 32);
        gload_lds16(gB + k0,            lB);
        __syncthreads();
        bf16x8 af[4], bf[2];
        #pragma unroll
        for (int i = 0; i < 4; i++)
            af[i] = *(const bf16x8*)&As[(wy * 64 + i * 16 + l16) * 32 + quad * 8];
        #pragma unroll
        for (int j = 0; j < 2; j++)
            bf[j] = *(const bf16x8*)&Bs[(wx * 32 + j * 16 + l16) * 32 + quad * 8];
        #pragma unroll
        for (int i = 0; i < 4; i++)
            #pragma unroll
            for (int j = 0; j < 2; j++)
                acc[i][j] = __builtin_amdgcn_mfma_f32_16x16x32_bf16(af[i], bf[j], acc[i][j], 0, 0, 0);
    }

    #pragma unroll
    for (int j = 0; j < 2; j++) {
        int col = nb + wx * 32 + j * 16 + l16;
        float bval = bp[col];
        #pragma unroll
        for (int i = 0; i < 4; i++) {
            #pragma unroll
            for (int r = 0; r < 4; r++) {
                int row = mb + wy * 64 + i * 16 + quad * 4 + r;
                out[(size_t)row * DIM + col] = acc[i][j][r] + bval;
            }
        }
    }
}

// ---------------------------------------------------------------------------
extern "C" void kernel_launch(void* const* d_in, const int* in_sizes, int n_in,
                              void* d_out, int out_size, void* d_ws, size_t ws_size,
                              hipStream_t stream) {
    const float* x   = (const float*)d_in[0];
    const float* Wq  = (const float*)d_in[1];
    const float* bq  = (const float*)d_in[2];
    const float* Wk  = (const float*)d_in[3];
    const float* bk  = (const float*)d_in[4];
    const float* Wv  = (const float*)d_in[5];
    const float* bv  = (const float*)d_in[6];
    const float* Wp  = (const float*)d_in[7];
    const float* bp  = (const float*)d_in[8];
    const float* rph = (const float*)d_in[9];
    const float* rpw = (const float*)d_in[10];
    const float* Aq  = (const float*)d_in[11];
    const float* Bq  = (const float*)d_in[12];
    const float* Ak  = (const float*)d_in[13];
    const float* Bk  = (const float*)d_in[14];
    const float* Av  = (const float*)d_in[15];
    const float* Bv  = (const float*)d_in[16];
    float* out = (float*)d_out;

    char* w = (char*)d_ws;
    size_t off = 0;
    auto carve = [&](size_t bytes) {
        char* p = w + off;
        off += (bytes + 255) & ~(size_t)255;
        return p;
    };
    ushort_t* xb    = (ushort_t*)carve((size_t)NTOK * DIM * 2);
    ushort_t* WT    = (ushort_t*)carve((size_t)4 * DIM * DIM * 2);
    ushort_t* Qb    = (ushort_t*)carve((size_t)HEADS * NTOK * HD * 2);
    ushort_t* Kb    = (ushort_t*)carve((size_t)HEADS * NTOK * HD * 2);
    ushort_t* Vtb   = (ushort_t*)carve((size_t)HEADS * HD * NTOK * 2);
    float*    relH  = (float*)carve((size_t)HEADS * NTOK * GRD * 4);
    ushort_t* relWb = (ushort_t*)carve((size_t)HEADS * NTOK * GRD * 2);
    ushort_t* Ob    = (ushort_t*)carve((size_t)NTOK * DIM * 2);
    float*    Opart = (float*)carve((size_t)CHUNKS * HEADS * NTOK * HD * 4);
    float*    Lpart = (float*)carve((size_t)CHUNKS * HEADS * NTOK * 4);
    ushort_t* rphb  = (ushort_t*)carve((size_t)(2 * GRD - 1) * HD * 2);
    ushort_t* rpwb  = (ushort_t*)carve((size_t)(2 * GRD - 1) * HD * 2);

    k_prep<<<dim3(2304), dim3(256), 0, stream>>>(
        x, xb, rph, rpw, rphb, rpwb,
        Wq, Wk, Wv, Wp, Aq, Bq, Ak, Bk, Av, Bv, WT);
    k_gemm_qkv<<<dim3(36, 18), dim3(256), 0, stream>>>(
        xb, WT, bq, bk, bv, Qb, Kb, Vtb);
    k_relmm<<<dim3(288), dim3(256), 0, stream>>>(
        Qb, rphb, rpwb, relH, relWb);
    k_attn<<<dim3(HEADS * CHUNKS, NTOK / 128), dim3(256), 0, stream>>>(
        Qb, Kb, Vtb, relH, relWb, Opart, Lpart);
    k_merge<<<dim3(HEADS * NTOK * HD / (256 * 4)), dim3(256), 0, stream>>>(
        Opart, Lpart, Ob);
    k_gemm_proj<<<dim3(12, 18), dim3(256), 0, stream>>>(
        Ob, WT + (size_t)3 * DIM * DIM, bp, out);
}

// Round 7
// 194.647 us; speedup vs baseline: 1.1086x; 1.1086x over previous
//
#include <hip/hip_runtime.h>

// ---------------------------------------------------------------------------
// LoRA_Attention: fold LoRA into weights; bf16 MFMA GEMMs; split-K flash
// attention. R15 = R13 + relW prefetched ONE kt ahead (ping-pong regs),
// issued AFTER barrier#2 so barrier#1's vmcnt(0) drain never exposes raw
// load latency (R13 issued rwv right before barrier#1 -> full L2 latency
// serialized every kt). +16 VGPR only — R14 proved the (256,3) arch cap
// is ~104 (K/V ping-pong +32 spilled, WRITE_SIZE 21->90MB); 76+16=92 fits.
// CHUNKS=3 (648 blocks <= 768 cap, single phase). relW direct-global bf16.
// ---------------------------------------------------------------------------

#define DIM   768
#define HEADS 12
#define HD    64
#define NTOK  2304
#define RANK  8
#define GRD   48
#define CHUNKS 3
#define KEYS_PER_CHUNK 768
#define KT_PER 12
#define LOG2E 1.44269504088896f

typedef __attribute__((ext_vector_type(8))) short bf16x8;
typedef __attribute__((ext_vector_type(4))) float f32x4;
typedef unsigned short ushort_t;

__device__ __forceinline__ unsigned short f2bf(float x) {
    union { float f; unsigned u; } v; v.f = x;
    unsigned r = v.u + 0x7fffu + ((v.u >> 16) & 1u);
    return (unsigned short)(r >> 16);
}
__device__ __forceinline__ float bf2f(unsigned short h) {
    return __uint_as_float(((unsigned)h) << 16);
}
__device__ __forceinline__ void gload_lds16(const ushort_t* g, ushort_t* l) {
    __builtin_amdgcn_global_load_lds(
        (const __attribute__((address_space(1))) unsigned int*)g,
        (__attribute__((address_space(3))) unsigned int*)l, 16, 0, 0);
}

// ---------------------------------------------------------------------------
// k_prep: fold LoRA into transposed weights (all 2304 blocks) + convert
// x / rel tables to bf16 (blocks < 1740). Independent tasks, one launch.
// ---------------------------------------------------------------------------
__global__ __launch_bounds__(256) void k_prep(
    const float* __restrict__ x, ushort_t* __restrict__ xb,
    const float* __restrict__ rph, const float* __restrict__ rpw,
    ushort_t* __restrict__ rphb, ushort_t* __restrict__ rpwb,
    const float* __restrict__ Wq, const float* __restrict__ Wk,
    const float* __restrict__ Wv, const float* __restrict__ Wp,
    const float* __restrict__ Aq, const float* __restrict__ Bq,
    const float* __restrict__ Ak, const float* __restrict__ Bk,
    const float* __restrict__ Av, const float* __restrict__ Bv,
    ushort_t* __restrict__ WT) {
    int bid = blockIdx.x, tid = threadIdx.x;

    if (bid < 1740) {
        if (bid < 1728) {
            int idx = (bid * 256 + tid) * 4;
            float4 v = *(const float4*)(x + idx);
            ushort4 o = make_ushort4(f2bf(v.x), f2bf(v.y), f2bf(v.z), f2bf(v.w));
            *(ushort4*)(xb + idx) = o;
        } else {
            int e = ((bid - 1728) * 256 + tid) * 4;
            const int TSZ = (2 * GRD - 1) * HD;   // 6080
            if (e < TSZ) {
                float4 v = *(const float4*)(rph + e);
                ushort4 o = make_ushort4(f2bf(v.x), f2bf(v.y), f2bf(v.z), f2bf(v.w));
                *(ushort4*)(rphb + e) = o;
            } else if (e < 2 * TSZ) {
                float4 v = *(const float4*)(rpw + e - TSZ);
                ushort4 o = make_ushort4(f2bf(v.x), f2bf(v.y), f2bf(v.z), f2bf(v.w));
                *(ushort4*)(rpwb + e - TSZ) = o;
            }
        }
    }

    int kb = (bid % 24) * 32;
    int nb = (bid / 24) * 32;
    int sel = nb / DIM, nmod = nb % DIM;
    const float* W = (sel == 0) ? Wq : (sel == 1) ? Wk : (sel == 2) ? Wv : Wp;
    const float* A = (sel == 0) ? Aq : (sel == 1) ? Ak : Av;
    const float* B = (sel == 0) ? Bq : (sel == 1) ? Bk : Bv;
    __shared__ float T[32][33];
    for (int i = tid; i < 1024; i += 256) {
        int kl = i >> 5, nl = i & 31;
        float v = W[(kb + kl) * DIM + nmod + nl];
        if (sel < 3) {
            #pragma unroll
            for (int r = 0; r < RANK; r++)
                v += A[(kb + kl) * RANK + r] * B[r * DIM + nmod + nl];
        }
        T[kl][nl] = v;
    }
    __syncthreads();
    for (int i = tid; i < 1024; i += 256) {
        int nl = i >> 5, kl = i & 31;
        WT[(size_t)(nb + nl) * DIM + kb + kl] = f2bf(T[kl][nl]);
    }
}

// ---------------------------------------------------------------------------
// QKV GEMM: 128(M)x64(N) tiles -> 648 blocks (~2.5/CU, no packing tail),
// BK=32, global_load_lds DMA, 12 KB LDS. Waves 2x2: wave = 64 rows x 32 cols.
// ---------------------------------------------------------------------------
__global__ __launch_bounds__(256) void k_gemm_qkv(
    const ushort_t* __restrict__ xb, const ushort_t* __restrict__ WT,
    const float* __restrict__ bq, const float* __restrict__ bk,
    const float* __restrict__ bv,
    ushort_t* __restrict__ Qb, ushort_t* __restrict__ Kb,
    ushort_t* __restrict__ Vtb) {
    __shared__ __align__(16) ushort_t As[128 * 32];   // 8 KB
    __shared__ __align__(16) ushort_t Bs[64 * 32];    // 4 KB
    int tid = threadIdx.x;
    int wave = tid >> 6, lane = tid & 63, quad = lane >> 4, l16 = lane & 15;
    int wx = wave & 1, wy = wave >> 1;
    int nb = blockIdx.x * 64, mb = blockIdx.y * 128;

    f32x4 zero = {0.f, 0.f, 0.f, 0.f};
    f32x4 acc[4][2];
    #pragma unroll
    for (int i = 0; i < 4; i++)
        #pragma unroll
        for (int j = 0; j < 2; j++) acc[i][j] = zero;

    int rl = lane >> 2;            // 0..15
    int cl = (lane & 3) * 8;       // element col within 32
    const ushort_t* gA = xb + (size_t)(mb + wave * 32 + rl) * DIM + cl;
    const ushort_t* gB = WT + (size_t)(nb + wave * 16 + rl) * DIM + cl;
    ushort_t* lA = &As[(wave * 32) * 32];
    ushort_t* lB = &Bs[(wave * 16) * 32];

    for (int k0 = 0; k0 < DIM; k0 += 32) {
        __syncthreads();
        gload_lds16(gA + k0,            lA);
        gload_lds16(gA + k0 + 16 * DIM, lA + 16 * 32);
        gload_lds16(gB + k0,            lB);
        __syncthreads();
        bf16x8 af[4], bf[2];
        #pragma unroll
        for (int i = 0; i < 4; i++)
            af[i] = *(const bf16x8*)&As[(wy * 64 + i * 16 + l16) * 32 + quad * 8];
        #pragma unroll
        for (int j = 0; j < 2; j++)
            bf[j] = *(const bf16x8*)&Bs[(wx * 32 + j * 16 + l16) * 32 + quad * 8];
        #pragma unroll
        for (int i = 0; i < 4; i++)
            #pragma unroll
            for (int j = 0; j < 2; j++)
                acc[i][j] = __builtin_amdgcn_mfma_f32_16x16x32_bf16(af[i], bf[j], acc[i][j], 0, 0, 0);
    }

    #pragma unroll
    for (int j = 0; j < 2; j++) {
        int col = nb + wx * 32 + j * 16 + l16;
        int sel = col / DIM, rem = col % DIM;
        int hh = rem >> 6, cc = rem & 63;
        const float* bias = (sel == 0) ? bq : (sel == 1) ? bk : bv;
        float bval = bias[rem];
        #pragma unroll
        for (int i = 0; i < 4; i++) {
            #pragma unroll
            for (int r = 0; r < 4; r++) {
                int row = mb + wy * 64 + i * 16 + quad * 4 + r;
                unsigned short o = f2bf(acc[i][j][r] + bval);
                if (sel == 0)      Qb[(size_t)(hh * NTOK + row) * HD + cc] = o;
                else if (sel == 1) Kb[(size_t)(hh * NTOK + row) * HD + cc] = o;
                else               Vtb[(size_t)(hh * HD + cc) * NTOK + row] = o;
            }
        }
    }
}

// ---------------------------------------------------------------------------
// Rel-pos bias via MFMA (outputs pre-scaled by log2 e).
// relW emitted as bf16 (k_attn reads it directly from global); relH
// stays f32 (staged+converted into k_attn's small rhs LDS buffer).
// ---------------------------------------------------------------------------
__global__ __launch_bounds__(256) void k_relmm(
    const ushort_t* __restrict__ Qb, const ushort_t* __restrict__ rphb,
    const ushort_t* __restrict__ rpwb, float* __restrict__ relH,
    ushort_t* __restrict__ relWb) {
    int id = blockIdx.x * 4 + (threadIdx.x >> 6);
    int lane = threadIdx.x & 63, quad = lane >> 4, l16 = lane & 15;
    bool isW = id >= 576;
    int t = isW ? id - 576 : id;
    int h = t / GRD, g = t % GRD;
    const ushort_t* tab = isW ? rpwb : rphb;

    f32x4 zero = {0.f, 0.f, 0.f, 0.f};
    f32x4 acc[3][3];
    #pragma unroll
    for (int i = 0; i < 3; i++)
        #pragma unroll
        for (int j = 0; j < 3; j++) acc[i][j] = zero;

    bf16x8 bfr[3][2];
    #pragma unroll
    for (int ct = 0; ct < 3; ct++) {
        int trow = g + 47 - (ct * 16 + l16);
        bfr[ct][0] = *(const bf16x8*)&tab[(size_t)trow * HD + quad * 8];
        bfr[ct][1] = *(const bf16x8*)&tab[(size_t)trow * HD + 32 + quad * 8];
    }
    #pragma unroll
    for (int ms = 0; ms < 3; ms++) {
        int m = ms * 16 + l16;
        int n = isW ? m * GRD + g : g * GRD + m;
        bf16x8 a0 = *(const bf16x8*)&Qb[(size_t)(h * NTOK + n) * HD + quad * 8];
        bf16x8 a1 = *(const bf16x8*)&Qb[(size_t)(h * NTOK + n) * HD + 32 + quad * 8];
        #pragma unroll
        for (int ct = 0; ct < 3; ct++) {
            acc[ms][ct] = __builtin_amdgcn_mfma_f32_16x16x32_bf16(a0, bfr[ct][0], acc[ms][ct], 0, 0, 0);
            acc[ms][ct] = __builtin_amdgcn_mfma_f32_16x16x32_bf16(a1, bfr[ct][1], acc[ms][ct], 0, 0, 0);
        }
    }
    #pragma unroll
    for (int ms = 0; ms < 3; ms++) {
        #pragma unroll
        for (int ct = 0; ct < 3; ct++) {
            #pragma unroll
            for (int r = 0; r < 4; r++) {
                int m = ms * 16 + quad * 4 + r;
                int n = isW ? m * GRD + g : g * GRD + m;
                int col = ct * 16 + l16;
                float val = acc[ms][ct][r] * LOG2E;
                if (isW)
                    relWb[(size_t)(h * NTOK + n) * GRD + col] = f2bf(val);
                else
                    relH[(size_t)(h * NTOK + n) * GRD + col] = val;
            }
        }
    }
}

// ---------------------------------------------------------------------------
// Flash attention, split-K. Block = (128 q-rows, head, chunk of 768 keys).
// Grid 648 <= 768 capacity (3 blk/CU at (256,3)): single-phase.
// K/V 1-deep reg prefetch (issued post-barrier#2, full compute-phase cover);
// relW 1 kt ahead (ping-pong regs, also post-barrier#2) — barrier#1's
// vmcnt(0) drain only sees loads >= one full iteration old.
// ---------------------------------------------------------------------------
__global__ __launch_bounds__(256, 3) void k_attn(
    const ushort_t* __restrict__ Qb, const ushort_t* __restrict__ Kb,
    const ushort_t* __restrict__ Vtb, const float* __restrict__ relH,
    const ushort_t* __restrict__ relWb, float* __restrict__ Opart,
    float* __restrict__ Lpart) {
    int h = blockIdx.x / CHUNKS, chunk = blockIdx.x - h * CHUNKS;
    int qt = blockIdx.y;
    int tid = threadIdx.x;
    int wave = tid >> 6, lane = tid & 63, quad = lane >> 4, l16 = lane & 15;
    int qbase = qt * 128;
    int kbase = chunk * KEYS_PER_CHUNK;

    __shared__ __align__(16) ushort_t Ks[64 * 68];
    __shared__ __align__(16) ushort_t Vs[64 * 68];
    __shared__ __align__(16) ushort_t Ps[4][32 * 68];
    __shared__ __align__(16) ushort_t rhs[128 * 18];

    for (int i = tid; i < 128 * 16; i += 256) {
        int r = i >> 4, c = i & 15;
        rhs[r * 18 + c] = f2bf(relH[(size_t)(h * NTOK + qbase + r) * GRD + chunk * 16 + c]);
    }

    bf16x8 qf[2][2];
    #pragma unroll
    for (int s = 0; s < 2; s++) {
        int qrow = qbase + wave * 32 + s * 16 + l16;
        qf[s][0] = *(const bf16x8*)&Qb[(size_t)(h * NTOK + qrow) * HD + quad * 8];
        qf[s][1] = *(const bf16x8*)&Qb[(size_t)(h * NTOK + qrow) * HD + 32 + quad * 8];
    }

    int r0 = tid >> 3, c0 = (tid & 7) * 8;
    const ushort_t* kg0 = Kb + (size_t)(h * NTOK + r0) * HD + c0;
    const ushort_t* kg1 = Kb + (size_t)(h * NTOK + r0 + 32) * HD + c0;
    const ushort_t* vg0 = Vtb + (size_t)(h * HD + r0) * NTOK + c0;
    const ushort_t* vg1 = Vtb + (size_t)(h * HD + r0 + 32) * NTOK + c0;
    int sk0 = r0 * 68 + c0, sk1 = sk0 + 32 * 68;

    // per-lane relW row pointers (rows owned by this lane across s=0,1)
    const ushort_t* rw0 = relWb + (size_t)(h * NTOK + qbase + wave * 32 + l16) * GRD;
    const ushort_t* rw1 = rw0 + (size_t)16 * GRD;

    float lacc[2] = {0.f, 0.f};
    f32x4 zero = {0.f, 0.f, 0.f, 0.f};
    f32x4 oacc[2][4];
    #pragma unroll
    for (int s = 0; s < 2; s++)
        #pragma unroll
        for (int cs = 0; cs < 4; cs++) oacc[s][cs] = zero;

    const float scale2 = 0.125f * LOG2E;

    // prologue: K/V for kt=0, relW for kt=0 (one-time exposed latency)
    uint4 rk0 = *(const uint4*)(kg0 + (size_t)kbase * HD);
    uint4 rk1 = *(const uint4*)(kg1 + (size_t)kbase * HD);
    uint4 rv0 = *(const uint4*)(vg0 + kbase);
    uint4 rv1 = *(const uint4*)(vg1 + kbase);

    uint2 rwvA[2][4], rwvB[2][4];
    #pragma unroll
    for (int ks = 0; ks < 4; ks++) {
        int kb4 = kbase + ks * 16 + quad * 4;
        int kh = kb4 / 48;
        int kw0 = kb4 - kh * 48;
        rwvA[0][ks] = *(const uint2*)(rw0 + kw0);
        rwvA[1][ks] = *(const uint2*)(rw1 + kw0);
    }

    // one kt iteration; rwvC = current (already loaded), rwvN = fill for kt+1
    auto kt_body = [&](int kt, uint2 (&rwvC)[2][4], uint2 (&rwvN)[2][4]) {
        int kb = kbase + kt * 64;

        __syncthreads();
        *(uint4*)&Ks[sk0] = rk0;  *(uint4*)&Ks[sk1] = rk1;
        *(uint4*)&Vs[sk0] = rv0;  *(uint4*)&Vs[sk1] = rv1;
        __syncthreads();

        if (kt + 1 < KT_PER) {
            int kbn = kb + 64;
            // K/V for kt+1 (full S+PV phase to land before next barrier#1)
            rk0 = *(const uint4*)(kg0 + (size_t)kbn * HD);
            rk1 = *(const uint4*)(kg1 + (size_t)kbn * HD);
            rv0 = *(const uint4*)(vg0 + kbn);
            rv1 = *(const uint4*)(vg1 + kbn);
            // relW for kt+1 (same cover; consumed in next iteration's softmax)
            #pragma unroll
            for (int ks = 0; ks < 4; ks++) {
                int kb4 = kbn + ks * 16 + quad * 4;
                int kh = kb4 / 48;
                int kw0 = kb4 - kh * 48;
                rwvN[0][ks] = *(const uint2*)(rw0 + kw0);
                rwvN[1][ks] = *(const uint2*)(rw1 + kw0);
            }
        }

        #pragma unroll
        for (int ks = 0; ks < 4; ks++) {
            bf16x8 kf0 = *(const bf16x8*)&Ks[(ks * 16 + l16) * 68 + quad * 8];
            bf16x8 kf1 = *(const bf16x8*)&Ks[(ks * 16 + l16) * 68 + 32 + quad * 8];
            f32x4 st[2];
            #pragma unroll
            for (int s = 0; s < 2; s++) {
                f32x4 z = zero;
                z = __builtin_amdgcn_mfma_f32_16x16x32_bf16(kf0, qf[s][0], z, 0, 0, 0);
                z = __builtin_amdgcn_mfma_f32_16x16x32_bf16(kf1, qf[s][1], z, 0, 0, 0);
                st[s] = z;
            }
            int kb4 = kb + ks * 16 + quad * 4;
            int khl = kb4 / 48 - chunk * 16;
            #pragma unroll
            for (int s = 0; s < 2; s++) {
                int row = wave * 32 + s * 16 + l16;
                float rh = bf2f(rhs[row * 18 + khl]);
                uint2 u = rwvC[s][ks];
                float p0 = __builtin_amdgcn_exp2f(st[s][0] * scale2 + rh + __uint_as_float(u.x << 16));
                float p1 = __builtin_amdgcn_exp2f(st[s][1] * scale2 + rh + __uint_as_float(u.x & 0xffff0000u));
                float p2 = __builtin_amdgcn_exp2f(st[s][2] * scale2 + rh + __uint_as_float(u.y << 16));
                float p3 = __builtin_amdgcn_exp2f(st[s][3] * scale2 + rh + __uint_as_float(u.y & 0xffff0000u));
                lacc[s] += (p0 + p1) + (p2 + p3);
                uint2 w;
                w.x = __builtin_amdgcn_perm(__float_as_uint(p1), __float_as_uint(p0), 0x07060302u);
                w.y = __builtin_amdgcn_perm(__float_as_uint(p3), __float_as_uint(p2), 0x07060302u);
                *(uint2*)&Ps[wave][(s * 16 + l16) * 68 + ks * 16 + quad * 4] = w;
            }
        }

        bf16x8 vf[4][2];
        #pragma unroll
        for (int cs = 0; cs < 4; cs++) {
            vf[cs][0] = *(const bf16x8*)&Vs[(cs * 16 + l16) * 68 + quad * 8];
            vf[cs][1] = *(const bf16x8*)&Vs[(cs * 16 + l16) * 68 + 32 + quad * 8];
        }
        #pragma unroll
        for (int s = 0; s < 2; s++) {
            bf16x8 pa0 = *(const bf16x8*)&Ps[wave][(s * 16 + l16) * 68 + quad * 8];
            bf16x8 pa1 = *(const bf16x8*)&Ps[wave][(s * 16 + l16) * 68 + 32 + quad * 8];
            #pragma unroll
            for (int cs = 0; cs < 4; cs++) {
                oacc[s][cs] = __builtin_amdgcn_mfma_f32_16x16x32_bf16(pa0, vf[cs][0], oacc[s][cs], 0, 0, 0);
                oacc[s][cs] = __builtin_amdgcn_mfma_f32_16x16x32_bf16(pa1, vf[cs][1], oacc[s][cs], 0, 0, 0);
            }
        }
    };

    #pragma unroll 1
    for (int kt = 0; kt < KT_PER; kt += 2) {
        kt_body(kt,     rwvA, rwvB);
        kt_body(kt + 1, rwvB, rwvA);
    }

    #pragma unroll
    for (int s = 0; s < 2; s++) {
        float l = lacc[s];
        l += __shfl_xor(l, 16);
        l += __shfl_xor(l, 32);
        lacc[s] = l;
    }

    size_t obase = (size_t)(chunk * HEADS + h) * NTOK;
    #pragma unroll
    for (int s = 0; s < 2; s++) {
        #pragma unroll
        for (int cs = 0; cs < 4; cs++) {
            #pragma unroll
            for (int r = 0; r < 4; r++) {
                int row = qbase + wave * 32 + s * 16 + quad * 4 + r;
                Opart[(obase + row) * HD + cs * 16 + l16] = oacc[s][cs][r];
            }
        }
        if (quad == 0)
            Lpart[obase + qbase + wave * 32 + s * 16 + l16] = lacc[s];
    }
}

// ---------------------------------------------------------------------------
// Merge split-K partials: Ob = (sum_ch O) / (sum_ch l), bf16.
// ---------------------------------------------------------------------------
__global__ __launch_bounds__(256) void k_merge(const float* __restrict__ Opart,
                                               const float* __restrict__ Lpart,
                                               ushort_t* __restrict__ Ob) {
    int t = blockIdx.x * 256 + threadIdx.x;
    int e = t * 4;
    int c = e & (HD - 1);
    int row = (e >> 6) % NTOK;
    int h = e / (NTOK * HD);
    const int ostride = HEADS * NTOK * HD;
    float4 s = {0.f, 0.f, 0.f, 0.f};
    float l = 0.f;
    #pragma unroll
    for (int ch = 0; ch < CHUNKS; ch++) {
        float4 v = *(const float4*)&Opart[(size_t)ch * ostride + e];
        s.x += v.x; s.y += v.y; s.z += v.z; s.w += v.w;
        l += Lpart[(size_t)(ch * HEADS + h) * NTOK + row];
    }
    float inv = 1.0f / l;
    ushort4 o = make_ushort4(f2bf(s.x * inv), f2bf(s.y * inv),
                             f2bf(s.z * inv), f2bf(s.w * inv));
    *(ushort4*)&Ob[(size_t)row * DIM + h * HD + c] = o;
}

// ---------------------------------------------------------------------------
// Output projection: 128(M)x64(N) tiles -> 216 blocks, BK=32,
// global_load_lds DMA staging, 12 KB LDS. 2x2 waves: wave = 64 rows x 32 cols.
// ---------------------------------------------------------------------------
__global__ __launch_bounds__(256) void k_gemm_proj(
    const ushort_t* __restrict__ Ob, const ushort_t* __restrict__ WTp,
    const float* __restrict__ bp, float* __restrict__ out) {
    __shared__ __align__(16) ushort_t As[128 * 32];   // 8 KB
    __shared__ __align__(16) ushort_t Bs[64 * 32];    // 4 KB
    int tid = threadIdx.x;
    int wave = tid >> 6, lane = tid & 63, quad = lane >> 4, l16 = lane & 15;
    int wx = wave & 1, wy = wave >> 1;
    int nb = blockIdx.x * 64, mb = blockIdx.y * 128;

    f32x4 zero = {0.f, 0.f, 0.f, 0.f};
    f32x4 acc[4][2];
    #pragma unroll
    for (int i = 0; i < 4; i++)
        #pragma unroll
        for (int j = 0; j < 2; j++) acc[i][j] = zero;

    int rl = lane >> 2;
    int cl = (lane & 3) * 8;
    const ushort_t* gA = Ob + (size_t)(mb + wave * 32 + rl) * DIM + cl;
    const ushort_t* gB = WTp + (size_t)(nb + wave * 16 + rl) * DIM + cl;
    ushort_t* lA = &As[(wave * 32) * 32];
    ushort_t* lB = &Bs[(wave * 16) * 32];

    for (int k0 = 0; k0 < DIM; k0 += 32) {
        __syncthreads();
        gload_lds16(gA + k0,            lA);
        gload_lds16(gA + k0 + 16 * DIM, lA + 16 * 32);
        gload_lds16(gB + k0,            lB);
        __syncthreads();
        bf16x8 af[4], bf[2];
        #pragma unroll
        for (int i = 0; i < 4; i++)
            af[i] = *(const bf16x8*)&As[(wy * 64 + i * 16 + l16) * 32 + quad * 8];
        #pragma unroll
        for (int j = 0; j < 2; j++)
            bf[j] = *(const bf16x8*)&Bs[(wx * 32 + j * 16 + l16) * 32 + quad * 8];
        #pragma unroll
        for (int i = 0; i < 4; i++)
            #pragma unroll
            for (int j = 0; j < 2; j++)
                acc[i][j] = __builtin_amdgcn_mfma_f32_16x16x32_bf16(af[i], bf[j], acc[i][j], 0, 0, 0);
    }

    #pragma unroll
    for (int j = 0; j < 2; j++) {
        int col = nb + wx * 32 + j * 16 + l16;
        float bval = bp[col];
        #pragma unroll
        for (int i = 0; i < 4; i++) {
            #pragma unroll
            for (int r = 0; r < 4; r++) {
                int row = mb + wy * 64 + i * 16 + quad * 4 + r;
                out[(size_t)row * DIM + col] = acc[i][j][r] + bval;
            }
        }
    }
}

// ---------------------------------------------------------------------------
extern "C" void kernel_launch(void* const* d_in, const int* in_sizes, int n_in,
                              void* d_out, int out_size, void* d_ws, size_t ws_size,
                              hipStream_t stream) {
    const float* x   = (const float*)d_in[0];
    const float* Wq  = (const float*)d_in[1];
    const float* bq  = (const float*)d_in[2];
    const float* Wk  = (const float*)d_in[3];
    const float* bk  = (const float*)d_in[4];
    const float* Wv  = (const float*)d_in[5];
    const float* bv  = (const float*)d_in[6];
    const float* Wp  = (const float*)d_in[7];
    const float* bp  = (const float*)d_in[8];
    const float* rph = (const float*)d_in[9];
    const float* rpw = (const float*)d_in[10];
    const float* Aq  = (const float*)d_in[11];
    const float* Bq  = (const float*)d_in[12];
    const float* Ak  = (const float*)d_in[13];
    const float* Bk  = (const float*)d_in[14];
    const float* Av  = (const float*)d_in[15];
    const float* Bv  = (const float*)d_in[16];
    float* out = (float*)d_out;

    char* w = (char*)d_ws;
    size_t off = 0;
    auto carve = [&](size_t bytes) {
        char* p = w + off;
        off += (bytes + 255) & ~(size_t)255;
        return p;
    };
    ushort_t* xb    = (ushort_t*)carve((size_t)NTOK * DIM * 2);
    ushort_t* WT    = (ushort_t*)carve((size_t)4 * DIM * DIM * 2);
    ushort_t* Qb    = (ushort_t*)carve((size_t)HEADS * NTOK * HD * 2);
    ushort_t* Kb    = (ushort_t*)carve((size_t)HEADS * NTOK * HD * 2);
    ushort_t* Vtb   = (ushort_t*)carve((size_t)HEADS * HD * NTOK * 2);
    float*    relH  = (float*)carve((size_t)HEADS * NTOK * GRD * 4);
    ushort_t* relWb = (ushort_t*)carve((size_t)HEADS * NTOK * GRD * 2);
    ushort_t* Ob    = (ushort_t*)carve((size_t)NTOK * DIM * 2);
    float*    Opart = (float*)carve((size_t)CHUNKS * HEADS * NTOK * HD * 4);
    float*    Lpart = (float*)carve((size_t)CHUNKS * HEADS * NTOK * 4);
    ushort_t* rphb  = (ushort_t*)carve((size_t)(2 * GRD - 1) * HD * 2);
    ushort_t* rpwb  = (ushort_t*)carve((size_t)(2 * GRD - 1) * HD * 2);

    k_prep<<<dim3(2304), dim3(256), 0, stream>>>(
        x, xb, rph, rpw, rphb, rpwb,
        Wq, Wk, Wv, Wp, Aq, Bq, Ak, Bk, Av, Bv, WT);
    k_gemm_qkv<<<dim3(36, 18), dim3(256), 0, stream>>>(
        xb, WT, bq, bk, bv, Qb, Kb, Vtb);
    k_relmm<<<dim3(288), dim3(256), 0, stream>>>(
        Qb, rphb, rpwb, relH, relWb);
    k_attn<<<dim3(HEADS * CHUNKS, NTOK / 128), dim3(256), 0, stream>>>(
        Qb, Kb, Vtb, relH, relWb, Opart, Lpart);
    k_merge<<<dim3(HEADS * NTOK * HD / (256 * 4)), dim3(256), 0, stream>>>(
        Opart, Lpart, Ob);
    k_gemm_proj<<<dim3(12, 18), dim3(256), 0, stream>>>(
        Ob, WT + (size_t)3 * DIM * DIM, bp, out);
}

// Round 8
// 189.451 us; speedup vs baseline: 1.1390x; 1.0274x over previous
//
#include <hip/hip_runtime.h>

// ---------------------------------------------------------------------------
// LoRA_Attention: fold LoRA into weights; bf16 MFMA GEMMs; split-K flash
// attention. R16 = R13 with ONE scheduling change (zero extra registers):
// rwv (relW) loads moved from loop-top (fresh at barrier#1's vmcnt(0) ->
// full L2 latency serialized every kt) to AFTER barrier#2, issued BEFORE
// the K/V next-tile loads (softmax then waits vmcnt(4): rwv done, K/V
// still in flight with full S+PV cover). R14/R15 proved the (256,3) arch
// cap ~84-104: any added pipeline state spills (WRITE_SIZE tripwire) —
// this change shortens live ranges instead. CHUNKS=3, 648 blks <= 768 cap.
// ---------------------------------------------------------------------------

#define DIM   768
#define HEADS 12
#define HD    64
#define NTOK  2304
#define RANK  8
#define GRD   48
#define CHUNKS 3
#define KEYS_PER_CHUNK 768
#define KT_PER 12
#define LOG2E 1.44269504088896f

typedef __attribute__((ext_vector_type(8))) short bf16x8;
typedef __attribute__((ext_vector_type(4))) float f32x4;
typedef unsigned short ushort_t;

__device__ __forceinline__ unsigned short f2bf(float x) {
    union { float f; unsigned u; } v; v.f = x;
    unsigned r = v.u + 0x7fffu + ((v.u >> 16) & 1u);
    return (unsigned short)(r >> 16);
}
__device__ __forceinline__ float bf2f(unsigned short h) {
    return __uint_as_float(((unsigned)h) << 16);
}
__device__ __forceinline__ void gload_lds16(const ushort_t* g, ushort_t* l) {
    __builtin_amdgcn_global_load_lds(
        (const __attribute__((address_space(1))) unsigned int*)g,
        (__attribute__((address_space(3))) unsigned int*)l, 16, 0, 0);
}

// ---------------------------------------------------------------------------
// k_prep: fold LoRA into transposed weights (all 2304 blocks) + convert
// x / rel tables to bf16 (blocks < 1740). Independent tasks, one launch.
// ---------------------------------------------------------------------------
__global__ __launch_bounds__(256) void k_prep(
    const float* __restrict__ x, ushort_t* __restrict__ xb,
    const float* __restrict__ rph, const float* __restrict__ rpw,
    ushort_t* __restrict__ rphb, ushort_t* __restrict__ rpwb,
    const float* __restrict__ Wq, const float* __restrict__ Wk,
    const float* __restrict__ Wv, const float* __restrict__ Wp,
    const float* __restrict__ Aq, const float* __restrict__ Bq,
    const float* __restrict__ Ak, const float* __restrict__ Bk,
    const float* __restrict__ Av, const float* __restrict__ Bv,
    ushort_t* __restrict__ WT) {
    int bid = blockIdx.x, tid = threadIdx.x;

    if (bid < 1740) {
        if (bid < 1728) {
            int idx = (bid * 256 + tid) * 4;
            float4 v = *(const float4*)(x + idx);
            ushort4 o = make_ushort4(f2bf(v.x), f2bf(v.y), f2bf(v.z), f2bf(v.w));
            *(ushort4*)(xb + idx) = o;
        } else {
            int e = ((bid - 1728) * 256 + tid) * 4;
            const int TSZ = (2 * GRD - 1) * HD;   // 6080
            if (e < TSZ) {
                float4 v = *(const float4*)(rph + e);
                ushort4 o = make_ushort4(f2bf(v.x), f2bf(v.y), f2bf(v.z), f2bf(v.w));
                *(ushort4*)(rphb + e) = o;
            } else if (e < 2 * TSZ) {
                float4 v = *(const float4*)(rpw + e - TSZ);
                ushort4 o = make_ushort4(f2bf(v.x), f2bf(v.y), f2bf(v.z), f2bf(v.w));
                *(ushort4*)(rpwb + e - TSZ) = o;
            }
        }
    }

    int kb = (bid % 24) * 32;
    int nb = (bid / 24) * 32;
    int sel = nb / DIM, nmod = nb % DIM;
    const float* W = (sel == 0) ? Wq : (sel == 1) ? Wk : (sel == 2) ? Wv : Wp;
    const float* A = (sel == 0) ? Aq : (sel == 1) ? Ak : Av;
    const float* B = (sel == 0) ? Bq : (sel == 1) ? Bk : Bv;
    __shared__ float T[32][33];
    for (int i = tid; i < 1024; i += 256) {
        int kl = i >> 5, nl = i & 31;
        float v = W[(kb + kl) * DIM + nmod + nl];
        if (sel < 3) {
            #pragma unroll
            for (int r = 0; r < RANK; r++)
                v += A[(kb + kl) * RANK + r] * B[r * DIM + nmod + nl];
        }
        T[kl][nl] = v;
    }
    __syncthreads();
    for (int i = tid; i < 1024; i += 256) {
        int nl = i >> 5, kl = i & 31;
        WT[(size_t)(nb + nl) * DIM + kb + kl] = f2bf(T[kl][nl]);
    }
}

// ---------------------------------------------------------------------------
// QKV GEMM: 128(M)x64(N) tiles -> 648 blocks (~2.5/CU, no packing tail),
// BK=32, global_load_lds DMA, 12 KB LDS. Waves 2x2: wave = 64 rows x 32 cols.
// ---------------------------------------------------------------------------
__global__ __launch_bounds__(256) void k_gemm_qkv(
    const ushort_t* __restrict__ xb, const ushort_t* __restrict__ WT,
    const float* __restrict__ bq, const float* __restrict__ bk,
    const float* __restrict__ bv,
    ushort_t* __restrict__ Qb, ushort_t* __restrict__ Kb,
    ushort_t* __restrict__ Vtb) {
    __shared__ __align__(16) ushort_t As[128 * 32];   // 8 KB
    __shared__ __align__(16) ushort_t Bs[64 * 32];    // 4 KB
    int tid = threadIdx.x;
    int wave = tid >> 6, lane = tid & 63, quad = lane >> 4, l16 = lane & 15;
    int wx = wave & 1, wy = wave >> 1;
    int nb = blockIdx.x * 64, mb = blockIdx.y * 128;

    f32x4 zero = {0.f, 0.f, 0.f, 0.f};
    f32x4 acc[4][2];
    #pragma unroll
    for (int i = 0; i < 4; i++)
        #pragma unroll
        for (int j = 0; j < 2; j++) acc[i][j] = zero;

    int rl = lane >> 2;            // 0..15
    int cl = (lane & 3) * 8;       // element col within 32
    const ushort_t* gA = xb + (size_t)(mb + wave * 32 + rl) * DIM + cl;
    const ushort_t* gB = WT + (size_t)(nb + wave * 16 + rl) * DIM + cl;
    ushort_t* lA = &As[(wave * 32) * 32];
    ushort_t* lB = &Bs[(wave * 16) * 32];

    for (int k0 = 0; k0 < DIM; k0 += 32) {
        __syncthreads();
        gload_lds16(gA + k0,            lA);
        gload_lds16(gA + k0 + 16 * DIM, lA + 16 * 32);
        gload_lds16(gB + k0,            lB);
        __syncthreads();
        bf16x8 af[4], bf[2];
        #pragma unroll
        for (int i = 0; i < 4; i++)
            af[i] = *(const bf16x8*)&As[(wy * 64 + i * 16 + l16) * 32 + quad * 8];
        #pragma unroll
        for (int j = 0; j < 2; j++)
            bf[j] = *(const bf16x8*)&Bs[(wx * 32 + j * 16 + l16) * 32 + quad * 8];
        #pragma unroll
        for (int i = 0; i < 4; i++)
            #pragma unroll
            for (int j = 0; j < 2; j++)
                acc[i][j] = __builtin_amdgcn_mfma_f32_16x16x32_bf16(af[i], bf[j], acc[i][j], 0, 0, 0);
    }

    #pragma unroll
    for (int j = 0; j < 2; j++) {
        int col = nb + wx * 32 + j * 16 + l16;
        int sel = col / DIM, rem = col % DIM;
        int hh = rem >> 6, cc = rem & 63;
        const float* bias = (sel == 0) ? bq : (sel == 1) ? bk : bv;
        float bval = bias[rem];
        #pragma unroll
        for (int i = 0; i < 4; i++) {
            #pragma unroll
            for (int r = 0; r < 4; r++) {
                int row = mb + wy * 64 + i * 16 + quad * 4 + r;
                unsigned short o = f2bf(acc[i][j][r] + bval);
                if (sel == 0)      Qb[(size_t)(hh * NTOK + row) * HD + cc] = o;
                else if (sel == 1) Kb[(size_t)(hh * NTOK + row) * HD + cc] = o;
                else               Vtb[(size_t)(hh * HD + cc) * NTOK + row] = o;
            }
        }
    }
}

// ---------------------------------------------------------------------------
// Rel-pos bias via MFMA (outputs pre-scaled by log2 e).
// relW emitted as bf16 (k_attn reads it directly from global); relH
// stays f32 (staged+converted into k_attn's small rhs LDS buffer).
// ---------------------------------------------------------------------------
__global__ __launch_bounds__(256) void k_relmm(
    const ushort_t* __restrict__ Qb, const ushort_t* __restrict__ rphb,
    const ushort_t* __restrict__ rpwb, float* __restrict__ relH,
    ushort_t* __restrict__ relWb) {
    int id = blockIdx.x * 4 + (threadIdx.x >> 6);
    int lane = threadIdx.x & 63, quad = lane >> 4, l16 = lane & 15;
    bool isW = id >= 576;
    int t = isW ? id - 576 : id;
    int h = t / GRD, g = t % GRD;
    const ushort_t* tab = isW ? rpwb : rphb;

    f32x4 zero = {0.f, 0.f, 0.f, 0.f};
    f32x4 acc[3][3];
    #pragma unroll
    for (int i = 0; i < 3; i++)
        #pragma unroll
        for (int j = 0; j < 3; j++) acc[i][j] = zero;

    bf16x8 bfr[3][2];
    #pragma unroll
    for (int ct = 0; ct < 3; ct++) {
        int trow = g + 47 - (ct * 16 + l16);
        bfr[ct][0] = *(const bf16x8*)&tab[(size_t)trow * HD + quad * 8];
        bfr[ct][1] = *(const bf16x8*)&tab[(size_t)trow * HD + 32 + quad * 8];
    }
    #pragma unroll
    for (int ms = 0; ms < 3; ms++) {
        int m = ms * 16 + l16;
        int n = isW ? m * GRD + g : g * GRD + m;
        bf16x8 a0 = *(const bf16x8*)&Qb[(size_t)(h * NTOK + n) * HD + quad * 8];
        bf16x8 a1 = *(const bf16x8*)&Qb[(size_t)(h * NTOK + n) * HD + 32 + quad * 8];
        #pragma unroll
        for (int ct = 0; ct < 3; ct++) {
            acc[ms][ct] = __builtin_amdgcn_mfma_f32_16x16x32_bf16(a0, bfr[ct][0], acc[ms][ct], 0, 0, 0);
            acc[ms][ct] = __builtin_amdgcn_mfma_f32_16x16x32_bf16(a1, bfr[ct][1], acc[ms][ct], 0, 0, 0);
        }
    }
    #pragma unroll
    for (int ms = 0; ms < 3; ms++) {
        #pragma unroll
        for (int ct = 0; ct < 3; ct++) {
            #pragma unroll
            for (int r = 0; r < 4; r++) {
                int m = ms * 16 + quad * 4 + r;
                int n = isW ? m * GRD + g : g * GRD + m;
                int col = ct * 16 + l16;
                float val = acc[ms][ct][r] * LOG2E;
                if (isW)
                    relWb[(size_t)(h * NTOK + n) * GRD + col] = f2bf(val);
                else
                    relH[(size_t)(h * NTOK + n) * GRD + col] = val;
            }
        }
    }
}

// ---------------------------------------------------------------------------
// Flash attention, split-K. Block = (128 q-rows, head, chunk of 768 keys).
// Grid 648 <= 768 capacity (3 blk/CU at (256,3)): single-phase.
// Load schedule per kt: barrier#1 (drains only iteration-old K/V), LDS
// write, barrier#2, rwv issue (8 loads), K/V next-tile issue (4 loads),
// S-MFMA -> softmax waits vmcnt(4): rwv ready, K/V still in flight.
// ---------------------------------------------------------------------------
__global__ __launch_bounds__(256, 3) void k_attn(
    const ushort_t* __restrict__ Qb, const ushort_t* __restrict__ Kb,
    const ushort_t* __restrict__ Vtb, const float* __restrict__ relH,
    const ushort_t* __restrict__ relWb, float* __restrict__ Opart,
    float* __restrict__ Lpart) {
    int h = blockIdx.x / CHUNKS, chunk = blockIdx.x - h * CHUNKS;
    int qt = blockIdx.y;
    int tid = threadIdx.x;
    int wave = tid >> 6, lane = tid & 63, quad = lane >> 4, l16 = lane & 15;
    int qbase = qt * 128;
    int kbase = chunk * KEYS_PER_CHUNK;

    __shared__ __align__(16) ushort_t Ks[64 * 68];
    __shared__ __align__(16) ushort_t Vs[64 * 68];
    __shared__ __align__(16) ushort_t Ps[4][32 * 68];
    __shared__ __align__(16) ushort_t rhs[128 * 18];

    for (int i = tid; i < 128 * 16; i += 256) {
        int r = i >> 4, c = i & 15;
        rhs[r * 18 + c] = f2bf(relH[(size_t)(h * NTOK + qbase + r) * GRD + chunk * 16 + c]);
    }

    bf16x8 qf[2][2];
    #pragma unroll
    for (int s = 0; s < 2; s++) {
        int qrow = qbase + wave * 32 + s * 16 + l16;
        qf[s][0] = *(const bf16x8*)&Qb[(size_t)(h * NTOK + qrow) * HD + quad * 8];
        qf[s][1] = *(const bf16x8*)&Qb[(size_t)(h * NTOK + qrow) * HD + 32 + quad * 8];
    }

    int r0 = tid >> 3, c0 = (tid & 7) * 8;
    const ushort_t* kg0 = Kb + (size_t)(h * NTOK + r0) * HD + c0;
    const ushort_t* kg1 = Kb + (size_t)(h * NTOK + r0 + 32) * HD + c0;
    const ushort_t* vg0 = Vtb + (size_t)(h * HD + r0) * NTOK + c0;
    const ushort_t* vg1 = Vtb + (size_t)(h * HD + r0 + 32) * NTOK + c0;
    int sk0 = r0 * 68 + c0, sk1 = sk0 + 32 * 68;

    // per-lane relW row pointers (rows owned by this lane across s=0,1)
    const ushort_t* rw0 = relWb + (size_t)(h * NTOK + qbase + wave * 32 + l16) * GRD;
    const ushort_t* rw1 = rw0 + (size_t)16 * GRD;

    float lacc[2] = {0.f, 0.f};
    f32x4 zero = {0.f, 0.f, 0.f, 0.f};
    f32x4 oacc[2][4];
    #pragma unroll
    for (int s = 0; s < 2; s++)
        #pragma unroll
        for (int cs = 0; cs < 4; cs++) oacc[s][cs] = zero;

    const float scale2 = 0.125f * LOG2E;

    uint4 rk0 = *(const uint4*)(kg0 + (size_t)kbase * HD);
    uint4 rk1 = *(const uint4*)(kg1 + (size_t)kbase * HD);
    uint4 rv0 = *(const uint4*)(vg0 + kbase);
    uint4 rv1 = *(const uint4*)(vg1 + kbase);

    for (int kt = 0; kt < KT_PER; kt++) {
        int kb = kbase + kt * 64;

        __syncthreads();
        *(uint4*)&Ks[sk0] = rk0;  *(uint4*)&Ks[sk1] = rk1;
        *(uint4*)&Vs[sk0] = rv0;  *(uint4*)&Vs[sk1] = rv1;
        __syncthreads();

        // rwv for THIS kt, issued first: softmax's wait is vmcnt(4) so the
        // K/V loads below stay in flight; ~2 ds_reads + 2 MFMAs of cover.
        uint2 rwv[2][4];
        #pragma unroll
        for (int ks = 0; ks < 4; ks++) {
            int kb4 = kb + ks * 16 + quad * 4;
            int kh = kb4 / 48;
            int kw0 = kb4 - kh * 48;
            rwv[0][ks] = *(const uint2*)(rw0 + kw0);
            rwv[1][ks] = *(const uint2*)(rw1 + kw0);
        }

        if (kt < KT_PER - 1) {
            int kbn = kb + 64;
            rk0 = *(const uint4*)(kg0 + (size_t)kbn * HD);
            rk1 = *(const uint4*)(kg1 + (size_t)kbn * HD);
            rv0 = *(const uint4*)(vg0 + kbn);
            rv1 = *(const uint4*)(vg1 + kbn);
        }

        #pragma unroll
        for (int ks = 0; ks < 4; ks++) {
            bf16x8 kf0 = *(const bf16x8*)&Ks[(ks * 16 + l16) * 68 + quad * 8];
            bf16x8 kf1 = *(const bf16x8*)&Ks[(ks * 16 + l16) * 68 + 32 + quad * 8];
            f32x4 st[2];
            #pragma unroll
            for (int s = 0; s < 2; s++) {
                f32x4 z = zero;
                z = __builtin_amdgcn_mfma_f32_16x16x32_bf16(kf0, qf[s][0], z, 0, 0, 0);
                z = __builtin_amdgcn_mfma_f32_16x16x32_bf16(kf1, qf[s][1], z, 0, 0, 0);
                st[s] = z;
            }
            int kb4 = kb + ks * 16 + quad * 4;
            int khl = kb4 / 48 - chunk * 16;
            #pragma unroll
            for (int s = 0; s < 2; s++) {
                int row = wave * 32 + s * 16 + l16;
                float rh = bf2f(rhs[row * 18 + khl]);
                uint2 u = rwv[s][ks];
                float p0 = __builtin_amdgcn_exp2f(st[s][0] * scale2 + rh + __uint_as_float(u.x << 16));
                float p1 = __builtin_amdgcn_exp2f(st[s][1] * scale2 + rh + __uint_as_float(u.x & 0xffff0000u));
                float p2 = __builtin_amdgcn_exp2f(st[s][2] * scale2 + rh + __uint_as_float(u.y << 16));
                float p3 = __builtin_amdgcn_exp2f(st[s][3] * scale2 + rh + __uint_as_float(u.y & 0xffff0000u));
                lacc[s] += (p0 + p1) + (p2 + p3);
                uint2 w;
                w.x = __builtin_amdgcn_perm(__float_as_uint(p1), __float_as_uint(p0), 0x07060302u);
                w.y = __builtin_amdgcn_perm(__float_as_uint(p3), __float_as_uint(p2), 0x07060302u);
                *(uint2*)&Ps[wave][(s * 16 + l16) * 68 + ks * 16 + quad * 4] = w;
            }
        }

        bf16x8 vf[4][2];
        #pragma unroll
        for (int cs = 0; cs < 4; cs++) {
            vf[cs][0] = *(const bf16x8*)&Vs[(cs * 16 + l16) * 68 + quad * 8];
            vf[cs][1] = *(const bf16x8*)&Vs[(cs * 16 + l16) * 68 + 32 + quad * 8];
        }
        #pragma unroll
        for (int s = 0; s < 2; s++) {
            bf16x8 pa0 = *(const bf16x8*)&Ps[wave][(s * 16 + l16) * 68 + quad * 8];
            bf16x8 pa1 = *(const bf16x8*)&Ps[wave][(s * 16 + l16) * 68 + 32 + quad * 8];
            #pragma unroll
            for (int cs = 0; cs < 4; cs++) {
                oacc[s][cs] = __builtin_amdgcn_mfma_f32_16x16x32_bf16(pa0, vf[cs][0], oacc[s][cs], 0, 0, 0);
                oacc[s][cs] = __builtin_amdgcn_mfma_f32_16x16x32_bf16(pa1, vf[cs][1], oacc[s][cs], 0, 0, 0);
            }
        }
    }

    #pragma unroll
    for (int s = 0; s < 2; s++) {
        float l = lacc[s];
        l += __shfl_xor(l, 16);
        l += __shfl_xor(l, 32);
        lacc[s] = l;
    }

    size_t obase = (size_t)(chunk * HEADS + h) * NTOK;
    #pragma unroll
    for (int s = 0; s < 2; s++) {
        #pragma unroll
        for (int cs = 0; cs < 4; cs++) {
            #pragma unroll
            for (int r = 0; r < 4; r++) {
                int row = qbase + wave * 32 + s * 16 + quad * 4 + r;
                Opart[(obase + row) * HD + cs * 16 + l16] = oacc[s][cs][r];
            }
        }
        if (quad == 0)
            Lpart[obase + qbase + wave * 32 + s * 16 + l16] = lacc[s];
    }
}

// ---------------------------------------------------------------------------
// Merge split-K partials: Ob = (sum_ch O) / (sum_ch l), bf16.
// ---------------------------------------------------------------------------
__global__ __launch_bounds__(256) void k_merge(const float* __restrict__ Opart,
                                               const float* __restrict__ Lpart,
                                               ushort_t* __restrict__ Ob) {
    int t = blockIdx.x * 256 + threadIdx.x;
    int e = t * 4;
    int c = e & (HD - 1);
    int row = (e >> 6) % NTOK;
    int h = e / (NTOK * HD);
    const int ostride = HEADS * NTOK * HD;
    float4 s = {0.f, 0.f, 0.f, 0.f};
    float l = 0.f;
    #pragma unroll
    for (int ch = 0; ch < CHUNKS; ch++) {
        float4 v = *(const float4*)&Opart[(size_t)ch * ostride + e];
        s.x += v.x; s.y += v.y; s.z += v.z; s.w += v.w;
        l += Lpart[(size_t)(ch * HEADS + h) * NTOK + row];
    }
    float inv = 1.0f / l;
    ushort4 o = make_ushort4(f2bf(s.x * inv), f2bf(s.y * inv),
                             f2bf(s.z * inv), f2bf(s.w * inv));
    *(ushort4*)&Ob[(size_t)row * DIM + h * HD + c] = o;
}

// ---------------------------------------------------------------------------
// Output projection: 128(M)x64(N) tiles -> 216 blocks, BK=32,
// global_load_lds DMA staging, 12 KB LDS. 2x2 waves: wave = 64 rows x 32 cols.
// ---------------------------------------------------------------------------
__global__ __launch_bounds__(256) void k_gemm_proj(
    const ushort_t* __restrict__ Ob, const ushort_t* __restrict__ WTp,
    const float* __restrict__ bp, float* __restrict__ out) {
    __shared__ __align__(16) ushort_t As[128 * 32];   // 8 KB
    __shared__ __align__(16) ushort_t Bs[64 * 32];    // 4 KB
    int tid = threadIdx.x;
    int wave = tid >> 6, lane = tid & 63, quad = lane >> 4, l16 = lane & 15;
    int wx = wave & 1, wy = wave >> 1;
    int nb = blockIdx.x * 64, mb = blockIdx.y * 128;

    f32x4 zero = {0.f, 0.f, 0.f, 0.f};
    f32x4 acc[4][2];
    #pragma unroll
    for (int i = 0; i < 4; i++)
        #pragma unroll
        for (int j = 0; j < 2; j++) acc[i][j] = zero;

    int rl = lane >> 2;
    int cl = (lane & 3) * 8;
    const ushort_t* gA = Ob + (size_t)(mb + wave * 32 + rl) * DIM + cl;
    const ushort_t* gB = WTp + (size_t)(nb + wave * 16 + rl) * DIM + cl;
    ushort_t* lA = &As[(wave * 32) * 32];
    ushort_t* lB = &Bs[(wave * 16) * 32];

    for (int k0 = 0; k0 < DIM; k0 += 32) {
        __syncthreads();
        gload_lds16(gA + k0,            lA);
        gload_lds16(gA + k0 + 16 * DIM, lA + 16 * 32);
        gload_lds16(gB + k0,            lB);
        __syncthreads();
        bf16x8 af[4], bf[2];
        #pragma unroll
        for (int i = 0; i < 4; i++)
            af[i] = *(const bf16x8*)&As[(wy * 64 + i * 16 + l16) * 32 + quad * 8];
        #pragma unroll
        for (int j = 0; j < 2; j++)
            bf[j] = *(const bf16x8*)&Bs[(wx * 32 + j * 16 + l16) * 32 + quad * 8];
        #pragma unroll
        for (int i = 0; i < 4; i++)
            #pragma unroll
            for (int j = 0; j < 2; j++)
                acc[i][j] = __builtin_amdgcn_mfma_f32_16x16x32_bf16(af[i], bf[j], acc[i][j], 0, 0, 0);
    }

    #pragma unroll
    for (int j = 0; j < 2; j++) {
        int col = nb + wx * 32 + j * 16 + l16;
        float bval = bp[col];
        #pragma unroll
        for (int i = 0; i < 4; i++) {
            #pragma unroll
            for (int r = 0; r < 4; r++) {
                int row = mb + wy * 64 + i * 16 + quad * 4 + r;
                out[(size_t)row * DIM + col] = acc[i][j][r] + bval;
            }
        }
    }
}

// ---------------------------------------------------------------------------
extern "C" void kernel_launch(void* const* d_in, const int* in_sizes, int n_in,
                              void* d_out, int out_size, void* d_ws, size_t ws_size,
                              hipStream_t stream) {
    const float* x   = (const float*)d_in[0];
    const float* Wq  = (const float*)d_in[1];
    const float* bq  = (const float*)d_in[2];
    const float* Wk  = (const float*)d_in[3];
    const float* bk  = (const float*)d_in[4];
    const float* Wv  = (const float*)d_in[5];
    const float* bv  = (const float*)d_in[6];
    const float* Wp  = (const float*)d_in[7];
    const float* bp  = (const float*)d_in[8];
    const float* rph = (const float*)d_in[9];
    const float* rpw = (const float*)d_in[10];
    const float* Aq  = (const float*)d_in[11];
    const float* Bq  = (const float*)d_in[12];
    const float* Ak  = (const float*)d_in[13];
    const float* Bk  = (const float*)d_in[14];
    const float* Av  = (const float*)d_in[15];
    const float* Bv  = (const float*)d_in[16];
    float* out = (float*)d_out;

    char* w = (char*)d_ws;
    size_t off = 0;
    auto carve = [&](size_t bytes) {
        char* p = w + off;
        off += (bytes + 255) & ~(size_t)255;
        return p;
    };
    ushort_t* xb    = (ushort_t*)carve((size_t)NTOK * DIM * 2);
    ushort_t* WT    = (ushort_t*)carve((size_t)4 * DIM * DIM * 2);
    ushort_t* Qb    = (ushort_t*)carve((size_t)HEADS * NTOK * HD * 2);
    ushort_t* Kb    = (ushort_t*)carve((size_t)HEADS * NTOK * HD * 2);
    ushort_t* Vtb   = (ushort_t*)carve((size_t)HEADS * HD * NTOK * 2);
    float*    relH  = (float*)carve((size_t)HEADS * NTOK * GRD * 4);
    ushort_t* relWb = (ushort_t*)carve((size_t)HEADS * NTOK * GRD * 2);
    ushort_t* Ob    = (ushort_t*)carve((size_t)NTOK * DIM * 2);
    float*    Opart = (float*)carve((size_t)CHUNKS * HEADS * NTOK * HD * 4);
    float*    Lpart = (float*)carve((size_t)CHUNKS * HEADS * NTOK * 4);
    ushort_t* rphb  = (ushort_t*)carve((size_t)(2 * GRD - 1) * HD * 2);
    ushort_t* rpwb  = (ushort_t*)carve((size_t)(2 * GRD - 1) * HD * 2);

    k_prep<<<dim3(2304), dim3(256), 0, stream>>>(
        x, xb, rph, rpw, rphb, rpwb,
        Wq, Wk, Wv, Wp, Aq, Bq, Ak, Bk, Av, Bv, WT);
    k_gemm_qkv<<<dim3(36, 18), dim3(256), 0, stream>>>(
        xb, WT, bq, bk, bv, Qb, Kb, Vtb);
    k_relmm<<<dim3(288), dim3(256), 0, stream>>>(
        Qb, rphb, rpwb, relH, relWb);
    k_attn<<<dim3(HEADS * CHUNKS, NTOK / 128), dim3(256), 0, stream>>>(
        Qb, Kb, Vtb, relH, relWb, Opart, Lpart);
    k_merge<<<dim3(HEADS * NTOK * HD / (256 * 4)), dim3(256), 0, stream>>>(
        Opart, Lpart, Ob);
    k_gemm_proj<<<dim3(12, 18), dim3(256), 0, stream>>>(
        Ob, WT + (size_t)3 * DIM * DIM, bp, out);
}

// Round 9
// 189.288 us; speedup vs baseline: 1.1400x; 1.0009x over previous
//
#include <hip/hip_runtime.h>

// ---------------------------------------------------------------------------
// LoRA_Attention: fold LoRA into weights; bf16 MFMA GEMMs; split-K flash
// attention. R17: k_attn frozen at the R13/R16 plateau (45.2us; latency
// theories exhausted — walls: ~104 arch-VGPR cap at (256,3), no LDS room
// for dbuf at residency 3). This round attacks the GEMMs: BK 32 -> 64 in
// k_gemm_qkv / k_gemm_proj via TWO 32-col LDS planes (keeps the proven
// conflict-free 64B-stride reads + linear gload_lds staging; a flat
// [row][64] layout would be the m201 16-way-conflict case). Halves the
// barrier count (48->24), doubles DMA in flight per vmcnt(0) drain.
// Accumulation order bitwise identical to BK=32 (plane0=old k0, plane1=
// old k0+32) -> absmax must stay exactly 0.0004882812.
// ---------------------------------------------------------------------------

#define DIM   768
#define HEADS 12
#define HD    64
#define NTOK  2304
#define RANK  8
#define GRD   48
#define CHUNKS 3
#define KEYS_PER_CHUNK 768
#define KT_PER 12
#define LOG2E 1.44269504088896f

typedef __attribute__((ext_vector_type(8))) short bf16x8;
typedef __attribute__((ext_vector_type(4))) float f32x4;
typedef unsigned short ushort_t;

__device__ __forceinline__ unsigned short f2bf(float x) {
    union { float f; unsigned u; } v; v.f = x;
    unsigned r = v.u + 0x7fffu + ((v.u >> 16) & 1u);
    return (unsigned short)(r >> 16);
}
__device__ __forceinline__ float bf2f(unsigned short h) {
    return __uint_as_float(((unsigned)h) << 16);
}
__device__ __forceinline__ void gload_lds16(const ushort_t* g, ushort_t* l) {
    __builtin_amdgcn_global_load_lds(
        (const __attribute__((address_space(1))) unsigned int*)g,
        (__attribute__((address_space(3))) unsigned int*)l, 16, 0, 0);
}

// ---------------------------------------------------------------------------
// k_prep: fold LoRA into transposed weights (all 2304 blocks) + convert
// x / rel tables to bf16 (blocks < 1740). Independent tasks, one launch.
// ---------------------------------------------------------------------------
__global__ __launch_bounds__(256) void k_prep(
    const float* __restrict__ x, ushort_t* __restrict__ xb,
    const float* __restrict__ rph, const float* __restrict__ rpw,
    ushort_t* __restrict__ rphb, ushort_t* __restrict__ rpwb,
    const float* __restrict__ Wq, const float* __restrict__ Wk,
    const float* __restrict__ Wv, const float* __restrict__ Wp,
    const float* __restrict__ Aq, const float* __restrict__ Bq,
    const float* __restrict__ Ak, const float* __restrict__ Bk,
    const float* __restrict__ Av, const float* __restrict__ Bv,
    ushort_t* __restrict__ WT) {
    int bid = blockIdx.x, tid = threadIdx.x;

    if (bid < 1740) {
        if (bid < 1728) {
            int idx = (bid * 256 + tid) * 4;
            float4 v = *(const float4*)(x + idx);
            ushort4 o = make_ushort4(f2bf(v.x), f2bf(v.y), f2bf(v.z), f2bf(v.w));
            *(ushort4*)(xb + idx) = o;
        } else {
            int e = ((bid - 1728) * 256 + tid) * 4;
            const int TSZ = (2 * GRD - 1) * HD;   // 6080
            if (e < TSZ) {
                float4 v = *(const float4*)(rph + e);
                ushort4 o = make_ushort4(f2bf(v.x), f2bf(v.y), f2bf(v.z), f2bf(v.w));
                *(ushort4*)(rphb + e) = o;
            } else if (e < 2 * TSZ) {
                float4 v = *(const float4*)(rpw + e - TSZ);
                ushort4 o = make_ushort4(f2bf(v.x), f2bf(v.y), f2bf(v.z), f2bf(v.w));
                *(ushort4*)(rpwb + e - TSZ) = o;
            }
        }
    }

    int kb = (bid % 24) * 32;
    int nb = (bid / 24) * 32;
    int sel = nb / DIM, nmod = nb % DIM;
    const float* W = (sel == 0) ? Wq : (sel == 1) ? Wk : (sel == 2) ? Wv : Wp;
    const float* A = (sel == 0) ? Aq : (sel == 1) ? Ak : Av;
    const float* B = (sel == 0) ? Bq : (sel == 1) ? Bk : Bv;
    __shared__ float T[32][33];
    for (int i = tid; i < 1024; i += 256) {
        int kl = i >> 5, nl = i & 31;
        float v = W[(kb + kl) * DIM + nmod + nl];
        if (sel < 3) {
            #pragma unroll
            for (int r = 0; r < RANK; r++)
                v += A[(kb + kl) * RANK + r] * B[r * DIM + nmod + nl];
        }
        T[kl][nl] = v;
    }
    __syncthreads();
    for (int i = tid; i < 1024; i += 256) {
        int nl = i >> 5, kl = i & 31;
        WT[(size_t)(nb + nl) * DIM + kb + kl] = f2bf(T[kl][nl]);
    }
}

// ---------------------------------------------------------------------------
// QKV GEMM: 128(M)x64(N) tiles -> 648 blocks, BK=64 via two 32-col LDS
// planes (24 KB, ~6 blk/CU): 12 k-steps, 24 barriers (was 48), 6 DMA in
// flight per drain. Waves 2x2: wave = 64 rows x 32 cols.
// ---------------------------------------------------------------------------
__global__ __launch_bounds__(256) void k_gemm_qkv(
    const ushort_t* __restrict__ xb, const ushort_t* __restrict__ WT,
    const float* __restrict__ bq, const float* __restrict__ bk,
    const float* __restrict__ bv,
    ushort_t* __restrict__ Qb, ushort_t* __restrict__ Kb,
    ushort_t* __restrict__ Vtb) {
    __shared__ __align__(16) ushort_t As[2][128 * 32];   // 8 KB x2
    __shared__ __align__(16) ushort_t Bs[2][64 * 32];    // 4 KB x2
    int tid = threadIdx.x;
    int wave = tid >> 6, lane = tid & 63, quad = lane >> 4, l16 = lane & 15;
    int wx = wave & 1, wy = wave >> 1;
    int nb = blockIdx.x * 64, mb = blockIdx.y * 128;

    f32x4 zero = {0.f, 0.f, 0.f, 0.f};
    f32x4 acc[4][2];
    #pragma unroll
    for (int i = 0; i < 4; i++)
        #pragma unroll
        for (int j = 0; j < 2; j++) acc[i][j] = zero;

    int rl = lane >> 2;            // 0..15
    int cl = (lane & 3) * 8;       // element col within 32
    const ushort_t* gA = xb + (size_t)(mb + wave * 32 + rl) * DIM + cl;
    const ushort_t* gB = WT + (size_t)(nb + wave * 16 + rl) * DIM + cl;
    ushort_t* lA0 = &As[0][(wave * 32) * 32];
    ushort_t* lA1 = &As[1][(wave * 32) * 32];
    ushort_t* lB0 = &Bs[0][(wave * 16) * 32];
    ushort_t* lB1 = &Bs[1][(wave * 16) * 32];

    for (int k0 = 0; k0 < DIM; k0 += 64) {
        __syncthreads();
        gload_lds16(gA + k0,                 lA0);
        gload_lds16(gA + k0 + 16 * DIM,      lA0 + 16 * 32);
        gload_lds16(gA + k0 + 32,            lA1);
        gload_lds16(gA + k0 + 32 + 16 * DIM, lA1 + 16 * 32);
        gload_lds16(gB + k0,                 lB0);
        gload_lds16(gB + k0 + 32,            lB1);
        __syncthreads();
        #pragma unroll
        for (int p = 0; p < 2; p++) {
            bf16x8 af[4], bf[2];
            #pragma unroll
            for (int i = 0; i < 4; i++)
                af[i] = *(const bf16x8*)&As[p][(wy * 64 + i * 16 + l16) * 32 + quad * 8];
            #pragma unroll
            for (int j = 0; j < 2; j++)
                bf[j] = *(const bf16x8*)&Bs[p][(wx * 32 + j * 16 + l16) * 32 + quad * 8];
            #pragma unroll
            for (int i = 0; i < 4; i++)
                #pragma unroll
                for (int j = 0; j < 2; j++)
                    acc[i][j] = __builtin_amdgcn_mfma_f32_16x16x32_bf16(af[i], bf[j], acc[i][j], 0, 0, 0);
        }
    }

    #pragma unroll
    for (int j = 0; j < 2; j++) {
        int col = nb + wx * 32 + j * 16 + l16;
        int sel = col / DIM, rem = col % DIM;
        int hh = rem >> 6, cc = rem & 63;
        const float* bias = (sel == 0) ? bq : (sel == 1) ? bk : bv;
        float bval = bias[rem];
        #pragma unroll
        for (int i = 0; i < 4; i++) {
            #pragma unroll
            for (int r = 0; r < 4; r++) {
                int row = mb + wy * 64 + i * 16 + quad * 4 + r;
                unsigned short o = f2bf(acc[i][j][r] + bval);
                if (sel == 0)      Qb[(size_t)(hh * NTOK + row) * HD + cc] = o;
                else if (sel == 1) Kb[(size_t)(hh * NTOK + row) * HD + cc] = o;
                else               Vtb[(size_t)(hh * HD + cc) * NTOK + row] = o;
            }
        }
    }
}

// ---------------------------------------------------------------------------
// Rel-pos bias via MFMA (outputs pre-scaled by log2 e).
// relW emitted as bf16 (k_attn reads it directly from global); relH
// stays f32 (staged+converted into k_attn's small rhs LDS buffer).
// ---------------------------------------------------------------------------
__global__ __launch_bounds__(256) void k_relmm(
    const ushort_t* __restrict__ Qb, const ushort_t* __restrict__ rphb,
    const ushort_t* __restrict__ rpwb, float* __restrict__ relH,
    ushort_t* __restrict__ relWb) {
    int id = blockIdx.x * 4 + (threadIdx.x >> 6);
    int lane = threadIdx.x & 63, quad = lane >> 4, l16 = lane & 15;
    bool isW = id >= 576;
    int t = isW ? id - 576 : id;
    int h = t / GRD, g = t % GRD;
    const ushort_t* tab = isW ? rpwb : rphb;

    f32x4 zero = {0.f, 0.f, 0.f, 0.f};
    f32x4 acc[3][3];
    #pragma unroll
    for (int i = 0; i < 3; i++)
        #pragma unroll
        for (int j = 0; j < 3; j++) acc[i][j] = zero;

    bf16x8 bfr[3][2];
    #pragma unroll
    for (int ct = 0; ct < 3; ct++) {
        int trow = g + 47 - (ct * 16 + l16);
        bfr[ct][0] = *(const bf16x8*)&tab[(size_t)trow * HD + quad * 8];
        bfr[ct][1] = *(const bf16x8*)&tab[(size_t)trow * HD + 32 + quad * 8];
    }
    #pragma unroll
    for (int ms = 0; ms < 3; ms++) {
        int m = ms * 16 + l16;
        int n = isW ? m * GRD + g : g * GRD + m;
        bf16x8 a0 = *(const bf16x8*)&Qb[(size_t)(h * NTOK + n) * HD + quad * 8];
        bf16x8 a1 = *(const bf16x8*)&Qb[(size_t)(h * NTOK + n) * HD + 32 + quad * 8];
        #pragma unroll
        for (int ct = 0; ct < 3; ct++) {
            acc[ms][ct] = __builtin_amdgcn_mfma_f32_16x16x32_bf16(a0, bfr[ct][0], acc[ms][ct], 0, 0, 0);
            acc[ms][ct] = __builtin_amdgcn_mfma_f32_16x16x32_bf16(a1, bfr[ct][1], acc[ms][ct], 0, 0, 0);
        }
    }
    #pragma unroll
    for (int ms = 0; ms < 3; ms++) {
        #pragma unroll
        for (int ct = 0; ct < 3; ct++) {
            #pragma unroll
            for (int r = 0; r < 4; r++) {
                int m = ms * 16 + quad * 4 + r;
                int n = isW ? m * GRD + g : g * GRD + m;
                int col = ct * 16 + l16;
                float val = acc[ms][ct][r] * LOG2E;
                if (isW)
                    relWb[(size_t)(h * NTOK + n) * GRD + col] = f2bf(val);
                else
                    relH[(size_t)(h * NTOK + n) * GRD + col] = val;
            }
        }
    }
}

// ---------------------------------------------------------------------------
// Flash attention, split-K. Block = (128 q-rows, head, chunk of 768 keys).
// Grid 648 <= 768 capacity (3 blk/CU at (256,3)): single-phase. R16 core.
// ---------------------------------------------------------------------------
__global__ __launch_bounds__(256, 3) void k_attn(
    const ushort_t* __restrict__ Qb, const ushort_t* __restrict__ Kb,
    const ushort_t* __restrict__ Vtb, const float* __restrict__ relH,
    const ushort_t* __restrict__ relWb, float* __restrict__ Opart,
    float* __restrict__ Lpart) {
    int h = blockIdx.x / CHUNKS, chunk = blockIdx.x - h * CHUNKS;
    int qt = blockIdx.y;
    int tid = threadIdx.x;
    int wave = tid >> 6, lane = tid & 63, quad = lane >> 4, l16 = lane & 15;
    int qbase = qt * 128;
    int kbase = chunk * KEYS_PER_CHUNK;

    __shared__ __align__(16) ushort_t Ks[64 * 68];
    __shared__ __align__(16) ushort_t Vs[64 * 68];
    __shared__ __align__(16) ushort_t Ps[4][32 * 68];
    __shared__ __align__(16) ushort_t rhs[128 * 18];

    for (int i = tid; i < 128 * 16; i += 256) {
        int r = i >> 4, c = i & 15;
        rhs[r * 18 + c] = f2bf(relH[(size_t)(h * NTOK + qbase + r) * GRD + chunk * 16 + c]);
    }

    bf16x8 qf[2][2];
    #pragma unroll
    for (int s = 0; s < 2; s++) {
        int qrow = qbase + wave * 32 + s * 16 + l16;
        qf[s][0] = *(const bf16x8*)&Qb[(size_t)(h * NTOK + qrow) * HD + quad * 8];
        qf[s][1] = *(const bf16x8*)&Qb[(size_t)(h * NTOK + qrow) * HD + 32 + quad * 8];
    }

    int r0 = tid >> 3, c0 = (tid & 7) * 8;
    const ushort_t* kg0 = Kb + (size_t)(h * NTOK + r0) * HD + c0;
    const ushort_t* kg1 = Kb + (size_t)(h * NTOK + r0 + 32) * HD + c0;
    const ushort_t* vg0 = Vtb + (size_t)(h * HD + r0) * NTOK + c0;
    const ushort_t* vg1 = Vtb + (size_t)(h * HD + r0 + 32) * NTOK + c0;
    int sk0 = r0 * 68 + c0, sk1 = sk0 + 32 * 68;

    // per-lane relW row pointers (rows owned by this lane across s=0,1)
    const ushort_t* rw0 = relWb + (size_t)(h * NTOK + qbase + wave * 32 + l16) * GRD;
    const ushort_t* rw1 = rw0 + (size_t)16 * GRD;

    float lacc[2] = {0.f, 0.f};
    f32x4 zero = {0.f, 0.f, 0.f, 0.f};
    f32x4 oacc[2][4];
    #pragma unroll
    for (int s = 0; s < 2; s++)
        #pragma unroll
        for (int cs = 0; cs < 4; cs++) oacc[s][cs] = zero;

    const float scale2 = 0.125f * LOG2E;

    uint4 rk0 = *(const uint4*)(kg0 + (size_t)kbase * HD);
    uint4 rk1 = *(const uint4*)(kg1 + (size_t)kbase * HD);
    uint4 rv0 = *(const uint4*)(vg0 + kbase);
    uint4 rv1 = *(const uint4*)(vg1 + kbase);

    for (int kt = 0; kt < KT_PER; kt++) {
        int kb = kbase + kt * 64;

        __syncthreads();
        *(uint4*)&Ks[sk0] = rk0;  *(uint4*)&Ks[sk1] = rk1;
        *(uint4*)&Vs[sk0] = rv0;  *(uint4*)&Vs[sk1] = rv1;
        __syncthreads();

        // rwv for THIS kt, issued first: softmax's wait is vmcnt(4) so the
        // K/V loads below stay in flight; ~2 ds_reads + 2 MFMAs of cover.
        uint2 rwv[2][4];
        #pragma unroll
        for (int ks = 0; ks < 4; ks++) {
            int kb4 = kb + ks * 16 + quad * 4;
            int kh = kb4 / 48;
            int kw0 = kb4 - kh * 48;
            rwv[0][ks] = *(const uint2*)(rw0 + kw0);
            rwv[1][ks] = *(const uint2*)(rw1 + kw0);
        }

        if (kt < KT_PER - 1) {
            int kbn = kb + 64;
            rk0 = *(const uint4*)(kg0 + (size_t)kbn * HD);
            rk1 = *(const uint4*)(kg1 + (size_t)kbn * HD);
            rv0 = *(const uint4*)(vg0 + kbn);
            rv1 = *(const uint4*)(vg1 + kbn);
        }

        #pragma unroll
        for (int ks = 0; ks < 4; ks++) {
            bf16x8 kf0 = *(const bf16x8*)&Ks[(ks * 16 + l16) * 68 + quad * 8];
            bf16x8 kf1 = *(const bf16x8*)&Ks[(ks * 16 + l16) * 68 + 32 + quad * 8];
            f32x4 st[2];
            #pragma unroll
            for (int s = 0; s < 2; s++) {
                f32x4 z = zero;
                z = __builtin_amdgcn_mfma_f32_16x16x32_bf16(kf0, qf[s][0], z, 0, 0, 0);
                z = __builtin_amdgcn_mfma_f32_16x16x32_bf16(kf1, qf[s][1], z, 0, 0, 0);
                st[s] = z;
            }
            int kb4 = kb + ks * 16 + quad * 4;
            int khl = kb4 / 48 - chunk * 16;
            #pragma unroll
            for (int s = 0; s < 2; s++) {
                int row = wave * 32 + s * 16 + l16;
                float rh = bf2f(rhs[row * 18 + khl]);
                uint2 u = rwv[s][ks];
                float p0 = __builtin_amdgcn_exp2f(st[s][0] * scale2 + rh + __uint_as_float(u.x << 16));
                float p1 = __builtin_amdgcn_exp2f(st[s][1] * scale2 + rh + __uint_as_float(u.x & 0xffff0000u));
                float p2 = __builtin_amdgcn_exp2f(st[s][2] * scale2 + rh + __uint_as_float(u.y << 16));
                float p3 = __builtin_amdgcn_exp2f(st[s][3] * scale2 + rh + __uint_as_float(u.y & 0xffff0000u));
                lacc[s] += (p0 + p1) + (p2 + p3);
                uint2 w;
                w.x = __builtin_amdgcn_perm(__float_as_uint(p1), __float_as_uint(p0), 0x07060302u);
                w.y = __builtin_amdgcn_perm(__float_as_uint(p3), __float_as_uint(p2), 0x07060302u);
                *(uint2*)&Ps[wave][(s * 16 + l16) * 68 + ks * 16 + quad * 4] = w;
            }
        }

        bf16x8 vf[4][2];
        #pragma unroll
        for (int cs = 0; cs < 4; cs++) {
            vf[cs][0] = *(const bf16x8*)&Vs[(cs * 16 + l16) * 68 + quad * 8];
            vf[cs][1] = *(const bf16x8*)&Vs[(cs * 16 + l16) * 68 + 32 + quad * 8];
        }
        #pragma unroll
        for (int s = 0; s < 2; s++) {
            bf16x8 pa0 = *(const bf16x8*)&Ps[wave][(s * 16 + l16) * 68 + quad * 8];
            bf16x8 pa1 = *(const bf16x8*)&Ps[wave][(s * 16 + l16) * 68 + 32 + quad * 8];
            #pragma unroll
            for (int cs = 0; cs < 4; cs++) {
                oacc[s][cs] = __builtin_amdgcn_mfma_f32_16x16x32_bf16(pa0, vf[cs][0], oacc[s][cs], 0, 0, 0);
                oacc[s][cs] = __builtin_amdgcn_mfma_f32_16x16x32_bf16(pa1, vf[cs][1], oacc[s][cs], 0, 0, 0);
            }
        }
    }

    #pragma unroll
    for (int s = 0; s < 2; s++) {
        float l = lacc[s];
        l += __shfl_xor(l, 16);
        l += __shfl_xor(l, 32);
        lacc[s] = l;
    }

    size_t obase = (size_t)(chunk * HEADS + h) * NTOK;
    #pragma unroll
    for (int s = 0; s < 2; s++) {
        #pragma unroll
        for (int cs = 0; cs < 4; cs++) {
            #pragma unroll
            for (int r = 0; r < 4; r++) {
                int row = qbase + wave * 32 + s * 16 + quad * 4 + r;
                Opart[(obase + row) * HD + cs * 16 + l16] = oacc[s][cs][r];
            }
        }
        if (quad == 0)
            Lpart[obase + qbase + wave * 32 + s * 16 + l16] = lacc[s];
    }
}

// ---------------------------------------------------------------------------
// Merge split-K partials: Ob = (sum_ch O) / (sum_ch l), bf16.
// ---------------------------------------------------------------------------
__global__ __launch_bounds__(256) void k_merge(const float* __restrict__ Opart,
                                               const float* __restrict__ Lpart,
                                               ushort_t* __restrict__ Ob) {
    int t = blockIdx.x * 256 + threadIdx.x;
    int e = t * 4;
    int c = e & (HD - 1);
    int row = (e >> 6) % NTOK;
    int h = e / (NTOK * HD);
    const int ostride = HEADS * NTOK * HD;
    float4 s = {0.f, 0.f, 0.f, 0.f};
    float l = 0.f;
    #pragma unroll
    for (int ch = 0; ch < CHUNKS; ch++) {
        float4 v = *(const float4*)&Opart[(size_t)ch * ostride + e];
        s.x += v.x; s.y += v.y; s.z += v.z; s.w += v.w;
        l += Lpart[(size_t)(ch * HEADS + h) * NTOK + row];
    }
    float inv = 1.0f / l;
    ushort4 o = make_ushort4(f2bf(s.x * inv), f2bf(s.y * inv),
                             f2bf(s.z * inv), f2bf(s.w * inv));
    *(ushort4*)&Ob[(size_t)row * DIM + h * HD + c] = o;
}

// ---------------------------------------------------------------------------
// Output projection: 128(M)x64(N) tiles -> 216 blocks, BK=64 via two
// 32-col LDS planes (24 KB), 12 k-steps, 24 barriers.
// ---------------------------------------------------------------------------
__global__ __launch_bounds__(256) void k_gemm_proj(
    const ushort_t* __restrict__ Ob, const ushort_t* __restrict__ WTp,
    const float* __restrict__ bp, float* __restrict__ out) {
    __shared__ __align__(16) ushort_t As[2][128 * 32];   // 8 KB x2
    __shared__ __align__(16) ushort_t Bs[2][64 * 32];    // 4 KB x2
    int tid = threadIdx.x;
    int wave = tid >> 6, lane = tid & 63, quad = lane >> 4, l16 = lane & 15;
    int wx = wave & 1, wy = wave >> 1;
    int nb = blockIdx.x * 64, mb = blockIdx.y * 128;

    f32x4 zero = {0.f, 0.f, 0.f, 0.f};
    f32x4 acc[4][2];
    #pragma unroll
    for (int i = 0; i < 4; i++)
        #pragma unroll
        for (int j = 0; j < 2; j++) acc[i][j] = zero;

    int rl = lane >> 2;
    int cl = (lane & 3) * 8;
    const ushort_t* gA = Ob + (size_t)(mb + wave * 32 + rl) * DIM + cl;
    const ushort_t* gB = WTp + (size_t)(nb + wave * 16 + rl) * DIM + cl;
    ushort_t* lA0 = &As[0][(wave * 32) * 32];
    ushort_t* lA1 = &As[1][(wave * 32) * 32];
    ushort_t* lB0 = &Bs[0][(wave * 16) * 32];
    ushort_t* lB1 = &Bs[1][(wave * 16) * 32];

    for (int k0 = 0; k0 < DIM; k0 += 64) {
        __syncthreads();
        gload_lds16(gA + k0,                 lA0);
        gload_lds16(gA + k0 + 16 * DIM,      lA0 + 16 * 32);
        gload_lds16(gA + k0 + 32,            lA1);
        gload_lds16(gA + k0 + 32 + 16 * DIM, lA1 + 16 * 32);
        gload_lds16(gB + k0,                 lB0);
        gload_lds16(gB + k0 + 32,            lB1);
        __syncthreads();
        #pragma unroll
        for (int p = 0; p < 2; p++) {
            bf16x8 af[4], bf[2];
            #pragma unroll
            for (int i = 0; i < 4; i++)
                af[i] = *(const bf16x8*)&As[p][(wy * 64 + i * 16 + l16) * 32 + quad * 8];
            #pragma unroll
            for (int j = 0; j < 2; j++)
                bf[j] = *(const bf16x8*)&Bs[p][(wx * 32 + j * 16 + l16) * 32 + quad * 8];
            #pragma unroll
            for (int i = 0; i < 4; i++)
                #pragma unroll
                for (int j = 0; j < 2; j++)
                    acc[i][j] = __builtin_amdgcn_mfma_f32_16x16x32_bf16(af[i], bf[j], acc[i][j], 0, 0, 0);
        }
    }

    #pragma unroll
    for (int j = 0; j < 2; j++) {
        int col = nb + wx * 32 + j * 16 + l16;
        float bval = bp[col];
        #pragma unroll
        for (int i = 0; i < 4; i++) {
            #pragma unroll
            for (int r = 0; r < 4; r++) {
                int row = mb + wy * 64 + i * 16 + quad * 4 + r;
                out[(size_t)row * DIM + col] = acc[i][j][r] + bval;
            }
        }
    }
}

// ---------------------------------------------------------------------------
extern "C" void kernel_launch(void* const* d_in, const int* in_sizes, int n_in,
                              void* d_out, int out_size, void* d_ws, size_t ws_size,
                              hipStream_t stream) {
    const float* x   = (const float*)d_in[0];
    const float* Wq  = (const float*)d_in[1];
    const float* bq  = (const float*)d_in[2];
    const float* Wk  = (const float*)d_in[3];
    const float* bk  = (const float*)d_in[4];
    const float* Wv  = (const float*)d_in[5];
    const float* bv  = (const float*)d_in[6];
    const float* Wp  = (const float*)d_in[7];
    const float* bp  = (const float*)d_in[8];
    const float* rph = (const float*)d_in[9];
    const float* rpw = (const float*)d_in[10];
    const float* Aq  = (const float*)d_in[11];
    const float* Bq  = (const float*)d_in[12];
    const float* Ak  = (const float*)d_in[13];
    const float* Bk  = (const float*)d_in[14];
    const float* Av  = (const float*)d_in[15];
    const float* Bv  = (const float*)d_in[16];
    float* out = (float*)d_out;

    char* w = (char*)d_ws;
    size_t off = 0;
    auto carve = [&](size_t bytes) {
        char* p = w + off;
        off += (bytes + 255) & ~(size_t)255;
        return p;
    };
    ushort_t* xb    = (ushort_t*)carve((size_t)NTOK * DIM * 2);
    ushort_t* WT    = (ushort_t*)carve((size_t)4 * DIM * DIM * 2);
    ushort_t* Qb    = (ushort_t*)carve((size_t)HEADS * NTOK * HD * 2);
    ushort_t* Kb    = (ushort_t*)carve((size_t)HEADS * NTOK * HD * 2);
    ushort_t* Vtb   = (ushort_t*)carve((size_t)HEADS * HD * NTOK * 2);
    float*    relH  = (float*)carve((size_t)HEADS * NTOK * GRD * 4);
    ushort_t* relWb = (ushort_t*)carve((size_t)HEADS * NTOK * GRD * 2);
    ushort_t* Ob    = (ushort_t*)carve((size_t)NTOK * DIM * 2);
    float*    Opart = (float*)carve((size_t)CHUNKS * HEADS * NTOK * HD * 4);
    float*    Lpart = (float*)carve((size_t)CHUNKS * HEADS * NTOK * 4);
    ushort_t* rphb  = (ushort_t*)carve((size_t)(2 * GRD - 1) * HD * 2);
    ushort_t* rpwb  = (ushort_t*)carve((size_t)(2 * GRD - 1) * HD * 2);

    k_prep<<<dim3(2304), dim3(256), 0, stream>>>(
        x, xb, rph, rpw, rphb, rpwb,
        Wq, Wk, Wv, Wp, Aq, Bq, Ak, Bk, Av, Bv, WT);
    k_gemm_qkv<<<dim3(36, 18), dim3(256), 0, stream>>>(
        xb, WT, bq, bk, bv, Qb, Kb, Vtb);
    k_relmm<<<dim3(288), dim3(256), 0, stream>>>(
        Qb, rphb, rpwb, relH, relWb);
    k_attn<<<dim3(HEADS * CHUNKS, NTOK / 128), dim3(256), 0, stream>>>(
        Qb, Kb, Vtb, relH, relWb, Opart, Lpart);
    k_merge<<<dim3(HEADS * NTOK * HD / (256 * 4)), dim3(256), 0, stream>>>(
        Opart, Lpart, Ob);
    k_gemm_proj<<<dim3(12, 18), dim3(256), 0, stream>>>(
        Ob, WT + (size_t)3 * DIM * DIM, bp, out);
}

// Round 10
// 180.521 us; speedup vs baseline: 1.1953x; 1.0486x over previous
//
#include <hip/hip_runtime.h>

// ---------------------------------------------------------------------------
// LoRA_Attention: fold LoRA into weights; bf16 MFMA GEMMs; split-K flash
// attention. R18: k_gemm_qkv epilogue repacked through LDS (reuses the
// 24 KB staging pool post-barrier). Old epilogue: 32 scalar 2B stores per
// thread; V stores transposed-scattered (consecutive lanes 4608B apart,
// 1.77M isolated 2B stores). New: Q/K via [128][72] tile -> 128B row
// bursts; V via pre-transposed [64][136] tile -> 256B contiguous runs.
// Values bit-identical (absmax must stay 0.0004882812). BK=64 staging
// kept from R17 (neutral but fewer barriers). k_attn frozen (R16 core).
// ---------------------------------------------------------------------------

#define DIM   768
#define HEADS 12
#define HD    64
#define NTOK  2304
#define RANK  8
#define GRD   48
#define CHUNKS 3
#define KEYS_PER_CHUNK 768
#define KT_PER 12
#define LOG2E 1.44269504088896f

typedef __attribute__((ext_vector_type(8))) short bf16x8;
typedef __attribute__((ext_vector_type(4))) float f32x4;
typedef unsigned short ushort_t;

__device__ __forceinline__ unsigned short f2bf(float x) {
    union { float f; unsigned u; } v; v.f = x;
    unsigned r = v.u + 0x7fffu + ((v.u >> 16) & 1u);
    return (unsigned short)(r >> 16);
}
__device__ __forceinline__ float bf2f(unsigned short h) {
    return __uint_as_float(((unsigned)h) << 16);
}
__device__ __forceinline__ void gload_lds16(const ushort_t* g, ushort_t* l) {
    __builtin_amdgcn_global_load_lds(
        (const __attribute__((address_space(1))) unsigned int*)g,
        (__attribute__((address_space(3))) unsigned int*)l, 16, 0, 0);
}

// ---------------------------------------------------------------------------
// k_prep: fold LoRA into transposed weights (all 2304 blocks) + convert
// x / rel tables to bf16 (blocks < 1740). Independent tasks, one launch.
// ---------------------------------------------------------------------------
__global__ __launch_bounds__(256) void k_prep(
    const float* __restrict__ x, ushort_t* __restrict__ xb,
    const float* __restrict__ rph, const float* __restrict__ rpw,
    ushort_t* __restrict__ rphb, ushort_t* __restrict__ rpwb,
    const float* __restrict__ Wq, const float* __restrict__ Wk,
    const float* __restrict__ Wv, const float* __restrict__ Wp,
    const float* __restrict__ Aq, const float* __restrict__ Bq,
    const float* __restrict__ Ak, const float* __restrict__ Bk,
    const float* __restrict__ Av, const float* __restrict__ Bv,
    ushort_t* __restrict__ WT) {
    int bid = blockIdx.x, tid = threadIdx.x;

    if (bid < 1740) {
        if (bid < 1728) {
            int idx = (bid * 256 + tid) * 4;
            float4 v = *(const float4*)(x + idx);
            ushort4 o = make_ushort4(f2bf(v.x), f2bf(v.y), f2bf(v.z), f2bf(v.w));
            *(ushort4*)(xb + idx) = o;
        } else {
            int e = ((bid - 1728) * 256 + tid) * 4;
            const int TSZ = (2 * GRD - 1) * HD;   // 6080
            if (e < TSZ) {
                float4 v = *(const float4*)(rph + e);
                ushort4 o = make_ushort4(f2bf(v.x), f2bf(v.y), f2bf(v.z), f2bf(v.w));
                *(ushort4*)(rphb + e) = o;
            } else if (e < 2 * TSZ) {
                float4 v = *(const float4*)(rpw + e - TSZ);
                ushort4 o = make_ushort4(f2bf(v.x), f2bf(v.y), f2bf(v.z), f2bf(v.w));
                *(ushort4*)(rpwb + e - TSZ) = o;
            }
        }
    }

    int kb = (bid % 24) * 32;
    int nb = (bid / 24) * 32;
    int sel = nb / DIM, nmod = nb % DIM;
    const float* W = (sel == 0) ? Wq : (sel == 1) ? Wk : (sel == 2) ? Wv : Wp;
    const float* A = (sel == 0) ? Aq : (sel == 1) ? Ak : Av;
    const float* B = (sel == 0) ? Bq : (sel == 1) ? Bk : Bv;
    __shared__ float T[32][33];
    for (int i = tid; i < 1024; i += 256) {
        int kl = i >> 5, nl = i & 31;
        float v = W[(kb + kl) * DIM + nmod + nl];
        if (sel < 3) {
            #pragma unroll
            for (int r = 0; r < RANK; r++)
                v += A[(kb + kl) * RANK + r] * B[r * DIM + nmod + nl];
        }
        T[kl][nl] = v;
    }
    __syncthreads();
    for (int i = tid; i < 1024; i += 256) {
        int nl = i >> 5, kl = i & 31;
        WT[(size_t)(nb + nl) * DIM + kb + kl] = f2bf(T[kl][nl]);
    }
}

// ---------------------------------------------------------------------------
// QKV GEMM: 128(M)x64(N) tiles -> 648 blocks, BK=64 (two 32-col planes,
// 24 KB pool). Epilogue repacked through the SAME pool: Q/K -> [128][72]
// tile, 16B row-burst stores; V -> pre-transposed [64][136] tile, 256B
// contiguous Vtb runs. Each block's 64 cols = one (matrix, head) pair.
// ---------------------------------------------------------------------------
__global__ __launch_bounds__(256) void k_gemm_qkv(
    const ushort_t* __restrict__ xb, const ushort_t* __restrict__ WT,
    const float* __restrict__ bq, const float* __restrict__ bk,
    const float* __restrict__ bv,
    ushort_t* __restrict__ Qb, ushort_t* __restrict__ Kb,
    ushort_t* __restrict__ Vtb) {
    __shared__ __align__(16) ushort_t pool[12288];   // 24 KB
    ushort_t* As0 = pool;                // 128*32
    ushort_t* As1 = pool + 4096;
    ushort_t* Bs0 = pool + 8192;         // 64*32
    ushort_t* Bs1 = pool + 10240;
    int tid = threadIdx.x;
    int wave = tid >> 6, lane = tid & 63, quad = lane >> 4, l16 = lane & 15;
    int wx = wave & 1, wy = wave >> 1;
    int nb = blockIdx.x * 64, mb = blockIdx.y * 128;

    f32x4 zero = {0.f, 0.f, 0.f, 0.f};
    f32x4 acc[4][2];
    #pragma unroll
    for (int i = 0; i < 4; i++)
        #pragma unroll
        for (int j = 0; j < 2; j++) acc[i][j] = zero;

    int rl = lane >> 2;            // 0..15
    int cl = (lane & 3) * 8;       // element col within 32
    const ushort_t* gA = xb + (size_t)(mb + wave * 32 + rl) * DIM + cl;
    const ushort_t* gB = WT + (size_t)(nb + wave * 16 + rl) * DIM + cl;
    ushort_t* lA0 = As0 + (wave * 32) * 32;
    ushort_t* lA1 = As1 + (wave * 32) * 32;
    ushort_t* lB0 = Bs0 + (wave * 16) * 32;
    ushort_t* lB1 = Bs1 + (wave * 16) * 32;

    for (int k0 = 0; k0 < DIM; k0 += 64) {
        __syncthreads();
        gload_lds16(gA + k0,                 lA0);
        gload_lds16(gA + k0 + 16 * DIM,      lA0 + 16 * 32);
        gload_lds16(gA + k0 + 32,            lA1);
        gload_lds16(gA + k0 + 32 + 16 * DIM, lA1 + 16 * 32);
        gload_lds16(gB + k0,                 lB0);
        gload_lds16(gB + k0 + 32,            lB1);
        __syncthreads();
        #pragma unroll
        for (int p = 0; p < 2; p++) {
            const ushort_t* Ap = p ? As1 : As0;
            const ushort_t* Bp = p ? Bs1 : Bs0;
            bf16x8 af[4], bf[2];
            #pragma unroll
            for (int i = 0; i < 4; i++)
                af[i] = *(const bf16x8*)&Ap[(wy * 64 + i * 16 + l16) * 32 + quad * 8];
            #pragma unroll
            for (int j = 0; j < 2; j++)
                bf[j] = *(const bf16x8*)&Bp[(wx * 32 + j * 16 + l16) * 32 + quad * 8];
            #pragma unroll
            for (int i = 0; i < 4; i++)
                #pragma unroll
                for (int j = 0; j < 2; j++)
                    acc[i][j] = __builtin_amdgcn_mfma_f32_16x16x32_bf16(af[i], bf[j], acc[i][j], 0, 0, 0);
        }
    }

    // ---- epilogue: bias + convert + LDS repack + coalesced stores ----
    int sel = nb / DIM;
    int rem0 = nb - sel * DIM;
    int hh = rem0 >> 6;
    const float* bias = (sel == 0) ? bq : (sel == 1) ? bk : bv;

    __syncthreads();   // all staging reads done; pool is reusable

    if (sel < 2) {
        const int P = 72;   // row pitch (144B = 9x16B: aligned, bank-rotating)
        #pragma unroll
        for (int j = 0; j < 2; j++) {
            int c = wx * 32 + j * 16 + l16;
            float bval = bias[rem0 + c];
            #pragma unroll
            for (int i = 0; i < 4; i++)
                #pragma unroll
                for (int r = 0; r < 4; r++) {
                    int row = wy * 64 + i * 16 + quad * 4 + r;
                    pool[row * P + c] = f2bf(acc[i][j][r] + bval);
                }
        }
        __syncthreads();
        ushort_t* qout = ((sel == 0) ? Qb : Kb) + (size_t)(hh * NTOK + mb) * HD;
        for (int idx = tid; idx < 128 * 8; idx += 256) {
            int row = idx >> 3, s8 = idx & 7;
            uint4 v = *(const uint4*)&pool[row * P + s8 * 8];
            *(uint4*)&qout[(size_t)row * HD + s8 * 8] = v;
        }
    } else {
        const int PV = 136; // col pitch (272B = 17x16B: aligned)
        #pragma unroll
        for (int j = 0; j < 2; j++) {
            int c = wx * 32 + j * 16 + l16;
            float bval = bias[rem0 + c];
            #pragma unroll
            for (int i = 0; i < 4; i++)
                #pragma unroll
                for (int r = 0; r < 4; r++) {
                    int row = wy * 64 + i * 16 + quad * 4 + r;
                    pool[c * PV + row] = f2bf(acc[i][j][r] + bval);
                }
        }
        __syncthreads();
        ushort_t* vout = Vtb + (size_t)(hh * HD) * NTOK + mb;
        for (int idx = tid; idx < 64 * 16; idx += 256) {
            int cc = idx >> 4, r8 = idx & 15;
            uint4 v = *(const uint4*)&pool[cc * PV + r8 * 8];
            *(uint4*)&vout[(size_t)cc * NTOK + r8 * 8] = v;
        }
    }
}

// ---------------------------------------------------------------------------
// Rel-pos bias via MFMA (outputs pre-scaled by log2 e).
// relW emitted as bf16 (k_attn reads it directly from global); relH
// stays f32 (staged+converted into k_attn's small rhs LDS buffer).
// ---------------------------------------------------------------------------
__global__ __launch_bounds__(256) void k_relmm(
    const ushort_t* __restrict__ Qb, const ushort_t* __restrict__ rphb,
    const ushort_t* __restrict__ rpwb, float* __restrict__ relH,
    ushort_t* __restrict__ relWb) {
    int id = blockIdx.x * 4 + (threadIdx.x >> 6);
    int lane = threadIdx.x & 63, quad = lane >> 4, l16 = lane & 15;
    bool isW = id >= 576;
    int t = isW ? id - 576 : id;
    int h = t / GRD, g = t % GRD;
    const ushort_t* tab = isW ? rpwb : rphb;

    f32x4 zero = {0.f, 0.f, 0.f, 0.f};
    f32x4 acc[3][3];
    #pragma unroll
    for (int i = 0; i < 3; i++)
        #pragma unroll
        for (int j = 0; j < 3; j++) acc[i][j] = zero;

    bf16x8 bfr[3][2];
    #pragma unroll
    for (int ct = 0; ct < 3; ct++) {
        int trow = g + 47 - (ct * 16 + l16);
        bfr[ct][0] = *(const bf16x8*)&tab[(size_t)trow * HD + quad * 8];
        bfr[ct][1] = *(const bf16x8*)&tab[(size_t)trow * HD + 32 + quad * 8];
    }
    #pragma unroll
    for (int ms = 0; ms < 3; ms++) {
        int m = ms * 16 + l16;
        int n = isW ? m * GRD + g : g * GRD + m;
        bf16x8 a0 = *(const bf16x8*)&Qb[(size_t)(h * NTOK + n) * HD + quad * 8];
        bf16x8 a1 = *(const bf16x8*)&Qb[(size_t)(h * NTOK + n) * HD + 32 + quad * 8];
        #pragma unroll
        for (int ct = 0; ct < 3; ct++) {
            acc[ms][ct] = __builtin_amdgcn_mfma_f32_16x16x32_bf16(a0, bfr[ct][0], acc[ms][ct], 0, 0, 0);
            acc[ms][ct] = __builtin_amdgcn_mfma_f32_16x16x32_bf16(a1, bfr[ct][1], acc[ms][ct], 0, 0, 0);
        }
    }
    #pragma unroll
    for (int ms = 0; ms < 3; ms++) {
        #pragma unroll
        for (int ct = 0; ct < 3; ct++) {
            #pragma unroll
            for (int r = 0; r < 4; r++) {
                int m = ms * 16 + quad * 4 + r;
                int n = isW ? m * GRD + g : g * GRD + m;
                int col = ct * 16 + l16;
                float val = acc[ms][ct][r] * LOG2E;
                if (isW)
                    relWb[(size_t)(h * NTOK + n) * GRD + col] = f2bf(val);
                else
                    relH[(size_t)(h * NTOK + n) * GRD + col] = val;
            }
        }
    }
}

// ---------------------------------------------------------------------------
// Flash attention, split-K. Block = (128 q-rows, head, chunk of 768 keys).
// Grid 648 <= 768 capacity (3 blk/CU at (256,3)): single-phase. R16 core.
// ---------------------------------------------------------------------------
__global__ __launch_bounds__(256, 3) void k_attn(
    const ushort_t* __restrict__ Qb, const ushort_t* __restrict__ Kb,
    const ushort_t* __restrict__ Vtb, const float* __restrict__ relH,
    const ushort_t* __restrict__ relWb, float* __restrict__ Opart,
    float* __restrict__ Lpart) {
    int h = blockIdx.x / CHUNKS, chunk = blockIdx.x - h * CHUNKS;
    int qt = blockIdx.y;
    int tid = threadIdx.x;
    int wave = tid >> 6, lane = tid & 63, quad = lane >> 4, l16 = lane & 15;
    int qbase = qt * 128;
    int kbase = chunk * KEYS_PER_CHUNK;

    __shared__ __align__(16) ushort_t Ks[64 * 68];
    __shared__ __align__(16) ushort_t Vs[64 * 68];
    __shared__ __align__(16) ushort_t Ps[4][32 * 68];
    __shared__ __align__(16) ushort_t rhs[128 * 18];

    for (int i = tid; i < 128 * 16; i += 256) {
        int r = i >> 4, c = i & 15;
        rhs[r * 18 + c] = f2bf(relH[(size_t)(h * NTOK + qbase + r) * GRD + chunk * 16 + c]);
    }

    bf16x8 qf[2][2];
    #pragma unroll
    for (int s = 0; s < 2; s++) {
        int qrow = qbase + wave * 32 + s * 16 + l16;
        qf[s][0] = *(const bf16x8*)&Qb[(size_t)(h * NTOK + qrow) * HD + quad * 8];
        qf[s][1] = *(const bf16x8*)&Qb[(size_t)(h * NTOK + qrow) * HD + 32 + quad * 8];
    }

    int r0 = tid >> 3, c0 = (tid & 7) * 8;
    const ushort_t* kg0 = Kb + (size_t)(h * NTOK + r0) * HD + c0;
    const ushort_t* kg1 = Kb + (size_t)(h * NTOK + r0 + 32) * HD + c0;
    const ushort_t* vg0 = Vtb + (size_t)(h * HD + r0) * NTOK + c0;
    const ushort_t* vg1 = Vtb + (size_t)(h * HD + r0 + 32) * NTOK + c0;
    int sk0 = r0 * 68 + c0, sk1 = sk0 + 32 * 68;

    // per-lane relW row pointers (rows owned by this lane across s=0,1)
    const ushort_t* rw0 = relWb + (size_t)(h * NTOK + qbase + wave * 32 + l16) * GRD;
    const ushort_t* rw1 = rw0 + (size_t)16 * GRD;

    float lacc[2] = {0.f, 0.f};
    f32x4 zero = {0.f, 0.f, 0.f, 0.f};
    f32x4 oacc[2][4];
    #pragma unroll
    for (int s = 0; s < 2; s++)
        #pragma unroll
        for (int cs = 0; cs < 4; cs++) oacc[s][cs] = zero;

    const float scale2 = 0.125f * LOG2E;

    uint4 rk0 = *(const uint4*)(kg0 + (size_t)kbase * HD);
    uint4 rk1 = *(const uint4*)(kg1 + (size_t)kbase * HD);
    uint4 rv0 = *(const uint4*)(vg0 + kbase);
    uint4 rv1 = *(const uint4*)(vg1 + kbase);

    for (int kt = 0; kt < KT_PER; kt++) {
        int kb = kbase + kt * 64;

        __syncthreads();
        *(uint4*)&Ks[sk0] = rk0;  *(uint4*)&Ks[sk1] = rk1;
        *(uint4*)&Vs[sk0] = rv0;  *(uint4*)&Vs[sk1] = rv1;
        __syncthreads();

        // rwv for THIS kt, issued first: softmax's wait is vmcnt(4) so the
        // K/V loads below stay in flight; ~2 ds_reads + 2 MFMAs of cover.
        uint2 rwv[2][4];
        #pragma unroll
        for (int ks = 0; ks < 4; ks++) {
            int kb4 = kb + ks * 16 + quad * 4;
            int kh = kb4 / 48;
            int kw0 = kb4 - kh * 48;
            rwv[0][ks] = *(const uint2*)(rw0 + kw0);
            rwv[1][ks] = *(const uint2*)(rw1 + kw0);
        }

        if (kt < KT_PER - 1) {
            int kbn = kb + 64;
            rk0 = *(const uint4*)(kg0 + (size_t)kbn * HD);
            rk1 = *(const uint4*)(kg1 + (size_t)kbn * HD);
            rv0 = *(const uint4*)(vg0 + kbn);
            rv1 = *(const uint4*)(vg1 + kbn);
        }

        #pragma unroll
        for (int ks = 0; ks < 4; ks++) {
            bf16x8 kf0 = *(const bf16x8*)&Ks[(ks * 16 + l16) * 68 + quad * 8];
            bf16x8 kf1 = *(const bf16x8*)&Ks[(ks * 16 + l16) * 68 + 32 + quad * 8];
            f32x4 st[2];
            #pragma unroll
            for (int s = 0; s < 2; s++) {
                f32x4 z = zero;
                z = __builtin_amdgcn_mfma_f32_16x16x32_bf16(kf0, qf[s][0], z, 0, 0, 0);
                z = __builtin_amdgcn_mfma_f32_16x16x32_bf16(kf1, qf[s][1], z, 0, 0, 0);
                st[s] = z;
            }
            int kb4 = kb + ks * 16 + quad * 4;
            int khl = kb4 / 48 - chunk * 16;
            #pragma unroll
            for (int s = 0; s < 2; s++) {
                int row = wave * 32 + s * 16 + l16;
                float rh = bf2f(rhs[row * 18 + khl]);
                uint2 u = rwv[s][ks];
                float p0 = __builtin_amdgcn_exp2f(st[s][0] * scale2 + rh + __uint_as_float(u.x << 16));
                float p1 = __builtin_amdgcn_exp2f(st[s][1] * scale2 + rh + __uint_as_float(u.x & 0xffff0000u));
                float p2 = __builtin_amdgcn_exp2f(st[s][2] * scale2 + rh + __uint_as_float(u.y << 16));
                float p3 = __builtin_amdgcn_exp2f(st[s][3] * scale2 + rh + __uint_as_float(u.y & 0xffff0000u));
                lacc[s] += (p0 + p1) + (p2 + p3);
                uint2 w;
                w.x = __builtin_amdgcn_perm(__float_as_uint(p1), __float_as_uint(p0), 0x07060302u);
                w.y = __builtin_amdgcn_perm(__float_as_uint(p3), __float_as_uint(p2), 0x07060302u);
                *(uint2*)&Ps[wave][(s * 16 + l16) * 68 + ks * 16 + quad * 4] = w;
            }
        }

        bf16x8 vf[4][2];
        #pragma unroll
        for (int cs = 0; cs < 4; cs++) {
            vf[cs][0] = *(const bf16x8*)&Vs[(cs * 16 + l16) * 68 + quad * 8];
            vf[cs][1] = *(const bf16x8*)&Vs[(cs * 16 + l16) * 68 + 32 + quad * 8];
        }
        #pragma unroll
        for (int s = 0; s < 2; s++) {
            bf16x8 pa0 = *(const bf16x8*)&Ps[wave][(s * 16 + l16) * 68 + quad * 8];
            bf16x8 pa1 = *(const bf16x8*)&Ps[wave][(s * 16 + l16) * 68 + 32 + quad * 8];
            #pragma unroll
            for (int cs = 0; cs < 4; cs++) {
                oacc[s][cs] = __builtin_amdgcn_mfma_f32_16x16x32_bf16(pa0, vf[cs][0], oacc[s][cs], 0, 0, 0);
                oacc[s][cs] = __builtin_amdgcn_mfma_f32_16x16x32_bf16(pa1, vf[cs][1], oacc[s][cs], 0, 0, 0);
            }
        }
    }

    #pragma unroll
    for (int s = 0; s < 2; s++) {
        float l = lacc[s];
        l += __shfl_xor(l, 16);
        l += __shfl_xor(l, 32);
        lacc[s] = l;
    }

    size_t obase = (size_t)(chunk * HEADS + h) * NTOK;
    #pragma unroll
    for (int s = 0; s < 2; s++) {
        #pragma unroll
        for (int cs = 0; cs < 4; cs++) {
            #pragma unroll
            for (int r = 0; r < 4; r++) {
                int row = qbase + wave * 32 + s * 16 + quad * 4 + r;
                Opart[(obase + row) * HD + cs * 16 + l16] = oacc[s][cs][r];
            }
        }
        if (quad == 0)
            Lpart[obase + qbase + wave * 32 + s * 16 + l16] = lacc[s];
    }
}

// ---------------------------------------------------------------------------
// Merge split-K partials: Ob = (sum_ch O) / (sum_ch l), bf16.
// ---------------------------------------------------------------------------
__global__ __launch_bounds__(256) void k_merge(const float* __restrict__ Opart,
                                               const float* __restrict__ Lpart,
                                               ushort_t* __restrict__ Ob) {
    int t = blockIdx.x * 256 + threadIdx.x;
    int e = t * 4;
    int c = e & (HD - 1);
    int row = (e >> 6) % NTOK;
    int h = e / (NTOK * HD);
    const int ostride = HEADS * NTOK * HD;
    float4 s = {0.f, 0.f, 0.f, 0.f};
    float l = 0.f;
    #pragma unroll
    for (int ch = 0; ch < CHUNKS; ch++) {
        float4 v = *(const float4*)&Opart[(size_t)ch * ostride + e];
        s.x += v.x; s.y += v.y; s.z += v.z; s.w += v.w;
        l += Lpart[(size_t)(ch * HEADS + h) * NTOK + row];
    }
    float inv = 1.0f / l;
    ushort4 o = make_ushort4(f2bf(s.x * inv), f2bf(s.y * inv),
                             f2bf(s.z * inv), f2bf(s.w * inv));
    *(ushort4*)&Ob[(size_t)row * DIM + h * HD + c] = o;
}

// ---------------------------------------------------------------------------
// Output projection: 128(M)x64(N) tiles -> 216 blocks, BK=64 via two
// 32-col LDS planes (24 KB), 12 k-steps, 24 barriers.
// ---------------------------------------------------------------------------
__global__ __launch_bounds__(256) void k_gemm_proj(
    const ushort_t* __restrict__ Ob, const ushort_t* __restrict__ WTp,
    const float* __restrict__ bp, float* __restrict__ out) {
    __shared__ __align__(16) ushort_t As[2][128 * 32];   // 8 KB x2
    __shared__ __align__(16) ushort_t Bs[2][64 * 32];    // 4 KB x2
    int tid = threadIdx.x;
    int wave = tid >> 6, lane = tid & 63, quad = lane >> 4, l16 = lane & 15;
    int wx = wave & 1, wy = wave >> 1;
    int nb = blockIdx.x * 64, mb = blockIdx.y * 128;

    f32x4 zero = {0.f, 0.f, 0.f, 0.f};
    f32x4 acc[4][2];
    #pragma unroll
    for (int i = 0; i < 4; i++)
        #pragma unroll
        for (int j = 0; j < 2; j++) acc[i][j] = zero;

    int rl = lane >> 2;
    int cl = (lane & 3) * 8;
    const ushort_t* gA = Ob + (size_t)(mb + wave * 32 + rl) * DIM + cl;
    const ushort_t* gB = WTp + (size_t)(nb + wave * 16 + rl) * DIM + cl;
    ushort_t* lA0 = &As[0][(wave * 32) * 32];
    ushort_t* lA1 = &As[1][(wave * 32) * 32];
    ushort_t* lB0 = &Bs[0][(wave * 16) * 32];
    ushort_t* lB1 = &Bs[1][(wave * 16) * 32];

    for (int k0 = 0; k0 < DIM; k0 += 64) {
        __syncthreads();
        gload_lds16(gA + k0,                 lA0);
        gload_lds16(gA + k0 + 16 * DIM,      lA0 + 16 * 32);
        gload_lds16(gA + k0 + 32,            lA1);
        gload_lds16(gA + k0 + 32 + 16 * DIM, lA1 + 16 * 32);
        gload_lds16(gB + k0,                 lB0);
        gload_lds16(gB + k0 + 32,            lB1);
        __syncthreads();
        #pragma unroll
        for (int p = 0; p < 2; p++) {
            bf16x8 af[4], bf[2];
            #pragma unroll
            for (int i = 0; i < 4; i++)
                af[i] = *(const bf16x8*)&As[p][(wy * 64 + i * 16 + l16) * 32 + quad * 8];
            #pragma unroll
            for (int j = 0; j < 2; j++)
                bf[j] = *(const bf16x8*)&Bs[p][(wx * 32 + j * 16 + l16) * 32 + quad * 8];
            #pragma unroll
            for (int i = 0; i < 4; i++)
                #pragma unroll
                for (int j = 0; j < 2; j++)
                    acc[i][j] = __builtin_amdgcn_mfma_f32_16x16x32_bf16(af[i], bf[j], acc[i][j], 0, 0, 0);
        }
    }

    #pragma unroll
    for (int j = 0; j < 2; j++) {
        int col = nb + wx * 32 + j * 16 + l16;
        float bval = bp[col];
        #pragma unroll
        for (int i = 0; i < 4; i++) {
            #pragma unroll
            for (int r = 0; r < 4; r++) {
                int row = mb + wy * 64 + i * 16 + quad * 4 + r;
                out[(size_t)row * DIM + col] = acc[i][j][r] + bval;
            }
        }
    }
}

// ---------------------------------------------------------------------------
extern "C" void kernel_launch(void* const* d_in, const int* in_sizes, int n_in,
                              void* d_out, int out_size, void* d_ws, size_t ws_size,
                              hipStream_t stream) {
    const float* x   = (const float*)d_in[0];
    const float* Wq  = (const float*)d_in[1];
    const float* bq  = (const float*)d_in[2];
    const float* Wk  = (const float*)d_in[3];
    const float* bk  = (const float*)d_in[4];
    const float* Wv  = (const float*)d_in[5];
    const float* bv  = (const float*)d_in[6];
    const float* Wp  = (const float*)d_in[7];
    const float* bp  = (const float*)d_in[8];
    const float* rph = (const float*)d_in[9];
    const float* rpw = (const float*)d_in[10];
    const float* Aq  = (const float*)d_in[11];
    const float* Bq  = (const float*)d_in[12];
    const float* Ak  = (const float*)d_in[13];
    const float* Bk  = (const float*)d_in[14];
    const float* Av  = (const float*)d_in[15];
    const float* Bv  = (const float*)d_in[16];
    float* out = (float*)d_out;

    char* w = (char*)d_ws;
    size_t off = 0;
    auto carve = [&](size_t bytes) {
        char* p = w + off;
        off += (bytes + 255) & ~(size_t)255;
        return p;
    };
    ushort_t* xb    = (ushort_t*)carve((size_t)NTOK * DIM * 2);
    ushort_t* WT    = (ushort_t*)carve((size_t)4 * DIM * DIM * 2);
    ushort_t* Qb    = (ushort_t*)carve((size_t)HEADS * NTOK * HD * 2);
    ushort_t* Kb    = (ushort_t*)carve((size_t)HEADS * NTOK * HD * 2);
    ushort_t* Vtb   = (ushort_t*)carve((size_t)HEADS * HD * NTOK * 2);
    float*    relH  = (float*)carve((size_t)HEADS * NTOK * GRD * 4);
    ushort_t* relWb = (ushort_t*)carve((size_t)HEADS * NTOK * GRD * 2);
    ushort_t* Ob    = (ushort_t*)carve((size_t)NTOK * DIM * 2);
    float*    Opart = (float*)carve((size_t)CHUNKS * HEADS * NTOK * HD * 4);
    float*    Lpart = (float*)carve((size_t)CHUNKS * HEADS * NTOK * 4);
    ushort_t* rphb  = (ushort_t*)carve((size_t)(2 * GRD - 1) * HD * 2);
    ushort_t* rpwb  = (ushort_t*)carve((size_t)(2 * GRD - 1) * HD * 2);

    k_prep<<<dim3(2304), dim3(256), 0, stream>>>(
        x, xb, rph, rpw, rphb, rpwb,
        Wq, Wk, Wv, Wp, Aq, Bq, Ak, Bk, Av, Bv, WT);
    k_gemm_qkv<<<dim3(36, 18), dim3(256), 0, stream>>>(
        xb, WT, bq, bk, bv, Qb, Kb, Vtb);
    k_relmm<<<dim3(288), dim3(256), 0, stream>>>(
        Qb, rphb, rpwb, relH, relWb);
    k_attn<<<dim3(HEADS * CHUNKS, NTOK / 128), dim3(256), 0, stream>>>(
        Qb, Kb, Vtb, relH, relWb, Opart, Lpart);
    k_merge<<<dim3(HEADS * NTOK * HD / (256 * 4)), dim3(256), 0, stream>>>(
        Opart, Lpart, Ob);
    k_gemm_proj<<<dim3(12, 18), dim3(256), 0, stream>>>(
        Ob, WT + (size_t)3 * DIM * DIM, bp, out);
}

// Round 11
// 178.885 us; speedup vs baseline: 1.2063x; 1.0091x over previous
//
#include <hip/hip_runtime.h>

// ---------------------------------------------------------------------------
// LoRA_Attention: fold LoRA into weights; bf16 MFMA GEMMs; split-K flash
// attention. R19: k_relmm re-decomposed for occupancy — old: 288 blocks
// (1.1/CU = 1 wave/SIMD) each unit doing 3 ms-groups serially with 6
// scattered 16B Q-loads and nothing to hide their L2 latency. New: unit =
// (isW,h,g,ms) -> 3456 units, 864 blocks, 3.4 waves/SIMD. Same MFMA chain
// per (ms,ct) -> bitwise-identical outputs. Also k_prep WT writes
// vectorized 2B->16B/lane (1024->128 stores/block). k_attn frozen (R16),
// qkv epilogue-coalesced (R18), BK=64 staging (R17).
// ---------------------------------------------------------------------------

#define DIM   768
#define HEADS 12
#define HD    64
#define NTOK  2304
#define RANK  8
#define GRD   48
#define CHUNKS 3
#define KEYS_PER_CHUNK 768
#define KT_PER 12
#define LOG2E 1.44269504088896f

typedef __attribute__((ext_vector_type(8))) short bf16x8;
typedef __attribute__((ext_vector_type(4))) float f32x4;
typedef unsigned short ushort_t;

__device__ __forceinline__ unsigned short f2bf(float x) {
    union { float f; unsigned u; } v; v.f = x;
    unsigned r = v.u + 0x7fffu + ((v.u >> 16) & 1u);
    return (unsigned short)(r >> 16);
}
__device__ __forceinline__ float bf2f(unsigned short h) {
    return __uint_as_float(((unsigned)h) << 16);
}
__device__ __forceinline__ void gload_lds16(const ushort_t* g, ushort_t* l) {
    __builtin_amdgcn_global_load_lds(
        (const __attribute__((address_space(1))) unsigned int*)g,
        (__attribute__((address_space(3))) unsigned int*)l, 16, 0, 0);
}

// ---------------------------------------------------------------------------
// k_prep: fold LoRA into transposed weights (all 2304 blocks) + convert
// x / rel tables to bf16 (blocks < 1740). Independent tasks, one launch.
// WT write vectorized: 8 bf16 packed -> one 16B store (128 stores/block).
// ---------------------------------------------------------------------------
__global__ __launch_bounds__(256) void k_prep(
    const float* __restrict__ x, ushort_t* __restrict__ xb,
    const float* __restrict__ rph, const float* __restrict__ rpw,
    ushort_t* __restrict__ rphb, ushort_t* __restrict__ rpwb,
    const float* __restrict__ Wq, const float* __restrict__ Wk,
    const float* __restrict__ Wv, const float* __restrict__ Wp,
    const float* __restrict__ Aq, const float* __restrict__ Bq,
    const float* __restrict__ Ak, const float* __restrict__ Bk,
    const float* __restrict__ Av, const float* __restrict__ Bv,
    ushort_t* __restrict__ WT) {
    int bid = blockIdx.x, tid = threadIdx.x;

    if (bid < 1740) {
        if (bid < 1728) {
            int idx = (bid * 256 + tid) * 4;
            float4 v = *(const float4*)(x + idx);
            ushort4 o = make_ushort4(f2bf(v.x), f2bf(v.y), f2bf(v.z), f2bf(v.w));
            *(ushort4*)(xb + idx) = o;
        } else {
            int e = ((bid - 1728) * 256 + tid) * 4;
            const int TSZ = (2 * GRD - 1) * HD;   // 6080
            if (e < TSZ) {
                float4 v = *(const float4*)(rph + e);
                ushort4 o = make_ushort4(f2bf(v.x), f2bf(v.y), f2bf(v.z), f2bf(v.w));
                *(ushort4*)(rphb + e) = o;
            } else if (e < 2 * TSZ) {
                float4 v = *(const float4*)(rpw + e - TSZ);
                ushort4 o = make_ushort4(f2bf(v.x), f2bf(v.y), f2bf(v.z), f2bf(v.w));
                *(ushort4*)(rpwb + e - TSZ) = o;
            }
        }
    }

    int kb = (bid % 24) * 32;
    int nb = (bid / 24) * 32;
    int sel = nb / DIM, nmod = nb % DIM;
    const float* W = (sel == 0) ? Wq : (sel == 1) ? Wk : (sel == 2) ? Wv : Wp;
    const float* A = (sel == 0) ? Aq : (sel == 1) ? Ak : Av;
    const float* B = (sel == 0) ? Bq : (sel == 1) ? Bk : Bv;
    __shared__ float T[32][33];
    for (int i = tid; i < 1024; i += 256) {
        int kl = i >> 5, nl = i & 31;
        float v = W[(kb + kl) * DIM + nmod + nl];
        if (sel < 3) {
            #pragma unroll
            for (int r = 0; r < RANK; r++)
                v += A[(kb + kl) * RANK + r] * B[r * DIM + nmod + nl];
        }
        T[kl][nl] = v;
    }
    __syncthreads();
    if (tid < 128) {
        int nl = tid >> 2, k8 = (tid & 3) * 8;
        ushort_t tmp[8];
        #pragma unroll
        for (int q = 0; q < 8; q++) tmp[q] = f2bf(T[k8 + q][nl]);
        *(uint4*)&WT[(size_t)(nb + nl) * DIM + kb + k8] = *(const uint4*)tmp;
    }
}

// ---------------------------------------------------------------------------
// QKV GEMM: 128(M)x64(N) tiles -> 648 blocks, BK=64 (two 32-col planes,
// 24 KB pool). Epilogue repacked through the SAME pool (R18): Q/K ->
// [128][72] tile, 16B row-burst stores; V -> pre-transposed [64][136]
// tile, 256B contiguous Vtb runs. Block's 64 cols = one (matrix, head).
// ---------------------------------------------------------------------------
__global__ __launch_bounds__(256) void k_gemm_qkv(
    const ushort_t* __restrict__ xb, const ushort_t* __restrict__ WT,
    const float* __restrict__ bq, const float* __restrict__ bk,
    const float* __restrict__ bv,
    ushort_t* __restrict__ Qb, ushort_t* __restrict__ Kb,
    ushort_t* __restrict__ Vtb) {
    __shared__ __align__(16) ushort_t pool[12288];   // 24 KB
    ushort_t* As0 = pool;                // 128*32
    ushort_t* As1 = pool + 4096;
    ushort_t* Bs0 = pool + 8192;         // 64*32
    ushort_t* Bs1 = pool + 10240;
    int tid = threadIdx.x;
    int wave = tid >> 6, lane = tid & 63, quad = lane >> 4, l16 = lane & 15;
    int wx = wave & 1, wy = wave >> 1;
    int nb = blockIdx.x * 64, mb = blockIdx.y * 128;

    f32x4 zero = {0.f, 0.f, 0.f, 0.f};
    f32x4 acc[4][2];
    #pragma unroll
    for (int i = 0; i < 4; i++)
        #pragma unroll
        for (int j = 0; j < 2; j++) acc[i][j] = zero;

    int rl = lane >> 2;            // 0..15
    int cl = (lane & 3) * 8;       // element col within 32
    const ushort_t* gA = xb + (size_t)(mb + wave * 32 + rl) * DIM + cl;
    const ushort_t* gB = WT + (size_t)(nb + wave * 16 + rl) * DIM + cl;
    ushort_t* lA0 = As0 + (wave * 32) * 32;
    ushort_t* lA1 = As1 + (wave * 32) * 32;
    ushort_t* lB0 = Bs0 + (wave * 16) * 32;
    ushort_t* lB1 = Bs1 + (wave * 16) * 32;

    for (int k0 = 0; k0 < DIM; k0 += 64) {
        __syncthreads();
        gload_lds16(gA + k0,                 lA0);
        gload_lds16(gA + k0 + 16 * DIM,      lA0 + 16 * 32);
        gload_lds16(gA + k0 + 32,            lA1);
        gload_lds16(gA + k0 + 32 + 16 * DIM, lA1 + 16 * 32);
        gload_lds16(gB + k0,                 lB0);
        gload_lds16(gB + k0 + 32,            lB1);
        __syncthreads();
        #pragma unroll
        for (int p = 0; p < 2; p++) {
            const ushort_t* Ap = p ? As1 : As0;
            const ushort_t* Bp = p ? Bs1 : Bs0;
            bf16x8 af[4], bf[2];
            #pragma unroll
            for (int i = 0; i < 4; i++)
                af[i] = *(const bf16x8*)&Ap[(wy * 64 + i * 16 + l16) * 32 + quad * 8];
            #pragma unroll
            for (int j = 0; j < 2; j++)
                bf[j] = *(const bf16x8*)&Bp[(wx * 32 + j * 16 + l16) * 32 + quad * 8];
            #pragma unroll
            for (int i = 0; i < 4; i++)
                #pragma unroll
                for (int j = 0; j < 2; j++)
                    acc[i][j] = __builtin_amdgcn_mfma_f32_16x16x32_bf16(af[i], bf[j], acc[i][j], 0, 0, 0);
        }
    }

    // ---- epilogue: bias + convert + LDS repack + coalesced stores ----
    int sel = nb / DIM;
    int rem0 = nb - sel * DIM;
    int hh = rem0 >> 6;
    const float* bias = (sel == 0) ? bq : (sel == 1) ? bk : bv;

    __syncthreads();   // all staging reads done; pool is reusable

    if (sel < 2) {
        const int P = 72;   // row pitch (144B = 9x16B: aligned, bank-rotating)
        #pragma unroll
        for (int j = 0; j < 2; j++) {
            int c = wx * 32 + j * 16 + l16;
            float bval = bias[rem0 + c];
            #pragma unroll
            for (int i = 0; i < 4; i++)
                #pragma unroll
                for (int r = 0; r < 4; r++) {
                    int row = wy * 64 + i * 16 + quad * 4 + r;
                    pool[row * P + c] = f2bf(acc[i][j][r] + bval);
                }
        }
        __syncthreads();
        ushort_t* qout = ((sel == 0) ? Qb : Kb) + (size_t)(hh * NTOK + mb) * HD;
        for (int idx = tid; idx < 128 * 8; idx += 256) {
            int row = idx >> 3, s8 = idx & 7;
            uint4 v = *(const uint4*)&pool[row * P + s8 * 8];
            *(uint4*)&qout[(size_t)row * HD + s8 * 8] = v;
        }
    } else {
        const int PV = 136; // col pitch (272B = 17x16B: aligned)
        #pragma unroll
        for (int j = 0; j < 2; j++) {
            int c = wx * 32 + j * 16 + l16;
            float bval = bias[rem0 + c];
            #pragma unroll
            for (int i = 0; i < 4; i++)
                #pragma unroll
                for (int r = 0; r < 4; r++) {
                    int row = wy * 64 + i * 16 + quad * 4 + r;
                    pool[c * PV + row] = f2bf(acc[i][j][r] + bval);
                }
        }
        __syncthreads();
        ushort_t* vout = Vtb + (size_t)(hh * HD) * NTOK + mb;
        for (int idx = tid; idx < 64 * 16; idx += 256) {
            int cc = idx >> 4, r8 = idx & 15;
            uint4 v = *(const uint4*)&pool[cc * PV + r8 * 8];
            *(uint4*)&vout[(size_t)cc * NTOK + r8 * 8] = v;
        }
    }
}

// ---------------------------------------------------------------------------
// Rel-pos bias via MFMA (outputs pre-scaled by log2 e). R19: unit =
// (isW,h,g,ms) -> 3456 units / 864 blocks (3.4 waves/SIMD, was 1.1) so
// the scattered 16B Q-row loads have TLP cover. Same per-(ms,ct) MFMA
// chain -> bitwise-identical relH/relWb.
// ---------------------------------------------------------------------------
__global__ __launch_bounds__(256) void k_relmm(
    const ushort_t* __restrict__ Qb, const ushort_t* __restrict__ rphb,
    const ushort_t* __restrict__ rpwb, float* __restrict__ relH,
    ushort_t* __restrict__ relWb) {
    int id = blockIdx.x * 4 + (threadIdx.x >> 6);   // 0..3455
    int lane = threadIdx.x & 63, quad = lane >> 4, l16 = lane & 15;
    bool isW = id >= 1728;
    int t = isW ? id - 1728 : id;
    int ms = t % 3;
    int g  = (t / 3) % GRD;
    int h  = t / (3 * GRD);
    const ushort_t* tab = isW ? rpwb : rphb;

    f32x4 zero = {0.f, 0.f, 0.f, 0.f};
    f32x4 acc[3];
    #pragma unroll
    for (int ct = 0; ct < 3; ct++) acc[ct] = zero;

    bf16x8 bfr[3][2];
    #pragma unroll
    for (int ct = 0; ct < 3; ct++) {
        int trow = g + 47 - (ct * 16 + l16);
        bfr[ct][0] = *(const bf16x8*)&tab[(size_t)trow * HD + quad * 8];
        bfr[ct][1] = *(const bf16x8*)&tab[(size_t)trow * HD + 32 + quad * 8];
    }
    {
        int m = ms * 16 + l16;
        int n = isW ? m * GRD + g : g * GRD + m;
        bf16x8 a0 = *(const bf16x8*)&Qb[(size_t)(h * NTOK + n) * HD + quad * 8];
        bf16x8 a1 = *(const bf16x8*)&Qb[(size_t)(h * NTOK + n) * HD + 32 + quad * 8];
        #pragma unroll
        for (int ct = 0; ct < 3; ct++) {
            acc[ct] = __builtin_amdgcn_mfma_f32_16x16x32_bf16(a0, bfr[ct][0], acc[ct], 0, 0, 0);
            acc[ct] = __builtin_amdgcn_mfma_f32_16x16x32_bf16(a1, bfr[ct][1], acc[ct], 0, 0, 0);
        }
    }
    #pragma unroll
    for (int ct = 0; ct < 3; ct++) {
        #pragma unroll
        for (int r = 0; r < 4; r++) {
            int m = ms * 16 + quad * 4 + r;
            int n = isW ? m * GRD + g : g * GRD + m;
            int col = ct * 16 + l16;
            float val = acc[ct][r] * LOG2E;
            if (isW)
                relWb[(size_t)(h * NTOK + n) * GRD + col] = f2bf(val);
            else
                relH[(size_t)(h * NTOK + n) * GRD + col] = val;
        }
    }
}

// ---------------------------------------------------------------------------
// Flash attention, split-K. Block = (128 q-rows, head, chunk of 768 keys).
// Grid 648 <= 768 capacity (3 blk/CU at (256,3)): single-phase. R16 core.
// ---------------------------------------------------------------------------
__global__ __launch_bounds__(256, 3) void k_attn(
    const ushort_t* __restrict__ Qb, const ushort_t* __restrict__ Kb,
    const ushort_t* __restrict__ Vtb, const float* __restrict__ relH,
    const ushort_t* __restrict__ relWb, float* __restrict__ Opart,
    float* __restrict__ Lpart) {
    int h = blockIdx.x / CHUNKS, chunk = blockIdx.x - h * CHUNKS;
    int qt = blockIdx.y;
    int tid = threadIdx.x;
    int wave = tid >> 6, lane = tid & 63, quad = lane >> 4, l16 = lane & 15;
    int qbase = qt * 128;
    int kbase = chunk * KEYS_PER_CHUNK;

    __shared__ __align__(16) ushort_t Ks[64 * 68];
    __shared__ __align__(16) ushort_t Vs[64 * 68];
    __shared__ __align__(16) ushort_t Ps[4][32 * 68];
    __shared__ __align__(16) ushort_t rhs[128 * 18];

    for (int i = tid; i < 128 * 16; i += 256) {
        int r = i >> 4, c = i & 15;
        rhs[r * 18 + c] = f2bf(relH[(size_t)(h * NTOK + qbase + r) * GRD + chunk * 16 + c]);
    }

    bf16x8 qf[2][2];
    #pragma unroll
    for (int s = 0; s < 2; s++) {
        int qrow = qbase + wave * 32 + s * 16 + l16;
        qf[s][0] = *(const bf16x8*)&Qb[(size_t)(h * NTOK + qrow) * HD + quad * 8];
        qf[s][1] = *(const bf16x8*)&Qb[(size_t)(h * NTOK + qrow) * HD + 32 + quad * 8];
    }

    int r0 = tid >> 3, c0 = (tid & 7) * 8;
    const ushort_t* kg0 = Kb + (size_t)(h * NTOK + r0) * HD + c0;
    const ushort_t* kg1 = Kb + (size_t)(h * NTOK + r0 + 32) * HD + c0;
    const ushort_t* vg0 = Vtb + (size_t)(h * HD + r0) * NTOK + c0;
    const ushort_t* vg1 = Vtb + (size_t)(h * HD + r0 + 32) * NTOK + c0;
    int sk0 = r0 * 68 + c0, sk1 = sk0 + 32 * 68;

    // per-lane relW row pointers (rows owned by this lane across s=0,1)
    const ushort_t* rw0 = relWb + (size_t)(h * NTOK + qbase + wave * 32 + l16) * GRD;
    const ushort_t* rw1 = rw0 + (size_t)16 * GRD;

    float lacc[2] = {0.f, 0.f};
    f32x4 zero = {0.f, 0.f, 0.f, 0.f};
    f32x4 oacc[2][4];
    #pragma unroll
    for (int s = 0; s < 2; s++)
        #pragma unroll
        for (int cs = 0; cs < 4; cs++) oacc[s][cs] = zero;

    const float scale2 = 0.125f * LOG2E;

    uint4 rk0 = *(const uint4*)(kg0 + (size_t)kbase * HD);
    uint4 rk1 = *(const uint4*)(kg1 + (size_t)kbase * HD);
    uint4 rv0 = *(const uint4*)(vg0 + kbase);
    uint4 rv1 = *(const uint4*)(vg1 + kbase);

    for (int kt = 0; kt < KT_PER; kt++) {
        int kb = kbase + kt * 64;

        __syncthreads();
        *(uint4*)&Ks[sk0] = rk0;  *(uint4*)&Ks[sk1] = rk1;
        *(uint4*)&Vs[sk0] = rv0;  *(uint4*)&Vs[sk1] = rv1;
        __syncthreads();

        // rwv for THIS kt, issued first: softmax's wait is vmcnt(4) so the
        // K/V loads below stay in flight; ~2 ds_reads + 2 MFMAs of cover.
        uint2 rwv[2][4];
        #pragma unroll
        for (int ks = 0; ks < 4; ks++) {
            int kb4 = kb + ks * 16 + quad * 4;
            int kh = kb4 / 48;
            int kw0 = kb4 - kh * 48;
            rwv[0][ks] = *(const uint2*)(rw0 + kw0);
            rwv[1][ks] = *(const uint2*)(rw1 + kw0);
        }

        if (kt < KT_PER - 1) {
            int kbn = kb + 64;
            rk0 = *(const uint4*)(kg0 + (size_t)kbn * HD);
            rk1 = *(const uint4*)(kg1 + (size_t)kbn * HD);
            rv0 = *(const uint4*)(vg0 + kbn);
            rv1 = *(const uint4*)(vg1 + kbn);
        }

        #pragma unroll
        for (int ks = 0; ks < 4; ks++) {
            bf16x8 kf0 = *(const bf16x8*)&Ks[(ks * 16 + l16) * 68 + quad * 8];
            bf16x8 kf1 = *(const bf16x8*)&Ks[(ks * 16 + l16) * 68 + 32 + quad * 8];
            f32x4 st[2];
            #pragma unroll
            for (int s = 0; s < 2; s++) {
                f32x4 z = zero;
                z = __builtin_amdgcn_mfma_f32_16x16x32_bf16(kf0, qf[s][0], z, 0, 0, 0);
                z = __builtin_amdgcn_mfma_f32_16x16x32_bf16(kf1, qf[s][1], z, 0, 0, 0);
                st[s] = z;
            }
            int kb4 = kb + ks * 16 + quad * 4;
            int khl = kb4 / 48 - chunk * 16;
            #pragma unroll
            for (int s = 0; s < 2; s++) {
                int row = wave * 32 + s * 16 + l16;
                float rh = bf2f(rhs[row * 18 + khl]);
                uint2 u = rwv[s][ks];
                float p0 = __builtin_amdgcn_exp2f(st[s][0] * scale2 + rh + __uint_as_float(u.x << 16));
                float p1 = __builtin_amdgcn_exp2f(st[s][1] * scale2 + rh + __uint_as_float(u.x & 0xffff0000u));
                float p2 = __builtin_amdgcn_exp2f(st[s][2] * scale2 + rh + __uint_as_float(u.y << 16));
                float p3 = __builtin_amdgcn_exp2f(st[s][3] * scale2 + rh + __uint_as_float(u.y & 0xffff0000u));
                lacc[s] += (p0 + p1) + (p2 + p3);
                uint2 w;
                w.x = __builtin_amdgcn_perm(__float_as_uint(p1), __float_as_uint(p0), 0x07060302u);
                w.y = __builtin_amdgcn_perm(__float_as_uint(p3), __float_as_uint(p2), 0x07060302u);
                *(uint2*)&Ps[wave][(s * 16 + l16) * 68 + ks * 16 + quad * 4] = w;
            }
        }

        bf16x8 vf[4][2];
        #pragma unroll
        for (int cs = 0; cs < 4; cs++) {
            vf[cs][0] = *(const bf16x8*)&Vs[(cs * 16 + l16) * 68 + quad * 8];
            vf[cs][1] = *(const bf16x8*)&Vs[(cs * 16 + l16) * 68 + 32 + quad * 8];
        }
        #pragma unroll
        for (int s = 0; s < 2; s++) {
            bf16x8 pa0 = *(const bf16x8*)&Ps[wave][(s * 16 + l16) * 68 + quad * 8];
            bf16x8 pa1 = *(const bf16x8*)&Ps[wave][(s * 16 + l16) * 68 + 32 + quad * 8];
            #pragma unroll
            for (int cs = 0; cs < 4; cs++) {
                oacc[s][cs] = __builtin_amdgcn_mfma_f32_16x16x32_bf16(pa0, vf[cs][0], oacc[s][cs], 0, 0, 0);
                oacc[s][cs] = __builtin_amdgcn_mfma_f32_16x16x32_bf16(pa1, vf[cs][1], oacc[s][cs], 0, 0, 0);
            }
        }
    }

    #pragma unroll
    for (int s = 0; s < 2; s++) {
        float l = lacc[s];
        l += __shfl_xor(l, 16);
        l += __shfl_xor(l, 32);
        lacc[s] = l;
    }

    size_t obase = (size_t)(chunk * HEADS + h) * NTOK;
    #pragma unroll
    for (int s = 0; s < 2; s++) {
        #pragma unroll
        for (int cs = 0; cs < 4; cs++) {
            #pragma unroll
            for (int r = 0; r < 4; r++) {
                int row = qbase + wave * 32 + s * 16 + quad * 4 + r;
                Opart[(obase + row) * HD + cs * 16 + l16] = oacc[s][cs][r];
            }
        }
        if (quad == 0)
            Lpart[obase + qbase + wave * 32 + s * 16 + l16] = lacc[s];
    }
}

// ---------------------------------------------------------------------------
// Merge split-K partials: Ob = (sum_ch O) / (sum_ch l), bf16.
// ---------------------------------------------------------------------------
__global__ __launch_bounds__(256) void k_merge(const float* __restrict__ Opart,
                                               const float* __restrict__ Lpart,
                                               ushort_t* __restrict__ Ob) {
    int t = blockIdx.x * 256 + threadIdx.x;
    int e = t * 4;
    int c = e & (HD - 1);
    int row = (e >> 6) % NTOK;
    int h = e / (NTOK * HD);
    const int ostride = HEADS * NTOK * HD;
    float4 s = {0.f, 0.f, 0.f, 0.f};
    float l = 0.f;
    #pragma unroll
    for (int ch = 0; ch < CHUNKS; ch++) {
        float4 v = *(const float4*)&Opart[(size_t)ch * ostride + e];
        s.x += v.x; s.y += v.y; s.z += v.z; s.w += v.w;
        l += Lpart[(size_t)(ch * HEADS + h) * NTOK + row];
    }
    float inv = 1.0f / l;
    ushort4 o = make_ushort4(f2bf(s.x * inv), f2bf(s.y * inv),
                             f2bf(s.z * inv), f2bf(s.w * inv));
    *(ushort4*)&Ob[(size_t)row * DIM + h * HD + c] = o;
}

// ---------------------------------------------------------------------------
// Output projection: 128(M)x64(N) tiles -> 216 blocks, BK=64 via two
// 32-col LDS planes (24 KB), 12 k-steps, 24 barriers.
// ---------------------------------------------------------------------------
__global__ __launch_bounds__(256) void k_gemm_proj(
    const ushort_t* __restrict__ Ob, const ushort_t* __restrict__ WTp,
    const float* __restrict__ bp, float* __restrict__ out) {
    __shared__ __align__(16) ushort_t As[2][128 * 32];   // 8 KB x2
    __shared__ __align__(16) ushort_t Bs[2][64 * 32];    // 4 KB x2
    int tid = threadIdx.x;
    int wave = tid >> 6, lane = tid & 63, quad = lane >> 4, l16 = lane & 15;
    int wx = wave & 1, wy = wave >> 1;
    int nb = blockIdx.x * 64, mb = blockIdx.y * 128;

    f32x4 zero = {0.f, 0.f, 0.f, 0.f};
    f32x4 acc[4][2];
    #pragma unroll
    for (int i = 0; i < 4; i++)
        #pragma unroll
        for (int j = 0; j < 2; j++) acc[i][j] = zero;

    int rl = lane >> 2;
    int cl = (lane & 3) * 8;
    const ushort_t* gA = Ob + (size_t)(mb + wave * 32 + rl) * DIM + cl;
    const ushort_t* gB = WTp + (size_t)(nb + wave * 16 + rl) * DIM + cl;
    ushort_t* lA0 = &As[0][(wave * 32) * 32];
    ushort_t* lA1 = &As[1][(wave * 32) * 32];
    ushort_t* lB0 = &Bs[0][(wave * 16) * 32];
    ushort_t* lB1 = &Bs[1][(wave * 16) * 32];

    for (int k0 = 0; k0 < DIM; k0 += 64) {
        __syncthreads();
        gload_lds16(gA + k0,                 lA0);
        gload_lds16(gA + k0 + 16 * DIM,      lA0 + 16 * 32);
        gload_lds16(gA + k0 + 32,            lA1);
        gload_lds16(gA + k0 + 32 + 16 * DIM, lA1 + 16 * 32);
        gload_lds16(gB + k0,                 lB0);
        gload_lds16(gB + k0 + 32,            lB1);
        __syncthreads();
        #pragma unroll
        for (int p = 0; p < 2; p++) {
            bf16x8 af[4], bf[2];
            #pragma unroll
            for (int i = 0; i < 4; i++)
                af[i] = *(const bf16x8*)&As[p][(wy * 64 + i * 16 + l16) * 32 + quad * 8];
            #pragma unroll
            for (int j = 0; j < 2; j++)
                bf[j] = *(const bf16x8*)&Bs[p][(wx * 32 + j * 16 + l16) * 32 + quad * 8];
            #pragma unroll
            for (int i = 0; i < 4; i++)
                #pragma unroll
                for (int j = 0; j < 2; j++)
                    acc[i][j] = __builtin_amdgcn_mfma_f32_16x16x32_bf16(af[i], bf[j], acc[i][j], 0, 0, 0);
        }
    }

    #pragma unroll
    for (int j = 0; j < 2; j++) {
        int col = nb + wx * 32 + j * 16 + l16;
        float bval = bp[col];
        #pragma unroll
        for (int i = 0; i < 4; i++) {
            #pragma unroll
            for (int r = 0; r < 4; r++) {
                int row = mb + wy * 64 + i * 16 + quad * 4 + r;
                out[(size_t)row * DIM + col] = acc[i][j][r] + bval;
            }
        }
    }
}

// ---------------------------------------------------------------------------
extern "C" void kernel_launch(void* const* d_in, const int* in_sizes, int n_in,
                              void* d_out, int out_size, void* d_ws, size_t ws_size,
                              hipStream_t stream) {
    const float* x   = (const float*)d_in[0];
    const float* Wq  = (const float*)d_in[1];
    const float* bq  = (const float*)d_in[2];
    const float* Wk  = (const float*)d_in[3];
    const float* bk  = (const float*)d_in[4];
    const float* Wv  = (const float*)d_in[5];
    const float* bv  = (const float*)d_in[6];
    const float* Wp  = (const float*)d_in[7];
    const float* bp  = (const float*)d_in[8];
    const float* rph = (const float*)d_in[9];
    const float* rpw = (const float*)d_in[10];
    const float* Aq  = (const float*)d_in[11];
    const float* Bq  = (const float*)d_in[12];
    const float* Ak  = (const float*)d_in[13];
    const float* Bk  = (const float*)d_in[14];
    const float* Av  = (const float*)d_in[15];
    const float* Bv  = (const float*)d_in[16];
    float* out = (float*)d_out;

    char* w = (char*)d_ws;
    size_t off = 0;
    auto carve = [&](size_t bytes) {
        char* p = w + off;
        off += (bytes + 255) & ~(size_t)255;
        return p;
    };
    ushort_t* xb    = (ushort_t*)carve((size_t)NTOK * DIM * 2);
    ushort_t* WT    = (ushort_t*)carve((size_t)4 * DIM * DIM * 2);
    ushort_t* Qb    = (ushort_t*)carve((size_t)HEADS * NTOK * HD * 2);
    ushort_t* Kb    = (ushort_t*)carve((size_t)HEADS * NTOK * HD * 2);
    ushort_t* Vtb   = (ushort_t*)carve((size_t)HEADS * HD * NTOK * 2);
    float*    relH  = (float*)carve((size_t)HEADS * NTOK * GRD * 4);
    ushort_t* relWb = (ushort_t*)carve((size_t)HEADS * NTOK * GRD * 2);
    ushort_t* Ob    = (ushort_t*)carve((size_t)NTOK * DIM * 2);
    float*    Opart = (float*)carve((size_t)CHUNKS * HEADS * NTOK * HD * 4);
    float*    Lpart = (float*)carve((size_t)CHUNKS * HEADS * NTOK * 4);
    ushort_t* rphb  = (ushort_t*)carve((size_t)(2 * GRD - 1) * HD * 2);
    ushort_t* rpwb  = (ushort_t*)carve((size_t)(2 * GRD - 1) * HD * 2);

    k_prep<<<dim3(2304), dim3(256), 0, stream>>>(
        x, xb, rph, rpw, rphb, rpwb,
        Wq, Wk, Wv, Wp, Aq, Bq, Ak, Bk, Av, Bv, WT);
    k_gemm_qkv<<<dim3(36, 18), dim3(256), 0, stream>>>(
        xb, WT, bq, bk, bv, Qb, Kb, Vtb);
    k_relmm<<<dim3(864), dim3(256), 0, stream>>>(
        Qb, rphb, rpwb, relH, relWb);
    k_attn<<<dim3(HEADS * CHUNKS, NTOK / 128), dim3(256), 0, stream>>>(
        Qb, Kb, Vtb, relH, relWb, Opart, Lpart);
    k_merge<<<dim3(HEADS * NTOK * HD / (256 * 4)), dim3(256), 0, stream>>>(
        Opart, Lpart, Ob);
    k_gemm_proj<<<dim3(12, 18), dim3(256), 0, stream>>>(
        Ob, WT + (size_t)3 * DIM * DIM, bp, out);
}

// Round 12
// 177.352 us; speedup vs baseline: 1.2167x; 1.0086x over previous
//
#include <hip/hip_runtime.h>

// ---------------------------------------------------------------------------
// LoRA_Attention: fold LoRA into weights; bf16 MFMA GEMMs; split-K flash
// attention. R20: (1) k_gemm_proj retiled 128x64 -> 64x64 (grid 216 -> 432
// blocks; 216 < 256 CUs left 40 CUs idle). Same K accumulation order ->
// bitwise-identical out. (2) k_attn: s_setprio(1) around S and PV MFMA
// clusters (T5 — 3 blocks/CU at independent phases = the attn-positive
// regime, m191). k_relmm occupancy-split (R19), qkv epilogue-coalesced
// (R18), BK=64 staging (R17), R16 attn core.
// ---------------------------------------------------------------------------

#define DIM   768
#define HEADS 12
#define HD    64
#define NTOK  2304
#define RANK  8
#define GRD   48
#define CHUNKS 3
#define KEYS_PER_CHUNK 768
#define KT_PER 12
#define LOG2E 1.44269504088896f

typedef __attribute__((ext_vector_type(8))) short bf16x8;
typedef __attribute__((ext_vector_type(4))) float f32x4;
typedef unsigned short ushort_t;

__device__ __forceinline__ unsigned short f2bf(float x) {
    union { float f; unsigned u; } v; v.f = x;
    unsigned r = v.u + 0x7fffu + ((v.u >> 16) & 1u);
    return (unsigned short)(r >> 16);
}
__device__ __forceinline__ float bf2f(unsigned short h) {
    return __uint_as_float(((unsigned)h) << 16);
}
__device__ __forceinline__ void gload_lds16(const ushort_t* g, ushort_t* l) {
    __builtin_amdgcn_global_load_lds(
        (const __attribute__((address_space(1))) unsigned int*)g,
        (__attribute__((address_space(3))) unsigned int*)l, 16, 0, 0);
}

// ---------------------------------------------------------------------------
// k_prep: fold LoRA into transposed weights (all 2304 blocks) + convert
// x / rel tables to bf16 (blocks < 1740). Independent tasks, one launch.
// WT write vectorized: 8 bf16 packed -> one 16B store (128 stores/block).
// ---------------------------------------------------------------------------
__global__ __launch_bounds__(256) void k_prep(
    const float* __restrict__ x, ushort_t* __restrict__ xb,
    const float* __restrict__ rph, const float* __restrict__ rpw,
    ushort_t* __restrict__ rphb, ushort_t* __restrict__ rpwb,
    const float* __restrict__ Wq, const float* __restrict__ Wk,
    const float* __restrict__ Wv, const float* __restrict__ Wp,
    const float* __restrict__ Aq, const float* __restrict__ Bq,
    const float* __restrict__ Ak, const float* __restrict__ Bk,
    const float* __restrict__ Av, const float* __restrict__ Bv,
    ushort_t* __restrict__ WT) {
    int bid = blockIdx.x, tid = threadIdx.x;

    if (bid < 1740) {
        if (bid < 1728) {
            int idx = (bid * 256 + tid) * 4;
            float4 v = *(const float4*)(x + idx);
            ushort4 o = make_ushort4(f2bf(v.x), f2bf(v.y), f2bf(v.z), f2bf(v.w));
            *(ushort4*)(xb + idx) = o;
        } else {
            int e = ((bid - 1728) * 256 + tid) * 4;
            const int TSZ = (2 * GRD - 1) * HD;   // 6080
            if (e < TSZ) {
                float4 v = *(const float4*)(rph + e);
                ushort4 o = make_ushort4(f2bf(v.x), f2bf(v.y), f2bf(v.z), f2bf(v.w));
                *(ushort4*)(rphb + e) = o;
            } else if (e < 2 * TSZ) {
                float4 v = *(const float4*)(rpw + e - TSZ);
                ushort4 o = make_ushort4(f2bf(v.x), f2bf(v.y), f2bf(v.z), f2bf(v.w));
                *(ushort4*)(rpwb + e - TSZ) = o;
            }
        }
    }

    int kb = (bid % 24) * 32;
    int nb = (bid / 24) * 32;
    int sel = nb / DIM, nmod = nb % DIM;
    const float* W = (sel == 0) ? Wq : (sel == 1) ? Wk : (sel == 2) ? Wv : Wp;
    const float* A = (sel == 0) ? Aq : (sel == 1) ? Ak : Av;
    const float* B = (sel == 0) ? Bq : (sel == 1) ? Bk : Bv;
    __shared__ float T[32][33];
    for (int i = tid; i < 1024; i += 256) {
        int kl = i >> 5, nl = i & 31;
        float v = W[(kb + kl) * DIM + nmod + nl];
        if (sel < 3) {
            #pragma unroll
            for (int r = 0; r < RANK; r++)
                v += A[(kb + kl) * RANK + r] * B[r * DIM + nmod + nl];
        }
        T[kl][nl] = v;
    }
    __syncthreads();
    if (tid < 128) {
        int nl = tid >> 2, k8 = (tid & 3) * 8;
        ushort_t tmp[8];
        #pragma unroll
        for (int q = 0; q < 8; q++) tmp[q] = f2bf(T[k8 + q][nl]);
        *(uint4*)&WT[(size_t)(nb + nl) * DIM + kb + k8] = *(const uint4*)tmp;
    }
}

// ---------------------------------------------------------------------------
// QKV GEMM: 128(M)x64(N) tiles -> 648 blocks, BK=64 (two 32-col planes,
// 24 KB pool). Epilogue repacked through the SAME pool (R18): Q/K ->
// [128][72] tile, 16B row-burst stores; V -> pre-transposed [64][136]
// tile, 256B contiguous Vtb runs. Block's 64 cols = one (matrix, head).
// ---------------------------------------------------------------------------
__global__ __launch_bounds__(256) void k_gemm_qkv(
    const ushort_t* __restrict__ xb, const ushort_t* __restrict__ WT,
    const float* __restrict__ bq, const float* __restrict__ bk,
    const float* __restrict__ bv,
    ushort_t* __restrict__ Qb, ushort_t* __restrict__ Kb,
    ushort_t* __restrict__ Vtb) {
    __shared__ __align__(16) ushort_t pool[12288];   // 24 KB
    ushort_t* As0 = pool;                // 128*32
    ushort_t* As1 = pool + 4096;
    ushort_t* Bs0 = pool + 8192;         // 64*32
    ushort_t* Bs1 = pool + 10240;
    int tid = threadIdx.x;
    int wave = tid >> 6, lane = tid & 63, quad = lane >> 4, l16 = lane & 15;
    int wx = wave & 1, wy = wave >> 1;
    int nb = blockIdx.x * 64, mb = blockIdx.y * 128;

    f32x4 zero = {0.f, 0.f, 0.f, 0.f};
    f32x4 acc[4][2];
    #pragma unroll
    for (int i = 0; i < 4; i++)
        #pragma unroll
        for (int j = 0; j < 2; j++) acc[i][j] = zero;

    int rl = lane >> 2;            // 0..15
    int cl = (lane & 3) * 8;       // element col within 32
    const ushort_t* gA = xb + (size_t)(mb + wave * 32 + rl) * DIM + cl;
    const ushort_t* gB = WT + (size_t)(nb + wave * 16 + rl) * DIM + cl;
    ushort_t* lA0 = As0 + (wave * 32) * 32;
    ushort_t* lA1 = As1 + (wave * 32) * 32;
    ushort_t* lB0 = Bs0 + (wave * 16) * 32;
    ushort_t* lB1 = Bs1 + (wave * 16) * 32;

    for (int k0 = 0; k0 < DIM; k0 += 64) {
        __syncthreads();
        gload_lds16(gA + k0,                 lA0);
        gload_lds16(gA + k0 + 16 * DIM,      lA0 + 16 * 32);
        gload_lds16(gA + k0 + 32,            lA1);
        gload_lds16(gA + k0 + 32 + 16 * DIM, lA1 + 16 * 32);
        gload_lds16(gB + k0,                 lB0);
        gload_lds16(gB + k0 + 32,            lB1);
        __syncthreads();
        #pragma unroll
        for (int p = 0; p < 2; p++) {
            const ushort_t* Ap = p ? As1 : As0;
            const ushort_t* Bp = p ? Bs1 : Bs0;
            bf16x8 af[4], bf[2];
            #pragma unroll
            for (int i = 0; i < 4; i++)
                af[i] = *(const bf16x8*)&Ap[(wy * 64 + i * 16 + l16) * 32 + quad * 8];
            #pragma unroll
            for (int j = 0; j < 2; j++)
                bf[j] = *(const bf16x8*)&Bp[(wx * 32 + j * 16 + l16) * 32 + quad * 8];
            #pragma unroll
            for (int i = 0; i < 4; i++)
                #pragma unroll
                for (int j = 0; j < 2; j++)
                    acc[i][j] = __builtin_amdgcn_mfma_f32_16x16x32_bf16(af[i], bf[j], acc[i][j], 0, 0, 0);
        }
    }

    // ---- epilogue: bias + convert + LDS repack + coalesced stores ----
    int sel = nb / DIM;
    int rem0 = nb - sel * DIM;
    int hh = rem0 >> 6;
    const float* bias = (sel == 0) ? bq : (sel == 1) ? bk : bv;

    __syncthreads();   // all staging reads done; pool is reusable

    if (sel < 2) {
        const int P = 72;   // row pitch (144B = 9x16B: aligned, bank-rotating)
        #pragma unroll
        for (int j = 0; j < 2; j++) {
            int c = wx * 32 + j * 16 + l16;
            float bval = bias[rem0 + c];
            #pragma unroll
            for (int i = 0; i < 4; i++)
                #pragma unroll
                for (int r = 0; r < 4; r++) {
                    int row = wy * 64 + i * 16 + quad * 4 + r;
                    pool[row * P + c] = f2bf(acc[i][j][r] + bval);
                }
        }
        __syncthreads();
        ushort_t* qout = ((sel == 0) ? Qb : Kb) + (size_t)(hh * NTOK + mb) * HD;
        for (int idx = tid; idx < 128 * 8; idx += 256) {
            int row = idx >> 3, s8 = idx & 7;
            uint4 v = *(const uint4*)&pool[row * P + s8 * 8];
            *(uint4*)&qout[(size_t)row * HD + s8 * 8] = v;
        }
    } else {
        const int PV = 136; // col pitch (272B = 17x16B: aligned)
        #pragma unroll
        for (int j = 0; j < 2; j++) {
            int c = wx * 32 + j * 16 + l16;
            float bval = bias[rem0 + c];
            #pragma unroll
            for (int i = 0; i < 4; i++)
                #pragma unroll
                for (int r = 0; r < 4; r++) {
                    int row = wy * 64 + i * 16 + quad * 4 + r;
                    pool[c * PV + row] = f2bf(acc[i][j][r] + bval);
                }
        }
        __syncthreads();
        ushort_t* vout = Vtb + (size_t)(hh * HD) * NTOK + mb;
        for (int idx = tid; idx < 64 * 16; idx += 256) {
            int cc = idx >> 4, r8 = idx & 15;
            uint4 v = *(const uint4*)&pool[cc * PV + r8 * 8];
            *(uint4*)&vout[(size_t)cc * NTOK + r8 * 8] = v;
        }
    }
}

// ---------------------------------------------------------------------------
// Rel-pos bias via MFMA (outputs pre-scaled by log2 e). R19 decomposition:
// unit = (isW,h,g,ms) -> 3456 units / 864 blocks (3.4 waves/SIMD).
// ---------------------------------------------------------------------------
__global__ __launch_bounds__(256) void k_relmm(
    const ushort_t* __restrict__ Qb, const ushort_t* __restrict__ rphb,
    const ushort_t* __restrict__ rpwb, float* __restrict__ relH,
    ushort_t* __restrict__ relWb) {
    int id = blockIdx.x * 4 + (threadIdx.x >> 6);   // 0..3455
    int lane = threadIdx.x & 63, quad = lane >> 4, l16 = lane & 15;
    bool isW = id >= 1728;
    int t = isW ? id - 1728 : id;
    int ms = t % 3;
    int g  = (t / 3) % GRD;
    int h  = t / (3 * GRD);
    const ushort_t* tab = isW ? rpwb : rphb;

    f32x4 zero = {0.f, 0.f, 0.f, 0.f};
    f32x4 acc[3];
    #pragma unroll
    for (int ct = 0; ct < 3; ct++) acc[ct] = zero;

    bf16x8 bfr[3][2];
    #pragma unroll
    for (int ct = 0; ct < 3; ct++) {
        int trow = g + 47 - (ct * 16 + l16);
        bfr[ct][0] = *(const bf16x8*)&tab[(size_t)trow * HD + quad * 8];
        bfr[ct][1] = *(const bf16x8*)&tab[(size_t)trow * HD + 32 + quad * 8];
    }
    {
        int m = ms * 16 + l16;
        int n = isW ? m * GRD + g : g * GRD + m;
        bf16x8 a0 = *(const bf16x8*)&Qb[(size_t)(h * NTOK + n) * HD + quad * 8];
        bf16x8 a1 = *(const bf16x8*)&Qb[(size_t)(h * NTOK + n) * HD + 32 + quad * 8];
        #pragma unroll
        for (int ct = 0; ct < 3; ct++) {
            acc[ct] = __builtin_amdgcn_mfma_f32_16x16x32_bf16(a0, bfr[ct][0], acc[ct], 0, 0, 0);
            acc[ct] = __builtin_amdgcn_mfma_f32_16x16x32_bf16(a1, bfr[ct][1], acc[ct], 0, 0, 0);
        }
    }
    #pragma unroll
    for (int ct = 0; ct < 3; ct++) {
        #pragma unroll
        for (int r = 0; r < 4; r++) {
            int m = ms * 16 + quad * 4 + r;
            int n = isW ? m * GRD + g : g * GRD + m;
            int col = ct * 16 + l16;
            float val = acc[ct][r] * LOG2E;
            if (isW)
                relWb[(size_t)(h * NTOK + n) * GRD + col] = f2bf(val);
            else
                relH[(size_t)(h * NTOK + n) * GRD + col] = val;
        }
    }
}

// ---------------------------------------------------------------------------
// Flash attention, split-K. Block = (128 q-rows, head, chunk of 768 keys).
// Grid 648 <= 768 capacity (3 blk/CU at (256,3)): single-phase. R16 core
// + s_setprio(1) around the S and PV MFMA clusters (T5).
// ---------------------------------------------------------------------------
__global__ __launch_bounds__(256, 3) void k_attn(
    const ushort_t* __restrict__ Qb, const ushort_t* __restrict__ Kb,
    const ushort_t* __restrict__ Vtb, const float* __restrict__ relH,
    const ushort_t* __restrict__ relWb, float* __restrict__ Opart,
    float* __restrict__ Lpart) {
    int h = blockIdx.x / CHUNKS, chunk = blockIdx.x - h * CHUNKS;
    int qt = blockIdx.y;
    int tid = threadIdx.x;
    int wave = tid >> 6, lane = tid & 63, quad = lane >> 4, l16 = lane & 15;
    int qbase = qt * 128;
    int kbase = chunk * KEYS_PER_CHUNK;

    __shared__ __align__(16) ushort_t Ks[64 * 68];
    __shared__ __align__(16) ushort_t Vs[64 * 68];
    __shared__ __align__(16) ushort_t Ps[4][32 * 68];
    __shared__ __align__(16) ushort_t rhs[128 * 18];

    for (int i = tid; i < 128 * 16; i += 256) {
        int r = i >> 4, c = i & 15;
        rhs[r * 18 + c] = f2bf(relH[(size_t)(h * NTOK + qbase + r) * GRD + chunk * 16 + c]);
    }

    bf16x8 qf[2][2];
    #pragma unroll
    for (int s = 0; s < 2; s++) {
        int qrow = qbase + wave * 32 + s * 16 + l16;
        qf[s][0] = *(const bf16x8*)&Qb[(size_t)(h * NTOK + qrow) * HD + quad * 8];
        qf[s][1] = *(const bf16x8*)&Qb[(size_t)(h * NTOK + qrow) * HD + 32 + quad * 8];
    }

    int r0 = tid >> 3, c0 = (tid & 7) * 8;
    const ushort_t* kg0 = Kb + (size_t)(h * NTOK + r0) * HD + c0;
    const ushort_t* kg1 = Kb + (size_t)(h * NTOK + r0 + 32) * HD + c0;
    const ushort_t* vg0 = Vtb + (size_t)(h * HD + r0) * NTOK + c0;
    const ushort_t* vg1 = Vtb + (size_t)(h * HD + r0 + 32) * NTOK + c0;
    int sk0 = r0 * 68 + c0, sk1 = sk0 + 32 * 68;

    // per-lane relW row pointers (rows owned by this lane across s=0,1)
    const ushort_t* rw0 = relWb + (size_t)(h * NTOK + qbase + wave * 32 + l16) * GRD;
    const ushort_t* rw1 = rw0 + (size_t)16 * GRD;

    float lacc[2] = {0.f, 0.f};
    f32x4 zero = {0.f, 0.f, 0.f, 0.f};
    f32x4 oacc[2][4];
    #pragma unroll
    for (int s = 0; s < 2; s++)
        #pragma unroll
        for (int cs = 0; cs < 4; cs++) oacc[s][cs] = zero;

    const float scale2 = 0.125f * LOG2E;

    uint4 rk0 = *(const uint4*)(kg0 + (size_t)kbase * HD);
    uint4 rk1 = *(const uint4*)(kg1 + (size_t)kbase * HD);
    uint4 rv0 = *(const uint4*)(vg0 + kbase);
    uint4 rv1 = *(const uint4*)(vg1 + kbase);

    for (int kt = 0; kt < KT_PER; kt++) {
        int kb = kbase + kt * 64;

        __syncthreads();
        *(uint4*)&Ks[sk0] = rk0;  *(uint4*)&Ks[sk1] = rk1;
        *(uint4*)&Vs[sk0] = rv0;  *(uint4*)&Vs[sk1] = rv1;
        __syncthreads();

        // rwv for THIS kt, issued first: softmax's wait is vmcnt(4) so the
        // K/V loads below stay in flight; ~2 ds_reads + 2 MFMAs of cover.
        uint2 rwv[2][4];
        #pragma unroll
        for (int ks = 0; ks < 4; ks++) {
            int kb4 = kb + ks * 16 + quad * 4;
            int kh = kb4 / 48;
            int kw0 = kb4 - kh * 48;
            rwv[0][ks] = *(const uint2*)(rw0 + kw0);
            rwv[1][ks] = *(const uint2*)(rw1 + kw0);
        }

        if (kt < KT_PER - 1) {
            int kbn = kb + 64;
            rk0 = *(const uint4*)(kg0 + (size_t)kbn * HD);
            rk1 = *(const uint4*)(kg1 + (size_t)kbn * HD);
            rv0 = *(const uint4*)(vg0 + kbn);
            rv1 = *(const uint4*)(vg1 + kbn);
        }

        #pragma unroll
        for (int ks = 0; ks < 4; ks++) {
            bf16x8 kf0 = *(const bf16x8*)&Ks[(ks * 16 + l16) * 68 + quad * 8];
            bf16x8 kf1 = *(const bf16x8*)&Ks[(ks * 16 + l16) * 68 + 32 + quad * 8];
            f32x4 st[2];
            __builtin_amdgcn_s_setprio(1);
            #pragma unroll
            for (int s = 0; s < 2; s++) {
                f32x4 z = zero;
                z = __builtin_amdgcn_mfma_f32_16x16x32_bf16(kf0, qf[s][0], z, 0, 0, 0);
                z = __builtin_amdgcn_mfma_f32_16x16x32_bf16(kf1, qf[s][1], z, 0, 0, 0);
                st[s] = z;
            }
            __builtin_amdgcn_s_setprio(0);
            int kb4 = kb + ks * 16 + quad * 4;
            int khl = kb4 / 48 - chunk * 16;
            #pragma unroll
            for (int s = 0; s < 2; s++) {
                int row = wave * 32 + s * 16 + l16;
                float rh = bf2f(rhs[row * 18 + khl]);
                uint2 u = rwv[s][ks];
                float p0 = __builtin_amdgcn_exp2f(st[s][0] * scale2 + rh + __uint_as_float(u.x << 16));
                float p1 = __builtin_amdgcn_exp2f(st[s][1] * scale2 + rh + __uint_as_float(u.x & 0xffff0000u));
                float p2 = __builtin_amdgcn_exp2f(st[s][2] * scale2 + rh + __uint_as_float(u.y << 16));
                float p3 = __builtin_amdgcn_exp2f(st[s][3] * scale2 + rh + __uint_as_float(u.y & 0xffff0000u));
                lacc[s] += (p0 + p1) + (p2 + p3);
                uint2 w;
                w.x = __builtin_amdgcn_perm(__float_as_uint(p1), __float_as_uint(p0), 0x07060302u);
                w.y = __builtin_amdgcn_perm(__float_as_uint(p3), __float_as_uint(p2), 0x07060302u);
                *(uint2*)&Ps[wave][(s * 16 + l16) * 68 + ks * 16 + quad * 4] = w;
            }
        }

        bf16x8 vf[4][2];
        #pragma unroll
        for (int cs = 0; cs < 4; cs++) {
            vf[cs][0] = *(const bf16x8*)&Vs[(cs * 16 + l16) * 68 + quad * 8];
            vf[cs][1] = *(const bf16x8*)&Vs[(cs * 16 + l16) * 68 + 32 + quad * 8];
        }
        __builtin_amdgcn_s_setprio(1);
        #pragma unroll
        for (int s = 0; s < 2; s++) {
            bf16x8 pa0 = *(const bf16x8*)&Ps[wave][(s * 16 + l16) * 68 + quad * 8];
            bf16x8 pa1 = *(const bf16x8*)&Ps[wave][(s * 16 + l16) * 68 + 32 + quad * 8];
            #pragma unroll
            for (int cs = 0; cs < 4; cs++) {
                oacc[s][cs] = __builtin_amdgcn_mfma_f32_16x16x32_bf16(pa0, vf[cs][0], oacc[s][cs], 0, 0, 0);
                oacc[s][cs] = __builtin_amdgcn_mfma_f32_16x16x32_bf16(pa1, vf[cs][1], oacc[s][cs], 0, 0, 0);
            }
        }
        __builtin_amdgcn_s_setprio(0);
    }

    #pragma unroll
    for (int s = 0; s < 2; s++) {
        float l = lacc[s];
        l += __shfl_xor(l, 16);
        l += __shfl_xor(l, 32);
        lacc[s] = l;
    }

    size_t obase = (size_t)(chunk * HEADS + h) * NTOK;
    #pragma unroll
    for (int s = 0; s < 2; s++) {
        #pragma unroll
        for (int cs = 0; cs < 4; cs++) {
            #pragma unroll
            for (int r = 0; r < 4; r++) {
                int row = qbase + wave * 32 + s * 16 + quad * 4 + r;
                Opart[(obase + row) * HD + cs * 16 + l16] = oacc[s][cs][r];
            }
        }
        if (quad == 0)
            Lpart[obase + qbase + wave * 32 + s * 16 + l16] = lacc[s];
    }
}

// ---------------------------------------------------------------------------
// Merge split-K partials: Ob = (sum_ch O) / (sum_ch l), bf16.
// ---------------------------------------------------------------------------
__global__ __launch_bounds__(256) void k_merge(const float* __restrict__ Opart,
                                               const float* __restrict__ Lpart,
                                               ushort_t* __restrict__ Ob) {
    int t = blockIdx.x * 256 + threadIdx.x;
    int e = t * 4;
    int c = e & (HD - 1);
    int row = (e >> 6) % NTOK;
    int h = e / (NTOK * HD);
    const int ostride = HEADS * NTOK * HD;
    float4 s = {0.f, 0.f, 0.f, 0.f};
    float l = 0.f;
    #pragma unroll
    for (int ch = 0; ch < CHUNKS; ch++) {
        float4 v = *(const float4*)&Opart[(size_t)ch * ostride + e];
        s.x += v.x; s.y += v.y; s.z += v.z; s.w += v.w;
        l += Lpart[(size_t)(ch * HEADS + h) * NTOK + row];
    }
    float inv = 1.0f / l;
    ushort4 o = make_ushort4(f2bf(s.x * inv), f2bf(s.y * inv),
                             f2bf(s.z * inv), f2bf(s.w * inv));
    *(ushort4*)&Ob[(size_t)row * DIM + h * HD + c] = o;
}

// ---------------------------------------------------------------------------
// Output projection: 64(M)x64(N) tiles -> 432 blocks (was 216 < 256 CUs:
// 40 CUs idle). BK=64 via two 32-col LDS planes (16 KB). Same K
// accumulation order per output element -> bitwise-identical out.
// Waves 2x2: wave = 32 rows x 32 cols.
// ---------------------------------------------------------------------------
__global__ __launch_bounds__(256) void k_gemm_proj(
    const ushort_t* __restrict__ Ob, const ushort_t* __restrict__ WTp,
    const float* __restrict__ bp, float* __restrict__ out) {
    __shared__ __align__(16) ushort_t As[2][64 * 32];    // 4 KB x2
    __shared__ __align__(16) ushort_t Bs[2][64 * 32];    // 4 KB x2
    int tid = threadIdx.x;
    int wave = tid >> 6, lane = tid & 63, quad = lane >> 4, l16 = lane & 15;
    int wx = wave & 1, wy = wave >> 1;
    int nb = blockIdx.x * 64, mb = blockIdx.y * 64;

    f32x4 zero = {0.f, 0.f, 0.f, 0.f};
    f32x4 acc[2][2];
    #pragma unroll
    for (int i = 0; i < 2; i++)
        #pragma unroll
        for (int j = 0; j < 2; j++) acc[i][j] = zero;

    int rl = lane >> 2;
    int cl = (lane & 3) * 8;
    const ushort_t* gA = Ob + (size_t)(mb + wave * 16 + rl) * DIM + cl;
    const ushort_t* gB = WTp + (size_t)(nb + wave * 16 + rl) * DIM + cl;
    ushort_t* lA0 = &As[0][(wave * 16) * 32];
    ushort_t* lA1 = &As[1][(wave * 16) * 32];
    ushort_t* lB0 = &Bs[0][(wave * 16) * 32];
    ushort_t* lB1 = &Bs[1][(wave * 16) * 32];

    for (int k0 = 0; k0 < DIM; k0 += 64) {
        __syncthreads();
        gload_lds16(gA + k0,      lA0);
        gload_lds16(gA + k0 + 32, lA1);
        gload_lds16(gB + k0,      lB0);
        gload_lds16(gB + k0 + 32, lB1);
        __syncthreads();
        #pragma unroll
        for (int p = 0; p < 2; p++) {
            bf16x8 af[2], bf[2];
            #pragma unroll
            for (int i = 0; i < 2; i++)
                af[i] = *(const bf16x8*)&As[p][(wy * 32 + i * 16 + l16) * 32 + quad * 8];
            #pragma unroll
            for (int j = 0; j < 2; j++)
                bf[j] = *(const bf16x8*)&Bs[p][(wx * 32 + j * 16 + l16) * 32 + quad * 8];
            #pragma unroll
            for (int i = 0; i < 2; i++)
                #pragma unroll
                for (int j = 0; j < 2; j++)
                    acc[i][j] = __builtin_amdgcn_mfma_f32_16x16x32_bf16(af[i], bf[j], acc[i][j], 0, 0, 0);
        }
    }

    #pragma unroll
    for (int j = 0; j < 2; j++) {
        int col = nb + wx * 32 + j * 16 + l16;
        float bval = bp[col];
        #pragma unroll
        for (int i = 0; i < 2; i++) {
            #pragma unroll
            for (int r = 0; r < 4; r++) {
                int row = mb + wy * 32 + i * 16 + quad * 4 + r;
                out[(size_t)row * DIM + col] = acc[i][j][r] + bval;
            }
        }
    }
}

// ---------------------------------------------------------------------------
extern "C" void kernel_launch(void* const* d_in, const int* in_sizes, int n_in,
                              void* d_out, int out_size, void* d_ws, size_t ws_size,
                              hipStream_t stream) {
    const float* x   = (const float*)d_in[0];
    const float* Wq  = (const float*)d_in[1];
    const float* bq  = (const float*)d_in[2];
    const float* Wk  = (const float*)d_in[3];
    const float* bk  = (const float*)d_in[4];
    const float* Wv  = (const float*)d_in[5];
    const float* bv  = (const float*)d_in[6];
    const float* Wp  = (const float*)d_in[7];
    const float* bp  = (const float*)d_in[8];
    const float* rph = (const float*)d_in[9];
    const float* rpw = (const float*)d_in[10];
    const float* Aq  = (const float*)d_in[11];
    const float* Bq  = (const float*)d_in[12];
    const float* Ak  = (const float*)d_in[13];
    const float* Bk  = (const float*)d_in[14];
    const float* Av  = (const float*)d_in[15];
    const float* Bv  = (const float*)d_in[16];
    float* out = (float*)d_out;

    char* w = (char*)d_ws;
    size_t off = 0;
    auto carve = [&](size_t bytes) {
        char* p = w + off;
        off += (bytes + 255) & ~(size_t)255;
        return p;
    };
    ushort_t* xb    = (ushort_t*)carve((size_t)NTOK * DIM * 2);
    ushort_t* WT    = (ushort_t*)carve((size_t)4 * DIM * DIM * 2);
    ushort_t* Qb    = (ushort_t*)carve((size_t)HEADS * NTOK * HD * 2);
    ushort_t* Kb    = (ushort_t*)carve((size_t)HEADS * NTOK * HD * 2);
    ushort_t* Vtb   = (ushort_t*)carve((size_t)HEADS * HD * NTOK * 2);
    float*    relH  = (float*)carve((size_t)HEADS * NTOK * GRD * 4);
    ushort_t* relWb = (ushort_t*)carve((size_t)HEADS * NTOK * GRD * 2);
    ushort_t* Ob    = (ushort_t*)carve((size_t)NTOK * DIM * 2);
    float*    Opart = (float*)carve((size_t)CHUNKS * HEADS * NTOK * HD * 4);
    float*    Lpart = (float*)carve((size_t)CHUNKS * HEADS * NTOK * 4);
    ushort_t* rphb  = (ushort_t*)carve((size_t)(2 * GRD - 1) * HD * 2);
    ushort_t* rpwb  = (ushort_t*)carve((size_t)(2 * GRD - 1) * HD * 2);

    k_prep<<<dim3(2304), dim3(256), 0, stream>>>(
        x, xb, rph, rpw, rphb, rpwb,
        Wq, Wk, Wv, Wp, Aq, Bq, Ak, Bk, Av, Bv, WT);
    k_gemm_qkv<<<dim3(36, 18), dim3(256), 0, stream>>>(
        xb, WT, bq, bk, bv, Qb, Kb, Vtb);
    k_relmm<<<dim3(864), dim3(256), 0, stream>>>(
        Qb, rphb, rpwb, relH, relWb);
    k_attn<<<dim3(HEADS * CHUNKS, NTOK / 128), dim3(256), 0, stream>>>(
        Qb, Kb, Vtb, relH, relWb, Opart, Lpart);
    k_merge<<<dim3(HEADS * NTOK * HD / (256 * 4)), dim3(256), 0, stream>>>(
        Opart, Lpart, Ob);
    k_gemm_proj<<<dim3(12, 36), dim3(256), 0, stream>>>(
        Ob, WT + (size_t)3 * DIM * DIM, bp, out);
}

// Round 13
// 172.637 us; speedup vs baseline: 1.2499x; 1.0273x over previous
//
#include <hip/hip_runtime.h>

// ---------------------------------------------------------------------------
// LoRA_Attention. R21: (1) qkv/proj staging truly pipelined — double-buffered
// LDS (qkv 48KB, proj 32KB), issue next tile's global_load_lds then counted
// "s_waitcnt vmcnt(6/4)" + raw s_barrier (T4 pattern): the vmcnt(0) drain
// R17 only halved is now off the critical path entirely. Compute order
// unchanged -> bitwise-identical. (2) k_attn: per-ks div-by-48 (8/kt)
// replaced by incremental mod-48 counter chain (serial-VALU diet; k_attn
// is wave-serial-issue bound: inferred 1.5us*CU/kt-block == measured 1/rho).
// R18 epilogue repack, R19 relmm split, R20 proj grid + setprio kept.
// ---------------------------------------------------------------------------

#define DIM   768
#define HEADS 12
#define HD    64
#define NTOK  2304
#define RANK  8
#define GRD   48
#define CHUNKS 3
#define KEYS_PER_CHUNK 768
#define KT_PER 12
#define LOG2E 1.44269504088896f

typedef __attribute__((ext_vector_type(8))) short bf16x8;
typedef __attribute__((ext_vector_type(4))) float f32x4;
typedef unsigned short ushort_t;

__device__ __forceinline__ unsigned short f2bf(float x) {
    union { float f; unsigned u; } v; v.f = x;
    unsigned r = v.u + 0x7fffu + ((v.u >> 16) & 1u);
    return (unsigned short)(r >> 16);
}
__device__ __forceinline__ float bf2f(unsigned short h) {
    return __uint_as_float(((unsigned)h) << 16);
}
__device__ __forceinline__ void gload_lds16(const ushort_t* g, ushort_t* l) {
    __builtin_amdgcn_global_load_lds(
        (const __attribute__((address_space(1))) unsigned int*)g,
        (__attribute__((address_space(3))) unsigned int*)l, 16, 0, 0);
}

// ---------------------------------------------------------------------------
// k_prep: fold LoRA into transposed weights (all 2304 blocks) + convert
// x / rel tables to bf16 (blocks < 1740). Independent tasks, one launch.
// ---------------------------------------------------------------------------
__global__ __launch_bounds__(256) void k_prep(
    const float* __restrict__ x, ushort_t* __restrict__ xb,
    const float* __restrict__ rph, const float* __restrict__ rpw,
    ushort_t* __restrict__ rphb, ushort_t* __restrict__ rpwb,
    const float* __restrict__ Wq, const float* __restrict__ Wk,
    const float* __restrict__ Wv, const float* __restrict__ Wp,
    const float* __restrict__ Aq, const float* __restrict__ Bq,
    const float* __restrict__ Ak, const float* __restrict__ Bk,
    const float* __restrict__ Av, const float* __restrict__ Bv,
    ushort_t* __restrict__ WT) {
    int bid = blockIdx.x, tid = threadIdx.x;

    if (bid < 1740) {
        if (bid < 1728) {
            int idx = (bid * 256 + tid) * 4;
            float4 v = *(const float4*)(x + idx);
            ushort4 o = make_ushort4(f2bf(v.x), f2bf(v.y), f2bf(v.z), f2bf(v.w));
            *(ushort4*)(xb + idx) = o;
        } else {
            int e = ((bid - 1728) * 256 + tid) * 4;
            const int TSZ = (2 * GRD - 1) * HD;   // 6080
            if (e < TSZ) {
                float4 v = *(const float4*)(rph + e);
                ushort4 o = make_ushort4(f2bf(v.x), f2bf(v.y), f2bf(v.z), f2bf(v.w));
                *(ushort4*)(rphb + e) = o;
            } else if (e < 2 * TSZ) {
                float4 v = *(const float4*)(rpw + e - TSZ);
                ushort4 o = make_ushort4(f2bf(v.x), f2bf(v.y), f2bf(v.z), f2bf(v.w));
                *(ushort4*)(rpwb + e - TSZ) = o;
            }
        }
    }

    int kb = (bid % 24) * 32;
    int nb = (bid / 24) * 32;
    int sel = nb / DIM, nmod = nb % DIM;
    const float* W = (sel == 0) ? Wq : (sel == 1) ? Wk : (sel == 2) ? Wv : Wp;
    const float* A = (sel == 0) ? Aq : (sel == 1) ? Ak : Av;
    const float* B = (sel == 0) ? Bq : (sel == 1) ? Bk : Bv;
    __shared__ float T[32][33];
    for (int i = tid; i < 1024; i += 256) {
        int kl = i >> 5, nl = i & 31;
        float v = W[(kb + kl) * DIM + nmod + nl];
        if (sel < 3) {
            #pragma unroll
            for (int r = 0; r < RANK; r++)
                v += A[(kb + kl) * RANK + r] * B[r * DIM + nmod + nl];
        }
        T[kl][nl] = v;
    }
    __syncthreads();
    if (tid < 128) {
        int nl = tid >> 2, k8 = (tid & 3) * 8;
        ushort_t tmp[8];
        #pragma unroll
        for (int q = 0; q < 8; q++) tmp[q] = f2bf(T[k8 + q][nl]);
        *(uint4*)&WT[(size_t)(nb + nl) * DIM + kb + k8] = *(const uint4*)tmp;
    }
}

// ---------------------------------------------------------------------------
// QKV GEMM: 128(M)x64(N) tiles -> 648 blocks, BK=64, DOUBLE-BUFFERED
// staging (48 KB): stage(next) -> vmcnt(6) -> s_barrier -> compute ->
// s_barrier. No vmcnt(0) drain in steady state. R18 coalesced epilogue.
// ---------------------------------------------------------------------------
__global__ __launch_bounds__(256) void k_gemm_qkv(
    const ushort_t* __restrict__ xb, const ushort_t* __restrict__ WT,
    const float* __restrict__ bq, const float* __restrict__ bk,
    const float* __restrict__ bv,
    ushort_t* __restrict__ Qb, ushort_t* __restrict__ Kb,
    ushort_t* __restrict__ Vtb) {
    __shared__ __align__(16) ushort_t As[2][2][128 * 32];   // 32 KB
    __shared__ __align__(16) ushort_t Bs[2][2][64 * 32];    // 16 KB
    int tid = threadIdx.x;
    int wave = tid >> 6, lane = tid & 63, quad = lane >> 4, l16 = lane & 15;
    int wx = wave & 1, wy = wave >> 1;
    int nb = blockIdx.x * 64, mb = blockIdx.y * 128;

    f32x4 zero = {0.f, 0.f, 0.f, 0.f};
    f32x4 acc[4][2];
    #pragma unroll
    for (int i = 0; i < 4; i++)
        #pragma unroll
        for (int j = 0; j < 2; j++) acc[i][j] = zero;

    int rl = lane >> 2;            // 0..15
    int cl = (lane & 3) * 8;       // element col within 32
    const ushort_t* gA = xb + (size_t)(mb + wave * 32 + rl) * DIM + cl;
    const ushort_t* gB = WT + (size_t)(nb + wave * 16 + rl) * DIM + cl;

    auto stage = [&](int k0, int b) {
        gload_lds16(gA + k0,                 &As[b][0][(wave * 32) * 32]);
        gload_lds16(gA + k0 + 16 * DIM,      &As[b][0][(wave * 32) * 32] + 16 * 32);
        gload_lds16(gA + k0 + 32,            &As[b][1][(wave * 32) * 32]);
        gload_lds16(gA + k0 + 32 + 16 * DIM, &As[b][1][(wave * 32) * 32] + 16 * 32);
        gload_lds16(gB + k0,                 &Bs[b][0][(wave * 16) * 32]);
        gload_lds16(gB + k0 + 32,            &Bs[b][1][(wave * 16) * 32]);
    };

    stage(0, 0);
    for (int it = 0; it < 12; ++it) {
        int cur = it & 1;
        if (it < 11) {
            stage((it + 1) * 64, cur ^ 1);
            asm volatile("s_waitcnt vmcnt(6)" ::: "memory");
        } else {
            asm volatile("s_waitcnt vmcnt(0)" ::: "memory");
        }
        __builtin_amdgcn_s_barrier();
        #pragma unroll
        for (int p = 0; p < 2; p++) {
            bf16x8 af[4], bf[2];
            #pragma unroll
            for (int i = 0; i < 4; i++)
                af[i] = *(const bf16x8*)&As[cur][p][(wy * 64 + i * 16 + l16) * 32 + quad * 8];
            #pragma unroll
            for (int j = 0; j < 2; j++)
                bf[j] = *(const bf16x8*)&Bs[cur][p][(wx * 32 + j * 16 + l16) * 32 + quad * 8];
            #pragma unroll
            for (int i = 0; i < 4; i++)
                #pragma unroll
                for (int j = 0; j < 2; j++)
                    acc[i][j] = __builtin_amdgcn_mfma_f32_16x16x32_bf16(af[i], bf[j], acc[i][j], 0, 0, 0);
        }
        __builtin_amdgcn_s_barrier();
    }

    // ---- epilogue: bias + convert + LDS repack + coalesced stores ----
    ushort_t* pool = &As[0][0][0];   // 32 KB contiguous, reusable now
    int sel = nb / DIM;
    int rem0 = nb - sel * DIM;
    int hh = rem0 >> 6;
    const float* bias = (sel == 0) ? bq : (sel == 1) ? bk : bv;

    __syncthreads();

    if (sel < 2) {
        const int P = 72;   // row pitch (144B = 9x16B: aligned, bank-rotating)
        #pragma unroll
        for (int j = 0; j < 2; j++) {
            int c = wx * 32 + j * 16 + l16;
            float bval = bias[rem0 + c];
            #pragma unroll
            for (int i = 0; i < 4; i++)
                #pragma unroll
                for (int r = 0; r < 4; r++) {
                    int row = wy * 64 + i * 16 + quad * 4 + r;
                    pool[row * P + c] = f2bf(acc[i][j][r] + bval);
                }
        }
        __syncthreads();
        ushort_t* qout = ((sel == 0) ? Qb : Kb) + (size_t)(hh * NTOK + mb) * HD;
        for (int idx = tid; idx < 128 * 8; idx += 256) {
            int row = idx >> 3, s8 = idx & 7;
            uint4 v = *(const uint4*)&pool[row * P + s8 * 8];
            *(uint4*)&qout[(size_t)row * HD + s8 * 8] = v;
        }
    } else {
        const int PV = 136; // col pitch (272B = 17x16B: aligned)
        #pragma unroll
        for (int j = 0; j < 2; j++) {
            int c = wx * 32 + j * 16 + l16;
            float bval = bias[rem0 + c];
            #pragma unroll
            for (int i = 0; i < 4; i++)
                #pragma unroll
                for (int r = 0; r < 4; r++) {
                    int row = wy * 64 + i * 16 + quad * 4 + r;
                    pool[c * PV + row] = f2bf(acc[i][j][r] + bval);
                }
        }
        __syncthreads();
        ushort_t* vout = Vtb + (size_t)(hh * HD) * NTOK + mb;
        for (int idx = tid; idx < 64 * 16; idx += 256) {
            int cc = idx >> 4, r8 = idx & 15;
            uint4 v = *(const uint4*)&pool[cc * PV + r8 * 8];
            *(uint4*)&vout[(size_t)cc * NTOK + r8 * 8] = v;
        }
    }
}

// ---------------------------------------------------------------------------
// Rel-pos bias via MFMA (outputs pre-scaled by log2 e). R19 decomposition:
// unit = (isW,h,g,ms) -> 3456 units / 864 blocks (3.4 waves/SIMD).
// ---------------------------------------------------------------------------
__global__ __launch_bounds__(256) void k_relmm(
    const ushort_t* __restrict__ Qb, const ushort_t* __restrict__ rphb,
    const ushort_t* __restrict__ rpwb, float* __restrict__ relH,
    ushort_t* __restrict__ relWb) {
    int id = blockIdx.x * 4 + (threadIdx.x >> 6);   // 0..3455
    int lane = threadIdx.x & 63, quad = lane >> 4, l16 = lane & 15;
    bool isW = id >= 1728;
    int t = isW ? id - 1728 : id;
    int ms = t % 3;
    int g  = (t / 3) % GRD;
    int h  = t / (3 * GRD);
    const ushort_t* tab = isW ? rpwb : rphb;

    f32x4 zero = {0.f, 0.f, 0.f, 0.f};
    f32x4 acc[3];
    #pragma unroll
    for (int ct = 0; ct < 3; ct++) acc[ct] = zero;

    bf16x8 bfr[3][2];
    #pragma unroll
    for (int ct = 0; ct < 3; ct++) {
        int trow = g + 47 - (ct * 16 + l16);
        bfr[ct][0] = *(const bf16x8*)&tab[(size_t)trow * HD + quad * 8];
        bfr[ct][1] = *(const bf16x8*)&tab[(size_t)trow * HD + 32 + quad * 8];
    }
    {
        int m = ms * 16 + l16;
        int n = isW ? m * GRD + g : g * GRD + m;
        bf16x8 a0 = *(const bf16x8*)&Qb[(size_t)(h * NTOK + n) * HD + quad * 8];
        bf16x8 a1 = *(const bf16x8*)&Qb[(size_t)(h * NTOK + n) * HD + 32 + quad * 8];
        #pragma unroll
        for (int ct = 0; ct < 3; ct++) {
            acc[ct] = __builtin_amdgcn_mfma_f32_16x16x32_bf16(a0, bfr[ct][0], acc[ct], 0, 0, 0);
            acc[ct] = __builtin_amdgcn_mfma_f32_16x16x32_bf16(a1, bfr[ct][1], acc[ct], 0, 0, 0);
        }
    }
    #pragma unroll
    for (int ct = 0; ct < 3; ct++) {
        #pragma unroll
        for (int r = 0; r < 4; r++) {
            int m = ms * 16 + quad * 4 + r;
            int n = isW ? m * GRD + g : g * GRD + m;
            int col = ct * 16 + l16;
            float val = acc[ct][r] * LOG2E;
            if (isW)
                relWb[(size_t)(h * NTOK + n) * GRD + col] = f2bf(val);
            else
                relH[(size_t)(h * NTOK + n) * GRD + col] = val;
        }
    }
}

// ---------------------------------------------------------------------------
// Flash attention, split-K. Block = (128 q-rows, head, chunk of 768 keys).
// Grid 648 <= 768 capacity (3 blk/CU at (256,3)): single-phase. R16 core
// + setprio (R20) + incremental mod-48 khl/kw chain (no divisions in loop).
// ---------------------------------------------------------------------------
__global__ __launch_bounds__(256, 3) void k_attn(
    const ushort_t* __restrict__ Qb, const ushort_t* __restrict__ Kb,
    const ushort_t* __restrict__ Vtb, const float* __restrict__ relH,
    const ushort_t* __restrict__ relWb, float* __restrict__ Opart,
    float* __restrict__ Lpart) {
    int h = blockIdx.x / CHUNKS, chunk = blockIdx.x - h * CHUNKS;
    int qt = blockIdx.y;
    int tid = threadIdx.x;
    int wave = tid >> 6, lane = tid & 63, quad = lane >> 4, l16 = lane & 15;
    int qbase = qt * 128;
    int kbase = chunk * KEYS_PER_CHUNK;

    __shared__ __align__(16) ushort_t Ks[64 * 68];
    __shared__ __align__(16) ushort_t Vs[64 * 68];
    __shared__ __align__(16) ushort_t Ps[4][32 * 68];
    __shared__ __align__(16) ushort_t rhs[128 * 18];

    for (int i = tid; i < 128 * 16; i += 256) {
        int r = i >> 4, c = i & 15;
        rhs[r * 18 + c] = f2bf(relH[(size_t)(h * NTOK + qbase + r) * GRD + chunk * 16 + c]);
    }

    bf16x8 qf[2][2];
    #pragma unroll
    for (int s = 0; s < 2; s++) {
        int qrow = qbase + wave * 32 + s * 16 + l16;
        qf[s][0] = *(const bf16x8*)&Qb[(size_t)(h * NTOK + qrow) * HD + quad * 8];
        qf[s][1] = *(const bf16x8*)&Qb[(size_t)(h * NTOK + qrow) * HD + 32 + quad * 8];
    }

    int r0 = tid >> 3, c0 = (tid & 7) * 8;
    const ushort_t* kg0 = Kb + (size_t)(h * NTOK + r0) * HD + c0;
    const ushort_t* kg1 = Kb + (size_t)(h * NTOK + r0 + 32) * HD + c0;
    const ushort_t* vg0 = Vtb + (size_t)(h * HD + r0) * NTOK + c0;
    const ushort_t* vg1 = Vtb + (size_t)(h * HD + r0 + 32) * NTOK + c0;
    int sk0 = r0 * 68 + c0, sk1 = sk0 + 32 * 68;

    // per-lane relW row pointers (rows owned by this lane across s=0,1)
    const ushort_t* rw0 = relWb + (size_t)(h * NTOK + qbase + wave * 32 + l16) * GRD;
    const ushort_t* rw1 = rw0 + (size_t)16 * GRD;

    float lacc[2] = {0.f, 0.f};
    f32x4 zero = {0.f, 0.f, 0.f, 0.f};
    f32x4 oacc[2][4];
    #pragma unroll
    for (int s = 0; s < 2; s++)
        #pragma unroll
        for (int cs = 0; cs < 4; cs++) oacc[s][cs] = zero;

    const float scale2 = 0.125f * LOG2E;

    uint4 rk0 = *(const uint4*)(kg0 + (size_t)kbase * HD);
    uint4 rk1 = *(const uint4*)(kg1 + (size_t)kbase * HD);
    uint4 rv0 = *(const uint4*)(vg0 + kbase);
    uint4 rv1 = *(const uint4*)(vg1 + kbase);

    // incremental (key mod 48, key/48) chain: start = kbase + quad*4
    // (kbase % 48 == 0, so kw=quad*4, khl=0); each ks advances by 16.
    int kwS = quad * 4;
    int khlS = 0;

    for (int kt = 0; kt < KT_PER; kt++) {
        int kb = kbase + kt * 64;

        // derive this kt's 4 (kw,khl) pairs from the chain
        int kwA[4], khlA[4];
        kwA[0] = kwS; khlA[0] = khlS;
        #pragma unroll
        for (int ks = 1; ks < 4; ks++) {
            int kw = kwA[ks - 1] + 16, kh = khlA[ks - 1];
            if (kw >= 48) { kw -= 48; kh += 1; }
            kwA[ks] = kw; khlA[ks] = kh;
        }
        { int kw = kwA[3] + 16, kh = khlA[3];
          if (kw >= 48) { kw -= 48; kh += 1; }
          kwS = kw; khlS = kh; }

        __syncthreads();
        *(uint4*)&Ks[sk0] = rk0;  *(uint4*)&Ks[sk1] = rk1;
        *(uint4*)&Vs[sk0] = rv0;  *(uint4*)&Vs[sk1] = rv1;
        __syncthreads();

        // rwv for THIS kt, issued first: softmax's wait is vmcnt(4) so the
        // K/V loads below stay in flight.
        uint2 rwv[2][4];
        #pragma unroll
        for (int ks = 0; ks < 4; ks++) {
            rwv[0][ks] = *(const uint2*)(rw0 + kwA[ks]);
            rwv[1][ks] = *(const uint2*)(rw1 + kwA[ks]);
        }

        if (kt < KT_PER - 1) {
            int kbn = kb + 64;
            rk0 = *(const uint4*)(kg0 + (size_t)kbn * HD);
            rk1 = *(const uint4*)(kg1 + (size_t)kbn * HD);
            rv0 = *(const uint4*)(vg0 + kbn);
            rv1 = *(const uint4*)(vg1 + kbn);
        }

        #pragma unroll
        for (int ks = 0; ks < 4; ks++) {
            bf16x8 kf0 = *(const bf16x8*)&Ks[(ks * 16 + l16) * 68 + quad * 8];
            bf16x8 kf1 = *(const bf16x8*)&Ks[(ks * 16 + l16) * 68 + 32 + quad * 8];
            f32x4 st[2];
            __builtin_amdgcn_s_setprio(1);
            #pragma unroll
            for (int s = 0; s < 2; s++) {
                f32x4 z = zero;
                z = __builtin_amdgcn_mfma_f32_16x16x32_bf16(kf0, qf[s][0], z, 0, 0, 0);
                z = __builtin_amdgcn_mfma_f32_16x16x32_bf16(kf1, qf[s][1], z, 0, 0, 0);
                st[s] = z;
            }
            __builtin_amdgcn_s_setprio(0);
            int khl = khlA[ks];
            #pragma unroll
            for (int s = 0; s < 2; s++) {
                int row = wave * 32 + s * 16 + l16;
                float rh = bf2f(rhs[row * 18 + khl]);
                uint2 u = rwv[s][ks];
                float p0 = __builtin_amdgcn_exp2f(st[s][0] * scale2 + rh + __uint_as_float(u.x << 16));
                float p1 = __builtin_amdgcn_exp2f(st[s][1] * scale2 + rh + __uint_as_float(u.x & 0xffff0000u));
                float p2 = __builtin_amdgcn_exp2f(st[s][2] * scale2 + rh + __uint_as_float(u.y << 16));
                float p3 = __builtin_amdgcn_exp2f(st[s][3] * scale2 + rh + __uint_as_float(u.y & 0xffff0000u));
                lacc[s] += (p0 + p1) + (p2 + p3);
                uint2 w;
                w.x = __builtin_amdgcn_perm(__float_as_uint(p1), __float_as_uint(p0), 0x07060302u);
                w.y = __builtin_amdgcn_perm(__float_as_uint(p3), __float_as_uint(p2), 0x07060302u);
                *(uint2*)&Ps[wave][(s * 16 + l16) * 68 + ks * 16 + quad * 4] = w;
            }
        }

        bf16x8 vf[4][2];
        #pragma unroll
        for (int cs = 0; cs < 4; cs++) {
            vf[cs][0] = *(const bf16x8*)&Vs[(cs * 16 + l16) * 68 + quad * 8];
            vf[cs][1] = *(const bf16x8*)&Vs[(cs * 16 + l16) * 68 + 32 + quad * 8];
        }
        __builtin_amdgcn_s_setprio(1);
        #pragma unroll
        for (int s = 0; s < 2; s++) {
            bf16x8 pa0 = *(const bf16x8*)&Ps[wave][(s * 16 + l16) * 68 + quad * 8];
            bf16x8 pa1 = *(const bf16x8*)&Ps[wave][(s * 16 + l16) * 68 + 32 + quad * 8];
            #pragma unroll
            for (int cs = 0; cs < 4; cs++) {
                oacc[s][cs] = __builtin_amdgcn_mfma_f32_16x16x32_bf16(pa0, vf[cs][0], oacc[s][cs], 0, 0, 0);
                oacc[s][cs] = __builtin_amdgcn_mfma_f32_16x16x32_bf16(pa1, vf[cs][1], oacc[s][cs], 0, 0, 0);
            }
        }
        __builtin_amdgcn_s_setprio(0);
    }

    #pragma unroll
    for (int s = 0; s < 2; s++) {
        float l = lacc[s];
        l += __shfl_xor(l, 16);
        l += __shfl_xor(l, 32);
        lacc[s] = l;
    }

    size_t obase = (size_t)(chunk * HEADS + h) * NTOK;
    #pragma unroll
    for (int s = 0; s < 2; s++) {
        #pragma unroll
        for (int cs = 0; cs < 4; cs++) {
            #pragma unroll
            for (int r = 0; r < 4; r++) {
                int row = qbase + wave * 32 + s * 16 + quad * 4 + r;
                Opart[(obase + row) * HD + cs * 16 + l16] = oacc[s][cs][r];
            }
        }
        if (quad == 0)
            Lpart[obase + qbase + wave * 32 + s * 16 + l16] = lacc[s];
    }
}

// ---------------------------------------------------------------------------
// Merge split-K partials: Ob = (sum_ch O) / (sum_ch l), bf16.
// ---------------------------------------------------------------------------
__global__ __launch_bounds__(256) void k_merge(const float* __restrict__ Opart,
                                               const float* __restrict__ Lpart,
                                               ushort_t* __restrict__ Ob) {
    int t = blockIdx.x * 256 + threadIdx.x;
    int e = t * 4;
    int c = e & (HD - 1);
    int row = (e >> 6) % NTOK;
    int h = e / (NTOK * HD);
    const int ostride = HEADS * NTOK * HD;
    float4 s = {0.f, 0.f, 0.f, 0.f};
    float l = 0.f;
    #pragma unroll
    for (int ch = 0; ch < CHUNKS; ch++) {
        float4 v = *(const float4*)&Opart[(size_t)ch * ostride + e];
        s.x += v.x; s.y += v.y; s.z += v.z; s.w += v.w;
        l += Lpart[(size_t)(ch * HEADS + h) * NTOK + row];
    }
    float inv = 1.0f / l;
    ushort4 o = make_ushort4(f2bf(s.x * inv), f2bf(s.y * inv),
                             f2bf(s.z * inv), f2bf(s.w * inv));
    *(ushort4*)&Ob[(size_t)row * DIM + h * HD + c] = o;
}

// ---------------------------------------------------------------------------
// Output projection: 64x64 tiles -> 432 blocks, BK=64, DOUBLE-BUFFERED
// staging (32 KB): stage(next) -> vmcnt(4) -> s_barrier -> compute ->
// s_barrier. Same K accumulation order -> bitwise-identical out.
// ---------------------------------------------------------------------------
__global__ __launch_bounds__(256) void k_gemm_proj(
    const ushort_t* __restrict__ Ob, const ushort_t* __restrict__ WTp,
    const float* __restrict__ bp, float* __restrict__ out) {
    __shared__ __align__(16) ushort_t As[2][2][64 * 32];    // 16 KB
    __shared__ __align__(16) ushort_t Bs[2][2][64 * 32];    // 16 KB
    int tid = threadIdx.x;
    int wave = tid >> 6, lane = tid & 63, quad = lane >> 4, l16 = lane & 15;
    int wx = wave & 1, wy = wave >> 1;
    int nb = blockIdx.x * 64, mb = blockIdx.y * 64;

    f32x4 zero = {0.f, 0.f, 0.f, 0.f};
    f32x4 acc[2][2];
    #pragma unroll
    for (int i = 0; i < 2; i++)
        #pragma unroll
        for (int j = 0; j < 2; j++) acc[i][j] = zero;

    int rl = lane >> 2;
    int cl = (lane & 3) * 8;
    const ushort_t* gA = Ob + (size_t)(mb + wave * 16 + rl) * DIM + cl;
    const ushort_t* gB = WTp + (size_t)(nb + wave * 16 + rl) * DIM + cl;

    auto stage = [&](int k0, int b) {
        gload_lds16(gA + k0,      &As[b][0][(wave * 16) * 32]);
        gload_lds16(gA + k0 + 32, &As[b][1][(wave * 16) * 32]);
        gload_lds16(gB + k0,      &Bs[b][0][(wave * 16) * 32]);
        gload_lds16(gB + k0 + 32, &Bs[b][1][(wave * 16) * 32]);
    };

    stage(0, 0);
    for (int it = 0; it < 12; ++it) {
        int cur = it & 1;
        if (it < 11) {
            stage((it + 1) * 64, cur ^ 1);
            asm volatile("s_waitcnt vmcnt(4)" ::: "memory");
        } else {
            asm volatile("s_waitcnt vmcnt(0)" ::: "memory");
        }
        __builtin_amdgcn_s_barrier();
        #pragma unroll
        for (int p = 0; p < 2; p++) {
            bf16x8 af[2], bf[2];
            #pragma unroll
            for (int i = 0; i < 2; i++)
                af[i] = *(const bf16x8*)&As[cur][p][(wy * 32 + i * 16 + l16) * 32 + quad * 8];
            #pragma unroll
            for (int j = 0; j < 2; j++)
                bf[j] = *(const bf16x8*)&Bs[cur][p][(wx * 32 + j * 16 + l16) * 32 + quad * 8];
            #pragma unroll
            for (int i = 0; i < 2; i++)
                #pragma unroll
                for (int j = 0; j < 2; j++)
                    acc[i][j] = __builtin_amdgcn_mfma_f32_16x16x32_bf16(af[i], bf[j], acc[i][j], 0, 0, 0);
        }
        __builtin_amdgcn_s_barrier();
    }

    #pragma unroll
    for (int j = 0; j < 2; j++) {
        int col = nb + wx * 32 + j * 16 + l16;
        float bval = bp[col];
        #pragma unroll
        for (int i = 0; i < 2; i++) {
            #pragma unroll
            for (int r = 0; r < 4; r++) {
                int row = mb + wy * 32 + i * 16 + quad * 4 + r;
                out[(size_t)row * DIM + col] = acc[i][j][r] + bval;
            }
        }
    }
}

// ---------------------------------------------------------------------------
extern "C" void kernel_launch(void* const* d_in, const int* in_sizes, int n_in,
                              void* d_out, int out_size, void* d_ws, size_t ws_size,
                              hipStream_t stream) {
    const float* x   = (const float*)d_in[0];
    const float* Wq  = (const float*)d_in[1];
    const float* bq  = (const float*)d_in[2];
    const float* Wk  = (const float*)d_in[3];
    const float* bk  = (const float*)d_in[4];
    const float* Wv  = (const float*)d_in[5];
    const float* bv  = (const float*)d_in[6];
    const float* Wp  = (const float*)d_in[7];
    const float* bp  = (const float*)d_in[8];
    const float* rph = (const float*)d_in[9];
    const float* rpw = (const float*)d_in[10];
    const float* Aq  = (const float*)d_in[11];
    const float* Bq  = (const float*)d_in[12];
    const float* Ak  = (const float*)d_in[13];
    const float* Bk  = (const float*)d_in[14];
    const float* Av  = (const float*)d_in[15];
    const float* Bv  = (const float*)d_in[16];
    float* out = (float*)d_out;

    char* w = (char*)d_ws;
    size_t off = 0;
    auto carve = [&](size_t bytes) {
        char* p = w + off;
        off += (bytes + 255) & ~(size_t)255;
        return p;
    };
    ushort_t* xb    = (ushort_t*)carve((size_t)NTOK * DIM * 2);
    ushort_t* WT    = (ushort_t*)carve((size_t)4 * DIM * DIM * 2);
    ushort_t* Qb    = (ushort_t*)carve((size_t)HEADS * NTOK * HD * 2);
    ushort_t* Kb    = (ushort_t*)carve((size_t)HEADS * NTOK * HD * 2);
    ushort_t* Vtb   = (ushort_t*)carve((size_t)HEADS * HD * NTOK * 2);
    float*    relH  = (float*)carve((size_t)HEADS * NTOK * GRD * 4);
    ushort_t* relWb = (ushort_t*)carve((size_t)HEADS * NTOK * GRD * 2);
    ushort_t* Ob    = (ushort_t*)carve((size_t)NTOK * DIM * 2);
    float*    Opart = (float*)carve((size_t)CHUNKS * HEADS * NTOK * HD * 4);
    float*    Lpart = (float*)carve((size_t)CHUNKS * HEADS * NTOK * 4);
    ushort_t* rphb  = (ushort_t*)carve((size_t)(2 * GRD - 1) * HD * 2);
    ushort_t* rpwb  = (ushort_t*)carve((size_t)(2 * GRD - 1) * HD * 2);

    k_prep<<<dim3(2304), dim3(256), 0, stream>>>(
        x, xb, rph, rpw, rphb, rpwb,
        Wq, Wk, Wv, Wp, Aq, Bq, Ak, Bk, Av, Bv, WT);
    k_gemm_qkv<<<dim3(36, 18), dim3(256), 0, stream>>>(
        xb, WT, bq, bk, bv, Qb, Kb, Vtb);
    k_relmm<<<dim3(864), dim3(256), 0, stream>>>(
        Qb, rphb, rpwb, relH, relWb);
    k_attn<<<dim3(HEADS * CHUNKS, NTOK / 128), dim3(256), 0, stream>>>(
        Qb, Kb, Vtb, relH, relWb, Opart, Lpart);
    k_merge<<<dim3(HEADS * NTOK * HD / (256 * 4)), dim3(256), 0, stream>>>(
        Opart, Lpart, Ob);
    k_gemm_proj<<<dim3(12, 36), dim3(256), 0, stream>>>(
        Ob, WT + (size_t)3 * DIM * DIM, bp, out);
}